// Round 1
// baseline (9111.448 us; speedup 1.0000x reference)
//
#include <hip/hip_runtime.h>
#include <math.h>

#define H 256
#define F 128
#define NLAYERS 4
#define NG 8192
#define NC 65536
#define EC 524288
#define EG 32768
#define NCONF 4096
#define NMOL 512
#define NGAUSS 50
#define CE 65536   // edge chunk size (EC/CE = 8 chunks)

// ---------------- elementwise / gather kernels ----------------

// x[i,h] = sum_f atom_emb[f, x_atom[i%NG, f], h]
__global__ __launch_bounds__(256) void k_init_x(const float* __restrict__ atom_emb,
    const int* __restrict__ x_atom, float* __restrict__ x)
{
    int i = blockIdx.x;
    int h = threadIdx.x;
    int g = i & (NG - 1);
    float s = 0.f;
#pragma unroll
    for (int f = 0; f < 9; ++f) {
        int a = x_atom[g * 9 + f];
        s += atom_emb[(f * 64 + a) * H + h];
    }
    x[(size_t)i * H + h] = s;
}

__global__ __launch_bounds__(256) void k_vninit(const float* __restrict__ vn_emb,
                                                float* __restrict__ vn)
{
    vn[(size_t)blockIdx.x * H + threadIdx.x] = vn_emb[threadIdx.x];
}

// d, cosine cutoff per conformer edge
__global__ __launch_bounds__(256) void k_geom(const float* __restrict__ pos,
    const int* __restrict__ ei, float* __restrict__ d, float* __restrict__ ccut)
{
    int e = blockIdx.x * 256 + threadIdx.x;
    if (e >= EC) return;
    int s = ei[e], t = ei[EC + e];
    float dx = pos[s * 3 + 0] - pos[t * 3 + 0];
    float dy = pos[s * 3 + 1] - pos[t * 3 + 1];
    float dz = pos[s * 3 + 2] - pos[t * 3 + 2];
    float dd = sqrtf(dx * dx + dy * dy + dz * dz);
    d[e] = dd;
    ccut[e] = 0.5f * (cosf(dd * 0.314159265358979f) + 1.0f);
}

__global__ __launch_bounds__(256) void k_addvn(float* __restrict__ x,
    const float* __restrict__ vn, const int* __restrict__ pos_batch)
{
    int i = blockIdx.x;
    int c = pos_batch[i];
    x[(size_t)i * H + threadIdx.x] += vn[(size_t)c * H + threadIdx.x];
}

// tmp[c] = vn[c] + sum over the 16 nodes of conformer c of x
// (pos_batch[r*NG + j] == (j/16)*8 + r  =>  c -> nodes r*NG + 16m + t, m=c>>3, r=c&7)
__global__ __launch_bounds__(256) void k_vn_tmp(const float* __restrict__ x,
    const float* __restrict__ vn, float* __restrict__ tmp)
{
    int c = blockIdx.x, h = threadIdx.x;
    int m = c >> 3, r = c & 7;
    size_t base = ((size_t)r * NG + m * 16) * H + h;
    float s = vn[(size_t)c * H + h];
#pragma unroll 4
    for (int t = 0; t < 16; ++t) s += x[base + (size_t)t * H];
    tmp[(size_t)c * H + h] = s;
}

// gaussian smearing for an edge chunk: g[e,k] = exp(-12.005*(d-off_k)^2)
__global__ __launch_bounds__(256) void k_gauss(const float* __restrict__ d,
    float* __restrict__ g, int e0)
{
    int idx = blockIdx.x * 256 + threadIdx.x;
    int e = idx >> 6, k = idx & 63;
    if (k >= NGAUSS) return;
    float off = (float)k * (10.0f / 49.0f);
    float dd = d[e0 + e] - off;
    g[(size_t)e * NGAUSS + k] = __expf(-12.005f * dd * dd);
}

// hagg[dst[e]] += cfh[src[e]] * We[e]   (32 threads/edge, 4 floats each)
__global__ __launch_bounds__(256) void k_cf_scatter(const float* __restrict__ We,
    const int* __restrict__ src, const int* __restrict__ dst,
    const float* __restrict__ cfh, float* __restrict__ hagg, int e0)
{
    int idx = blockIdx.x * 256 + threadIdx.x;
    int e = idx >> 5, q = idx & 31;
    int s = src[e0 + e], t = dst[e0 + e];
    float4 w  = *(const float4*)&We[(size_t)e * F + q * 4];
    float4 hv = *(const float4*)&cfh[(size_t)s * F + q * 4];
    float* dp = &hagg[(size_t)t * F + q * 4];
    atomicAdd(dp + 0, hv.x * w.x);
    atomicAdd(dp + 1, hv.y * w.y);
    atomicAdd(dp + 2, hv.z * w.z);
    atomicAdd(dp + 3, hv.w * w.w);
}

// xa[g] = max over the 8 conformer copies (conf_node_batch[i] == i % NG)
__global__ __launch_bounds__(256) void k_xa(const float* __restrict__ x,
                                            float* __restrict__ xa)
{
    int g = blockIdx.x, h = threadIdx.x;
    size_t off = (size_t)g * H + h;
    float m = x[off];
#pragma unroll
    for (int r = 1; r < 8; ++r) m = fmaxf(m, x[off + (size_t)r * NG * H]);
    xa[off] = m;
}

// agg[gdst] += relu(xa[gsrc] + bond_emb_sum)
__global__ __launch_bounds__(256) void k_gin_scatter(const float* __restrict__ xa,
    const float* __restrict__ bond, const int* __restrict__ ei,
    const int* __restrict__ attr, float* __restrict__ agg)
{
    int e = blockIdx.x, h = threadIdx.x;
    int s = ei[e], t = ei[EG + e];
    int a0 = attr[e * 3 + 0], a1 = attr[e * 3 + 1], a2 = attr[e * 3 + 2];
    float v = xa[(size_t)s * H + h]
            + bond[(0 * 8 + a0) * H + h]
            + bond[(1 * 8 + a1) * H + h]
            + bond[(2 * 8 + a2) * H + h];
    v = fmaxf(v, 0.f);
    atomicAdd(&agg[(size_t)t * H + h], v);
}

// agg = (1+eps)*xa + agg  (in place)
__global__ __launch_bounds__(256) void k_gin_pre(const float* __restrict__ xa,
    float* __restrict__ agg, const float* __restrict__ eps_p)
{
    size_t i = (size_t)blockIdx.x * 256 + threadIdx.x;
    agg[i] = (1.0f + eps_p[0]) * xa[i] + agg[i];
}

// column sums / sumsq over NG rows (64 blocks x 128 rows), atomics into stats[512]
__global__ __launch_bounds__(256) void k_bnstats(const float* __restrict__ z,
                                                 float* __restrict__ stats)
{
    int h = threadIdx.x;
    size_t r0 = (size_t)blockIdx.x * (NG / 64);
    float s = 0.f, q = 0.f;
    for (int r = 0; r < NG / 64; ++r) {
        float v = z[(r0 + r) * H + h];
        s += v; q = fmaf(v, v, q);
    }
    atomicAdd(&stats[h], s);
    atomicAdd(&stats[H + h], q);
}

template <bool RELU>
__global__ __launch_bounds__(256) void k_bnapply(float* __restrict__ z,
    const float* __restrict__ stats, const float* __restrict__ gamma,
    const float* __restrict__ beta)
{
    size_t i = (size_t)blockIdx.x * 256 + threadIdx.x;
    int h = threadIdx.x;   // H == 256, one row per block
    float mean = stats[h] * (1.0f / NG);
    float var = stats[H + h] * (1.0f / NG) - mean * mean;
    float v = (z[i] - mean) * rsqrtf(var + 1e-5f) * gamma[h] + beta[h];
    if (RELU) v = fmaxf(v, 0.f);
    z[i] = v;
}

// fused conf-max + mol-max: molecule m <- nodes r*NG + 16m + t, r<8, t<16
__global__ __launch_bounds__(256) void k_molmax(const float* __restrict__ x,
                                                float* __restrict__ xm)
{
    int m = blockIdx.x, h = threadIdx.x;
    float best = -3.4e38f;
    for (int r = 0; r < 8; ++r) {
        size_t base = ((size_t)r * NG + m * 16) * H + h;
#pragma unroll 4
        for (int t = 0; t < 16; ++t) best = fmaxf(best, x[base + (size_t)t * H]);
    }
    xm[(size_t)m * H + h] = best;
}

__global__ __launch_bounds__(256) void k_head(const float* __restrict__ y1,
    const float* __restrict__ w2, const float* __restrict__ b2,
    float* __restrict__ out)
{
    __shared__ float red[256];
    int m = blockIdx.x, h = threadIdx.x;
    red[h] = y1[(size_t)m * H + h] * w2[h];
    __syncthreads();
    for (int s = 128; s > 0; s >>= 1) {
        if (h < s) red[h] += red[h + s];
        __syncthreads();
    }
    if (h == 0) out[m] = red[0] + b2[0];
}

// ---------------- generic f32 GEMM: C[M,N] = A[M,K] @ B[K,N] (+epilogue) ----
// EPI 0: +bias            EPI 1: relu(+bias)
// EPI 2: (+bias)*aux[m]   EPI 3: C[m,n] = relu(C[m,n] + acc + bias[n] + aux[(m%NG)*N+n])
// M, N must be multiples of 64; K arbitrary (guarded).
template <int EPI>
__global__ __launch_bounds__(256) void k_gemm(const float* __restrict__ A,
    const float* __restrict__ B, const float* __restrict__ bias,
    float* __restrict__ C, int M, int N, int K, const float* __restrict__ aux)
{
    __shared__ float As[16 * 68];
    __shared__ float Bs[16 * 68];
    int bm = blockIdx.y * 64, bn = blockIdx.x * 64;
    int tid = threadIdx.x;
    int tr = tid >> 4, tc = tid & 15;
    float acc[4][4] = {{0.f}};
    for (int k0 = 0; k0 < K; k0 += 16) {
#pragma unroll
        for (int t = 0; t < 4; ++t) {
            int idx = tid + t * 256;
            int mm = idx >> 4, kk = idx & 15;
            int kg = k0 + kk;
            As[kk * 68 + mm] = (kg < K) ? A[(size_t)(bm + mm) * K + kg] : 0.f;
            int kk2 = idx >> 6, nn = idx & 63;
            int kg2 = k0 + kk2;
            Bs[kk2 * 68 + nn] = (kg2 < K) ? B[(size_t)kg2 * N + bn + nn] : 0.f;
        }
        __syncthreads();
#pragma unroll
        for (int kk = 0; kk < 16; ++kk) {
            float4 a4 = *(const float4*)(As + kk * 68 + tr * 4);
            float4 b4 = *(const float4*)(Bs + kk * 68 + tc * 4);
            float a[4] = {a4.x, a4.y, a4.z, a4.w};
            float b[4] = {b4.x, b4.y, b4.z, b4.w};
#pragma unroll
            for (int i = 0; i < 4; ++i)
#pragma unroll
                for (int j = 0; j < 4; ++j)
                    acc[i][j] = fmaf(a[i], b[j], acc[i][j]);
        }
        __syncthreads();
    }
#pragma unroll
    for (int i = 0; i < 4; ++i) {
        int m = bm + tr * 4 + i;
#pragma unroll
        for (int j = 0; j < 4; ++j) {
            int n = bn + tc * 4 + j;
            float v = acc[i][j];
            if (bias) v += bias[n];
            if (EPI == 1) v = fmaxf(v, 0.f);
            if (EPI == 2) v *= aux[m];
            if (EPI == 3) {
                size_t idx = (size_t)m * N + n;
                v += C[idx] + aux[(size_t)(m & (NG - 1)) * N + n];
                C[idx] = fmaxf(v, 0.f);
                continue;
            }
            C[(size_t)m * N + n] = v;
        }
    }
}

// ---------------- launch ----------------
// workspace (floats):  ~63.2M floats = ~253 MB
extern "C" void kernel_launch(void* const* d_in, const int* in_sizes, int n_in,
                              void* d_out, int out_size, void* d_ws, size_t ws_size,
                              hipStream_t stream)
{
    (void)in_sizes; (void)n_in; (void)out_size; (void)ws_size;
    const float* pos       = (const float*)d_in[0];
    const float* atom_emb  = (const float*)d_in[1];
    const float* vn_emb    = (const float*)d_in[2];
    const float* cf_lin1   = (const float*)d_in[3];
    const float* cf_mlp_w1 = (const float*)d_in[4];
    const float* cf_mlp_b1 = (const float*)d_in[5];
    const float* cf_mlp_w2 = (const float*)d_in[6];
    const float* cf_mlp_b2 = (const float*)d_in[7];
    const float* cf_lin2   = (const float*)d_in[8];
    const float* cf_lin2_b = (const float*)d_in[9];
    const float* lin_w     = (const float*)d_in[10];
    const float* lin_b     = (const float*)d_in[11];
    const float* bond_emb  = (const float*)d_in[12];
    const float* gin_eps   = (const float*)d_in[13];
    const float* gin_w1    = (const float*)d_in[14];
    const float* gin_b1    = (const float*)d_in[15];
    const float* gin_g1    = (const float*)d_in[16];
    const float* gin_be1   = (const float*)d_in[17];
    const float* gin_w2    = (const float*)d_in[18];
    const float* gin_b2    = (const float*)d_in[19];
    const float* bn_g      = (const float*)d_in[20];
    const float* bn_b      = (const float*)d_in[21];
    const float* vn_w1     = (const float*)d_in[22];
    const float* vn_b1     = (const float*)d_in[23];
    const float* vn_w2     = (const float*)d_in[24];
    const float* vn_b2     = (const float*)d_in[25];
    const float* out_w1    = (const float*)d_in[26];
    const float* out_b1    = (const float*)d_in[27];
    const float* out_w2    = (const float*)d_in[28];
    const float* out_b2    = (const float*)d_in[29];
    const int* x_atom      = (const int*)d_in[30];
    const int* pos_batch   = (const int*)d_in[32];
    const int* ei_conf     = (const int*)d_in[34];
    const int* ei_graph    = (const int*)d_in[35];
    const int* attr_graph  = (const int*)d_in[36];
    float* out = (float*)d_out;
    float* ws  = (float*)d_ws;

    size_t off = 0;
    float* X    = ws + off; off += (size_t)NC * H;      // 16.78M
    float* CFH  = ws + off; off += (size_t)NC * F;      //  8.39M
    float* HAGG = ws + off; off += (size_t)NC * F;      //  8.39M
    float* BIG  = ws + off; off += (size_t)NC * H;      // 16.78M (T1/WE/gauss chunks, then H2)
    float* Dd   = ws + off; off += EC;
    float* CCUT = ws + off; off += EC;
    float* XA   = ws + off; off += (size_t)NG * H;
    float* AGG  = ws + off; off += (size_t)NG * H;
    float* Z1   = ws + off; off += (size_t)NG * H;
    float* Z2   = ws + off; off += (size_t)NG * H;
    float* VN   = ws + off; off += (size_t)NCONF * H;
    float* TMP  = ws + off; off += (size_t)NCONF * H;
    float* TMP2 = ws + off; off += (size_t)NCONF * H;
    float* XM   = ws + off; off += (size_t)NMOL * H;
    float* Y1   = ws + off; off += (size_t)NMOL * H;
    float* STATS= ws + off; off += 512;

    float* T1  = BIG;                    // [CE,F]
    float* WE  = BIG + (size_t)CE * F;   // [CE,F]  (aliases gauss chunk region)
    float* GCH = WE;                     // [CE,50] lives until T1 GEMM done
    float* H2  = BIG;                    // [NC,H]  after edge pipeline finishes

    k_init_x<<<NC, 256, 0, stream>>>(atom_emb, x_atom, X);
    k_vninit<<<NCONF, 256, 0, stream>>>(vn_emb, VN);
    k_geom<<<EC / 256, 256, 0, stream>>>(pos, ei_conf, Dd, CCUT);

    for (int i = 0; i < NLAYERS; ++i) {
        k_addvn<<<NC, 256, 0, stream>>>(X, VN, pos_batch);
        if (i < NLAYERS - 1) {
            k_vn_tmp<<<NCONF, 256, 0, stream>>>(X, VN, TMP);
            k_gemm<1><<<dim3(H / 64, NCONF / 64), 256, 0, stream>>>(
                TMP, vn_w1, vn_b1, TMP2, NCONF, H, H, nullptr);
            k_gemm<1><<<dim3(H / 64, NCONF / 64), 256, 0, stream>>>(
                TMP2, vn_w2, vn_b2, VN, NCONF, H, H, nullptr);
        }
        // ---- CFConv ----
        k_gemm<0><<<dim3(F / 64, NC / 64), 256, 0, stream>>>(
            X, cf_lin1 + (size_t)i * H * F, nullptr, CFH, NC, F, H, nullptr);
        hipMemsetAsync(HAGG, 0, (size_t)NC * F * sizeof(float), stream);
        for (int c = 0; c < EC / CE; ++c) {
            int e0 = c * CE;
            k_gauss<<<CE * 64 / 256, 256, 0, stream>>>(Dd, GCH, e0);
            k_gemm<1><<<dim3(F / 64, CE / 64), 256, 0, stream>>>(
                GCH, cf_mlp_w1 + (size_t)i * NGAUSS * F, cf_mlp_b1 + i * F,
                T1, CE, F, NGAUSS, nullptr);
            k_gemm<2><<<dim3(F / 64, CE / 64), 256, 0, stream>>>(
                T1, cf_mlp_w2 + (size_t)i * F * F, cf_mlp_b2 + i * F,
                WE, CE, F, F, CCUT + e0);
            k_cf_scatter<<<CE * 32 / 256, 256, 0, stream>>>(
                WE, ei_conf, ei_conf + EC, CFH, HAGG, e0);
        }
        // ---- GIN (uses pre-update X) ----
        k_xa<<<NG, 256, 0, stream>>>(X, XA);
        hipMemsetAsync(AGG, 0, (size_t)NG * H * sizeof(float), stream);
        k_gin_scatter<<<EG, 256, 0, stream>>>(
            XA, bond_emb + (size_t)i * 3 * 8 * H, ei_graph, attr_graph, AGG);
        k_gin_pre<<<NG, 256, 0, stream>>>(XA, AGG, gin_eps + i);
        k_gemm<0><<<dim3(H / 64, NG / 64), 256, 0, stream>>>(
            AGG, gin_w1 + (size_t)i * H * H, gin_b1 + i * H, Z1, NG, H, H, nullptr);
        hipMemsetAsync(STATS, 0, 2048, stream);
        k_bnstats<<<64, 256, 0, stream>>>(Z1, STATS);
        k_bnapply<true><<<NG, 256, 0, stream>>>(Z1, STATS, gin_g1 + i * H, gin_be1 + i * H);
        k_gemm<0><<<dim3(H / 64, NG / 64), 256, 0, stream>>>(
            Z1, gin_w2 + (size_t)i * H * H, gin_b2 + i * H, Z2, NG, H, H, nullptr);
        hipMemsetAsync(STATS, 0, 2048, stream);
        k_bnstats<<<64, 256, 0, stream>>>(Z2, STATS);
        k_bnapply<false><<<NG, 256, 0, stream>>>(Z2, STATS, bn_g + i * H, bn_b + i * H);
        // ---- combine: H2 = relu(HAGG@cf_lin2+b); X = relu(X + H2@lin_w + lin_b + Z2[m%NG]) ----
        k_gemm<1><<<dim3(H / 64, NC / 64), 256, 0, stream>>>(
            HAGG, cf_lin2 + (size_t)i * F * H, cf_lin2_b + i * H, H2, NC, H, F, nullptr);
        k_gemm<3><<<dim3(H / 64, NC / 64), 256, 0, stream>>>(
            H2, lin_w + (size_t)i * H * H, lin_b + i * H, X, NC, H, H, Z2);
    }

    k_molmax<<<NMOL, 256, 0, stream>>>(X, XM);
    k_gemm<1><<<dim3(H / 64, NMOL / 64), 256, 0, stream>>>(
        XM, out_w1, out_b1, Y1, NMOL, H, H, nullptr);
    k_head<<<NMOL, 256, 0, stream>>>(Y1, out_w2, out_b2, out);
}

// Round 2
// 3506.256 us; speedup vs baseline: 2.5986x; 2.5986x over previous
//
#include <hip/hip_runtime.h>
#include <math.h>

#define H 256
#define F 128
#define NLAYERS 4
#define NG 8192
#define NC 65536
#define EC 524288
#define EG 32768
#define NCONF 4096
#define NMOL 512
#define NGAUSS 50
#define CE 131072   // edge chunk (EC/CE = 4 chunks)

using s16x8 = __attribute__((ext_vector_type(8))) short;
using f32x4 = __attribute__((ext_vector_type(4))) float;

static __device__ __forceinline__ unsigned short f2bf(float f) {
    unsigned int u = __float_as_uint(f);
    u += 0x7fffu + ((u >> 16) & 1u);   // round-to-nearest-even (finite values)
    return (unsigned short)(u >> 16);
}

// ---------------- elementwise / gather kernels ----------------

__global__ __launch_bounds__(256) void k_init_x(const float* __restrict__ atom_emb,
    const int* __restrict__ x_atom, float* __restrict__ x)
{
    int i = blockIdx.x, h = threadIdx.x;
    int g = i & (NG - 1);
    float s = 0.f;
#pragma unroll
    for (int f = 0; f < 9; ++f) {
        int a = x_atom[g * 9 + f];
        s += atom_emb[(f * 64 + a) * H + h];
    }
    x[(size_t)i * H + h] = s;
}

__global__ __launch_bounds__(256) void k_vninit(const float* __restrict__ vn_emb,
                                                float* __restrict__ vn)
{
    vn[(size_t)blockIdx.x * H + threadIdx.x] = vn_emb[threadIdx.x];
}

__global__ __launch_bounds__(256) void k_geom(const float* __restrict__ pos,
    const int* __restrict__ ei, float* __restrict__ d, float* __restrict__ ccut)
{
    int e = blockIdx.x * 256 + threadIdx.x;
    if (e >= EC) return;
    int s = ei[e], t = ei[EC + e];
    float dx = pos[s * 3 + 0] - pos[t * 3 + 0];
    float dy = pos[s * 3 + 1] - pos[t * 3 + 1];
    float dz = pos[s * 3 + 2] - pos[t * 3 + 2];
    float dd = sqrtf(dx * dx + dy * dy + dz * dz);
    d[e] = dd;
    ccut[e] = 0.5f * (cosf(dd * 0.314159265358979f) + 1.0f);
}

__global__ __launch_bounds__(256) void k_addvn(float* __restrict__ x,
    const float* __restrict__ vn, const int* __restrict__ pos_batch)
{
    int i = blockIdx.x;
    int c = pos_batch[i];
    x[(size_t)i * H + threadIdx.x] += vn[(size_t)c * H + threadIdx.x];
}

// tmp[c] = vn[c] + sum over 16 nodes of conformer c (c = m*8+r -> nodes r*NG+16m+t)
__global__ __launch_bounds__(256) void k_vn_tmp(const float* __restrict__ x,
    const float* __restrict__ vn, float* __restrict__ tmp)
{
    int c = blockIdx.x, h = threadIdx.x;
    int m = c >> 3, r = c & 7;
    size_t base = ((size_t)r * NG + m * 16) * H + h;
    float s = vn[(size_t)c * H + h];
#pragma unroll 4
    for (int t = 0; t < 16; ++t) s += x[base + (size_t)t * H];
    tmp[(size_t)c * H + h] = s;
}

__global__ __launch_bounds__(256) void k_xa(const float* __restrict__ x,
                                            float* __restrict__ xa)
{
    int g = blockIdx.x, h = threadIdx.x;
    size_t off = (size_t)g * H + h;
    float m = x[off];
#pragma unroll
    for (int r = 1; r < 8; ++r) m = fmaxf(m, x[off + (size_t)r * NG * H]);
    xa[off] = m;
}

__global__ __launch_bounds__(256) void k_gin_scatter(const float* __restrict__ xa,
    const float* __restrict__ bond, const int* __restrict__ ei,
    const int* __restrict__ attr, float* __restrict__ agg)
{
    int e = blockIdx.x, h = threadIdx.x;
    int s = ei[e], t = ei[EG + e];
    int a0 = attr[e * 3 + 0], a1 = attr[e * 3 + 1], a2 = attr[e * 3 + 2];
    float v = xa[(size_t)s * H + h]
            + bond[(0 * 8 + a0) * H + h]
            + bond[(1 * 8 + a1) * H + h]
            + bond[(2 * 8 + a2) * H + h];
    v = fmaxf(v, 0.f);
    atomicAdd(&agg[(size_t)t * H + h], v);
}

__global__ __launch_bounds__(256) void k_gin_pre(const float* __restrict__ xa,
    float* __restrict__ agg, const float* __restrict__ eps_p)
{
    size_t i = (size_t)blockIdx.x * 256 + threadIdx.x;
    agg[i] = (1.0f + eps_p[0]) * xa[i] + agg[i];
}

__global__ __launch_bounds__(256) void k_bnstats(const float* __restrict__ z,
                                                 float* __restrict__ stats)
{
    int h = threadIdx.x;
    size_t r0 = (size_t)blockIdx.x * (NG / 64);
    float s = 0.f, q = 0.f;
    for (int r = 0; r < NG / 64; ++r) {
        float v = z[(r0 + r) * H + h];
        s += v; q = fmaf(v, v, q);
    }
    atomicAdd(&stats[h], s);
    atomicAdd(&stats[H + h], q);
}

template <bool RELU>
__global__ __launch_bounds__(256) void k_bnapply(float* __restrict__ z,
    const float* __restrict__ stats, const float* __restrict__ gamma,
    const float* __restrict__ beta)
{
    size_t i = (size_t)blockIdx.x * 256 + threadIdx.x;
    int h = threadIdx.x;
    float mean = stats[h] * (1.0f / NG);
    float var = stats[H + h] * (1.0f / NG) - mean * mean;
    float v = (z[i] - mean) * rsqrtf(var + 1e-5f) * gamma[h] + beta[h];
    if (RELU) v = fmaxf(v, 0.f);
    z[i] = v;
}

__global__ __launch_bounds__(256) void k_molmax(const float* __restrict__ x,
                                                float* __restrict__ xm)
{
    int m = blockIdx.x, h = threadIdx.x;
    float best = -3.4e38f;
    for (int r = 0; r < 8; ++r) {
        size_t base = ((size_t)r * NG + m * 16) * H + h;
#pragma unroll 4
        for (int t = 0; t < 16; ++t) best = fmaxf(best, x[base + (size_t)t * H]);
    }
    xm[(size_t)m * H + h] = best;
}

__global__ __launch_bounds__(256) void k_head(const float* __restrict__ y1,
    const float* __restrict__ w2, const float* __restrict__ b2,
    float* __restrict__ out)
{
    __shared__ float red[256];
    int m = blockIdx.x, h = threadIdx.x;
    red[h] = y1[(size_t)m * H + h] * w2[h];
    __syncthreads();
    for (int s = 128; s > 0; s >>= 1) {
        if (h < s) red[h] += red[h + s];
        __syncthreads();
    }
    if (h == 0) out[m] = red[0] + b2[0];
}

// weight transpose+convert: Wt[n*Kp+k] = bf16(W[k*N+n]), zero-padded to Kp
__global__ __launch_bounds__(256) void k_wt(const float* __restrict__ W,
    unsigned short* __restrict__ Wt, int K, int N, int Kp)
{
    int n = blockIdx.x;
    for (int k = threadIdx.x; k < Kp; k += 256)
        Wt[(size_t)n * Kp + k] = (k < K) ? f2bf(W[(size_t)k * N + n]) : (unsigned short)0;
}

// ---------------- MFMA GEMM ----------------
// C[M,N] = A[M,K] @ B[K,N], tile 128x128, BK=64, 4 waves (2x2 of 64x64).
// ASRC: 0 = f32 A (convert on stage), 1 = gauss-generated from dgeo, 2 = bf16 A
// EPI:  0 = Cf=v+bias, 1 = relu, 2 = relu -> bf16 Cb,
//       3 = CFConv scatter: hagg[dst[m]][n] += (v+bias)*ccut[m]*cfh[src[m]][n]
//       4 = Cf[m][n] = relu(Cf[m][n] + v + bias + aux[(m&8191)*ldc+n])
template<int ASRC, int EPI>
__global__ __launch_bounds__(256) void mgemm(
    const float* __restrict__ Af, const unsigned short* __restrict__ Ab,
    const float* __restrict__ dgeo,
    const unsigned short* __restrict__ Bt,
    const float* __restrict__ bias,
    float* __restrict__ Cf, unsigned short* __restrict__ Cb,
    int K, int Kp, int ldc,
    const float* __restrict__ aux,
    const int* __restrict__ esrc, const int* __restrict__ edst,
    const float* __restrict__ cfh, float* __restrict__ hagg)
{
    __shared__ unsigned short As[128][72];
    __shared__ unsigned short Bs[128][72];
    const int tid = threadIdx.x;
    const int bm = blockIdx.y * 128;
    const int bn = blockIdx.x * 128;
    const int lane = tid & 63;
    const int wid = tid >> 6;
    const int wm = wid >> 1, wn = wid & 1;
    const int rsel = lane & 15, ksel = (lane >> 4) * 8;

    f32x4 acc[4][4];
#pragma unroll
    for (int a = 0; a < 4; ++a)
#pragma unroll
        for (int b = 0; b < 4; ++b) acc[a][b] = (f32x4){0.f, 0.f, 0.f, 0.f};

    for (int k0 = 0; k0 < Kp; k0 += 64) {
        // ---- stage B: Bt[N][Kp] bf16, 16B chunks ----
#pragma unroll
        for (int i = 0; i < 4; ++i) {
            int c = tid + i * 256;
            int row = c >> 3, kc = (c & 7) * 8;
            uint4 v = *(const uint4*)&Bt[(size_t)(bn + row) * Kp + k0 + kc];
            *(uint4*)&Bs[row][kc] = v;
        }
        // ---- stage A ----
        if constexpr (ASRC == 0) {
#pragma unroll
            for (int i = 0; i < 8; ++i) {
                int c = tid + i * 256;
                int row = c >> 4, kc = (c & 15) * 4;
                float4 v = *(const float4*)&Af[(size_t)(bm + row) * K + k0 + kc];
                ushort4 b;
                b.x = f2bf(v.x); b.y = f2bf(v.y); b.z = f2bf(v.z); b.w = f2bf(v.w);
                *(ushort4*)&As[row][kc] = b;
            }
        } else if constexpr (ASRC == 1) {
#pragma unroll
            for (int i = 0; i < 8; ++i) {
                int c = tid + i * 256;
                int row = c >> 4, kc = (c & 15) * 4;
                float dv = dgeo[bm + row];
                ushort4 b;
                unsigned short* bp = (unsigned short*)&b;
#pragma unroll
                for (int j = 0; j < 4; ++j) {
                    int k = k0 + kc + j;
                    float f = 0.f;
                    if (k < K) {
                        float t = dv - (float)k * (10.0f / 49.0f);
                        f = __expf(-12.005f * t * t);
                    }
                    bp[j] = f2bf(f);
                }
                *(ushort4*)&As[row][kc] = b;
            }
        } else {
#pragma unroll
            for (int i = 0; i < 4; ++i) {
                int c = tid + i * 256;
                int row = c >> 3, kc = (c & 7) * 8;
                uint4 v = *(const uint4*)&Ab[(size_t)(bm + row) * K + k0 + kc];
                *(uint4*)&As[row][kc] = v;
            }
        }
        __syncthreads();
        // ---- MFMA ----
#pragma unroll
        for (int kk = 0; kk < 64; kk += 32) {
            s16x8 af[4], bf[4];
#pragma unroll
            for (int mi = 0; mi < 4; ++mi)
                af[mi] = *(const s16x8*)&As[wm * 64 + mi * 16 + rsel][kk + ksel];
#pragma unroll
            for (int ni = 0; ni < 4; ++ni)
                bf[ni] = *(const s16x8*)&Bs[wn * 64 + ni * 16 + rsel][kk + ksel];
#pragma unroll
            for (int mi = 0; mi < 4; ++mi)
#pragma unroll
                for (int ni = 0; ni < 4; ++ni)
                    acc[mi][ni] = __builtin_amdgcn_mfma_f32_16x16x32_bf16(
                        af[mi], bf[ni], acc[mi][ni], 0, 0, 0);
        }
        __syncthreads();
    }

    // ---- epilogue ----
#pragma unroll
    for (int mi = 0; mi < 4; ++mi) {
#pragma unroll
        for (int r = 0; r < 4; ++r) {
            int m = bm + wm * 64 + mi * 16 + ((lane >> 4) << 2) + r;
            int sn = 0, tn = 0; float cc = 0.f;
            if constexpr (EPI == 3) {
                sn = esrc[m]; tn = edst[m]; cc = aux[m];
            }
#pragma unroll
            for (int ni = 0; ni < 4; ++ni) {
                int n = bn + wn * 64 + ni * 16 + (lane & 15);
                float v = acc[mi][ni][r];
                if (bias) v += bias[n];
                if constexpr (EPI == 0) {
                    Cf[(size_t)m * ldc + n] = v;
                } else if constexpr (EPI == 1) {
                    Cf[(size_t)m * ldc + n] = fmaxf(v, 0.f);
                } else if constexpr (EPI == 2) {
                    Cb[(size_t)m * ldc + n] = f2bf(fmaxf(v, 0.f));
                } else if constexpr (EPI == 3) {
                    float w = v * cc;
                    atomicAdd(&hagg[(size_t)tn * F + n],
                              w * cfh[(size_t)sn * F + n]);
                } else {  // EPI == 4
                    size_t ix = (size_t)m * ldc + n;
                    float o = Cf[ix] + v + aux[(size_t)(m & (NG - 1)) * ldc + n];
                    Cf[ix] = fmaxf(o, 0.f);
                }
            }
        }
    }
}

// ---------------- launch ----------------
extern "C" void kernel_launch(void* const* d_in, const int* in_sizes, int n_in,
                              void* d_out, int out_size, void* d_ws, size_t ws_size,
                              hipStream_t stream)
{
    (void)in_sizes; (void)n_in; (void)out_size; (void)ws_size;
    const float* pos       = (const float*)d_in[0];
    const float* atom_emb  = (const float*)d_in[1];
    const float* vn_emb    = (const float*)d_in[2];
    const float* cf_lin1   = (const float*)d_in[3];
    const float* cf_mlp_w1 = (const float*)d_in[4];
    const float* cf_mlp_b1 = (const float*)d_in[5];
    const float* cf_mlp_w2 = (const float*)d_in[6];
    const float* cf_mlp_b2 = (const float*)d_in[7];
    const float* cf_lin2   = (const float*)d_in[8];
    const float* cf_lin2_b = (const float*)d_in[9];
    const float* lin_w     = (const float*)d_in[10];
    const float* lin_b     = (const float*)d_in[11];
    const float* bond_emb  = (const float*)d_in[12];
    const float* gin_eps   = (const float*)d_in[13];
    const float* gin_w1    = (const float*)d_in[14];
    const float* gin_b1    = (const float*)d_in[15];
    const float* gin_g1    = (const float*)d_in[16];
    const float* gin_be1   = (const float*)d_in[17];
    const float* gin_w2    = (const float*)d_in[18];
    const float* gin_b2    = (const float*)d_in[19];
    const float* bn_g      = (const float*)d_in[20];
    const float* bn_b      = (const float*)d_in[21];
    const float* vn_w1     = (const float*)d_in[22];
    const float* vn_b1     = (const float*)d_in[23];
    const float* vn_w2     = (const float*)d_in[24];
    const float* vn_b2     = (const float*)d_in[25];
    const float* out_w1    = (const float*)d_in[26];
    const float* out_b1    = (const float*)d_in[27];
    const float* out_w2    = (const float*)d_in[28];
    const float* out_b2    = (const float*)d_in[29];
    const int* x_atom      = (const int*)d_in[30];
    const int* pos_batch   = (const int*)d_in[32];
    const int* ei_conf     = (const int*)d_in[34];
    const int* ei_graph    = (const int*)d_in[35];
    const int* attr_graph  = (const int*)d_in[36];
    float* out = (float*)d_out;
    float* ws  = (float*)d_ws;

    size_t o = 0;
    float* X    = ws + o; o += (size_t)NC * H;
    float* CFH  = ws + o; o += (size_t)NC * F;
    float* HAGG = ws + o; o += (size_t)NC * F;
    float* Dd   = ws + o; o += EC;
    float* CCUT = ws + o; o += EC;
    float* XA   = ws + o; o += (size_t)NG * H;
    float* AGG  = ws + o; o += (size_t)NG * H;
    float* Z1   = ws + o; o += (size_t)NG * H;
    float* Z2   = ws + o; o += (size_t)NG * H;
    float* VN   = ws + o; o += (size_t)NCONF * H;
    float* TMP  = ws + o; o += (size_t)NCONF * H;
    float* TMP2 = ws + o; o += (size_t)NCONF * H;
    float* XM   = ws + o; o += (size_t)NMOL * H;
    float* Y1   = ws + o; o += (size_t)NMOL * H;
    float* STATS= ws + o; o += 512;
    // bf16 region: T1 [CE,128] aliases H2 [NC,256] (both 16.78M ushorts)
    unsigned short* BIGBF = (unsigned short*)(ws + o); o += (size_t)NC * H / 2;
    unsigned short* T1 = BIGBF;
    unsigned short* H2 = BIGBF;
    // transposed bf16 weights
    unsigned short* WT = (unsigned short*)(ws + o);
    size_t wo = 0;
    unsigned short* lin1t = WT + wo; wo += (size_t)NLAYERS * 128 * 256;
    unsigned short* w1t   = WT + wo; wo += (size_t)NLAYERS * 128 * 64;
    unsigned short* w2t   = WT + wo; wo += (size_t)NLAYERS * 128 * 128;
    unsigned short* lin2t = WT + wo; wo += (size_t)NLAYERS * 256 * 128;
    unsigned short* linwt = WT + wo; wo += (size_t)NLAYERS * 256 * 256;
    unsigned short* g1t   = WT + wo; wo += (size_t)NLAYERS * 256 * 256;
    unsigned short* g2t   = WT + wo; wo += (size_t)NLAYERS * 256 * 256;
    unsigned short* vn1t  = WT + wo; wo += 256 * 256;
    unsigned short* vn2t  = WT + wo; wo += 256 * 256;
    unsigned short* ow1t  = WT + wo; wo += 256 * 256;

    // ---- weight prep ----
    for (int i = 0; i < NLAYERS; ++i) {
        k_wt<<<128, 256, 0, stream>>>(cf_lin1 + (size_t)i * H * F,   lin1t + (size_t)i * 128 * 256, 256, 128, 256);
        k_wt<<<128, 256, 0, stream>>>(cf_mlp_w1 + (size_t)i * NGAUSS * F, w1t + (size_t)i * 128 * 64, NGAUSS, 128, 64);
        k_wt<<<128, 256, 0, stream>>>(cf_mlp_w2 + (size_t)i * F * F, w2t + (size_t)i * 128 * 128, 128, 128, 128);
        k_wt<<<256, 256, 0, stream>>>(cf_lin2 + (size_t)i * F * H,   lin2t + (size_t)i * 256 * 128, 128, 256, 128);
        k_wt<<<256, 256, 0, stream>>>(lin_w + (size_t)i * H * H,     linwt + (size_t)i * 256 * 256, 256, 256, 256);
        k_wt<<<256, 256, 0, stream>>>(gin_w1 + (size_t)i * H * H,    g1t + (size_t)i * 256 * 256, 256, 256, 256);
        k_wt<<<256, 256, 0, stream>>>(gin_w2 + (size_t)i * H * H,    g2t + (size_t)i * 256 * 256, 256, 256, 256);
    }
    k_wt<<<256, 256, 0, stream>>>(vn_w1, vn1t, 256, 256, 256);
    k_wt<<<256, 256, 0, stream>>>(vn_w2, vn2t, 256, 256, 256);
    k_wt<<<256, 256, 0, stream>>>(out_w1, ow1t, 256, 256, 256);

    k_init_x<<<NC, 256, 0, stream>>>(atom_emb, x_atom, X);
    k_vninit<<<NCONF, 256, 0, stream>>>(vn_emb, VN);
    k_geom<<<EC / 256, 256, 0, stream>>>(pos, ei_conf, Dd, CCUT);

    for (int i = 0; i < NLAYERS; ++i) {
        k_addvn<<<NC, 256, 0, stream>>>(X, VN, pos_batch);
        if (i < NLAYERS - 1) {
            k_vn_tmp<<<NCONF, 256, 0, stream>>>(X, VN, TMP);
            mgemm<0, 1><<<dim3(2, NCONF / 128), 256, 0, stream>>>(
                TMP, 0, 0, vn1t, vn_b1, TMP2, 0, 256, 256, 256, 0, 0, 0, 0, 0);
            mgemm<0, 1><<<dim3(2, NCONF / 128), 256, 0, stream>>>(
                TMP2, 0, 0, vn2t, vn_b2, VN, 0, 256, 256, 256, 0, 0, 0, 0, 0);
        }
        // ---- CFConv ----
        mgemm<0, 0><<<dim3(1, NC / 128), 256, 0, stream>>>(
            X, 0, 0, lin1t + (size_t)i * 128 * 256, nullptr, CFH, 0,
            256, 256, 128, 0, 0, 0, 0, 0);
        hipMemsetAsync(HAGG, 0, (size_t)NC * F * sizeof(float), stream);
        for (int c = 0; c < EC / CE; ++c) {
            int e0 = c * CE;
            mgemm<1, 2><<<dim3(1, CE / 128), 256, 0, stream>>>(
                0, 0, Dd + e0, w1t + (size_t)i * 128 * 64, cf_mlp_b1 + i * F,
                0, T1, NGAUSS, 64, 128, 0, 0, 0, 0, 0);
            mgemm<2, 3><<<dim3(1, CE / 128), 256, 0, stream>>>(
                0, T1, 0, w2t + (size_t)i * 128 * 128, cf_mlp_b2 + i * F,
                0, 0, 128, 128, 0, CCUT + e0, ei_conf + e0, ei_conf + EC + e0,
                CFH, HAGG);
        }
        // ---- GIN (pre-update X) ----
        k_xa<<<NG, 256, 0, stream>>>(X, XA);
        hipMemsetAsync(AGG, 0, (size_t)NG * H * sizeof(float), stream);
        k_gin_scatter<<<EG, 256, 0, stream>>>(
            XA, bond_emb + (size_t)i * 3 * 8 * H, ei_graph, attr_graph, AGG);
        k_gin_pre<<<NG, 256, 0, stream>>>(XA, AGG, gin_eps + i);
        mgemm<0, 0><<<dim3(2, NG / 128), 256, 0, stream>>>(
            AGG, 0, 0, g1t + (size_t)i * 256 * 256, gin_b1 + i * H, Z1, 0,
            256, 256, 256, 0, 0, 0, 0, 0);
        hipMemsetAsync(STATS, 0, 2048, stream);
        k_bnstats<<<64, 256, 0, stream>>>(Z1, STATS);
        k_bnapply<true><<<NG, 256, 0, stream>>>(Z1, STATS, gin_g1 + i * H, gin_be1 + i * H);
        mgemm<0, 0><<<dim3(2, NG / 128), 256, 0, stream>>>(
            Z1, 0, 0, g2t + (size_t)i * 256 * 256, gin_b2 + i * H, Z2, 0,
            256, 256, 256, 0, 0, 0, 0, 0);
        hipMemsetAsync(STATS, 0, 2048, stream);
        k_bnstats<<<64, 256, 0, stream>>>(Z2, STATS);
        k_bnapply<false><<<NG, 256, 0, stream>>>(Z2, STATS, bn_g + i * H, bn_b + i * H);
        // ---- combine ----
        mgemm<0, 2><<<dim3(2, NC / 128), 256, 0, stream>>>(
            HAGG, 0, 0, lin2t + (size_t)i * 256 * 128, cf_lin2_b + i * H,
            0, H2, 128, 128, 256, 0, 0, 0, 0, 0);
        mgemm<2, 4><<<dim3(2, NC / 128), 256, 0, stream>>>(
            0, H2, 0, linwt + (size_t)i * 256 * 256, lin_b + i * H, X, 0,
            256, 256, 256, Z2, 0, 0, 0, 0);
    }

    k_molmax<<<NMOL, 256, 0, stream>>>(X, XM);
    mgemm<0, 1><<<dim3(2, NMOL / 128), 256, 0, stream>>>(
        XM, 0, 0, ow1t, out_b1, Y1, 0, 256, 256, 256, 0, 0, 0, 0, 0);
    k_head<<<NMOL, 256, 0, stream>>>(Y1, out_w2, out_b2, out);
}

// Round 3
// 3052.729 us; speedup vs baseline: 2.9847x; 1.1486x over previous
//
#include <hip/hip_runtime.h>
#include <math.h>

#define H 256
#define F 128
#define NLAYERS 4
#define NG 8192
#define NC 65536
#define EC 524288
#define EG 32768
#define NCONF 4096
#define NMOL 512
#define NGAUSS 50
#define CE 131072   // edge chunk (EC/CE = 4 chunks)

using s16x8 = __attribute__((ext_vector_type(8))) short;
using f32x4 = __attribute__((ext_vector_type(4))) float;

static __device__ __forceinline__ unsigned short f2bf(float f) {
    unsigned int u = __float_as_uint(f);
    u += 0x7fffu + ((u >> 16) & 1u);   // RNE (finite values)
    return (unsigned short)(u >> 16);
}
static __device__ __forceinline__ float bf2f(unsigned short b) {
    return __uint_as_float(((unsigned int)b) << 16);
}

// ---------------- elementwise / gather kernels ----------------

__global__ __launch_bounds__(256) void k_init_x(const float* __restrict__ atom_emb,
    const int* __restrict__ x_atom, float* __restrict__ x)
{
    int i = blockIdx.x, h = threadIdx.x;
    int g = i & (NG - 1);
    float s = 0.f;
#pragma unroll
    for (int f = 0; f < 9; ++f) {
        int a = x_atom[g * 9 + f];
        s += atom_emb[(f * 64 + a) * H + h];
    }
    x[(size_t)i * H + h] = s;
}

__global__ __launch_bounds__(256) void k_vninit(const float* __restrict__ vn_emb,
                                                float* __restrict__ vn)
{
    vn[(size_t)blockIdx.x * H + threadIdx.x] = vn_emb[threadIdx.x];
}

__global__ __launch_bounds__(256) void k_addvn(float* __restrict__ x,
    const float* __restrict__ vn, const int* __restrict__ pos_batch)
{
    int i = blockIdx.x;
    int c = pos_batch[i];
    x[(size_t)i * H + threadIdx.x] += vn[(size_t)c * H + threadIdx.x];
}

// tmp[c] = vn[c] + sum over 16 nodes of conformer c (c = m*8+r -> nodes r*NG+16m+t)
__global__ __launch_bounds__(256) void k_vn_tmp(const float* __restrict__ x,
    const float* __restrict__ vn, float* __restrict__ tmp)
{
    int c = blockIdx.x, h = threadIdx.x;
    int m = c >> 3, r = c & 7;
    size_t base = ((size_t)r * NG + m * 16) * H + h;
    float s = vn[(size_t)c * H + h];
#pragma unroll 4
    for (int t = 0; t < 16; ++t) s += x[base + (size_t)t * H];
    tmp[(size_t)c * H + h] = s;
}

__global__ __launch_bounds__(256) void k_xa(const float* __restrict__ x,
                                            float* __restrict__ xa)
{
    int g = blockIdx.x, h = threadIdx.x;
    size_t off = (size_t)g * H + h;
    float m = x[off];
#pragma unroll
    for (int r = 1; r < 8; ++r) m = fmaxf(m, x[off + (size_t)r * NG * H]);
    xa[off] = m;
}

__global__ __launch_bounds__(256) void k_bnstats(const float* __restrict__ z,
                                                 float* __restrict__ stats)
{
    int h = threadIdx.x;
    size_t r0 = (size_t)blockIdx.x * (NG / 64);
    float s = 0.f, q = 0.f;
    for (int r = 0; r < NG / 64; ++r) {
        float v = z[(r0 + r) * H + h];
        s += v; q = fmaf(v, v, q);
    }
    atomicAdd(&stats[h], s);
    atomicAdd(&stats[H + h], q);
}

template <bool RELU>
__global__ __launch_bounds__(256) void k_bnapply(float* __restrict__ z,
    const float* __restrict__ stats, const float* __restrict__ gamma,
    const float* __restrict__ beta)
{
    size_t i = (size_t)blockIdx.x * 256 + threadIdx.x;
    int h = threadIdx.x;
    float mean = stats[h] * (1.0f / NG);
    float var = stats[H + h] * (1.0f / NG) - mean * mean;
    float v = (z[i] - mean) * rsqrtf(var + 1e-5f) * gamma[h] + beta[h];
    if (RELU) v = fmaxf(v, 0.f);
    z[i] = v;
}

__global__ __launch_bounds__(256) void k_molmax(const float* __restrict__ x,
                                                float* __restrict__ xm)
{
    int m = blockIdx.x, h = threadIdx.x;
    float best = -3.4e38f;
    for (int r = 0; r < 8; ++r) {
        size_t base = ((size_t)r * NG + m * 16) * H + h;
#pragma unroll 4
        for (int t = 0; t < 16; ++t) best = fmaxf(best, x[base + (size_t)t * H]);
    }
    xm[(size_t)m * H + h] = best;
}

__global__ __launch_bounds__(256) void k_head(const float* __restrict__ y1,
    const float* __restrict__ w2, const float* __restrict__ b2,
    float* __restrict__ out)
{
    __shared__ float red[256];
    int m = blockIdx.x, h = threadIdx.x;
    red[h] = y1[(size_t)m * H + h] * w2[h];
    __syncthreads();
    for (int s = 128; s > 0; s >>= 1) {
        if (h < s) red[h] += red[h + s];
        __syncthreads();
    }
    if (h == 0) out[m] = red[0] + b2[0];
}

// weight transpose+convert: Wt[n*Kp+k] = bf16(W[k*N+n]), zero-padded to Kp
__global__ __launch_bounds__(256) void k_wt(const float* __restrict__ W,
    unsigned short* __restrict__ Wt, int K, int N, int Kp)
{
    int n = blockIdx.x;
    for (int k = threadIdx.x; k < Kp; k += 256)
        Wt[(size_t)n * Kp + k] = (k < K) ? f2bf(W[(size_t)k * N + n]) : (unsigned short)0;
}

// ---------------- counting sort by destination ----------------

__global__ __launch_bounds__(256) void k_hist(const int* __restrict__ dst,
                                              int* __restrict__ cnt, int ne)
{
    int e = blockIdx.x * 256 + threadIdx.x;
    if (e < ne) atomicAdd(&cnt[dst[e]], 1);
}

__global__ __launch_bounds__(256) void k_scan1(const int* __restrict__ cnt,
    int* __restrict__ part, int* __restrict__ bsum)
{
    __shared__ int sh[256];
    int t = threadIdx.x, idx = blockIdx.x * 256 + t;
    int v = cnt[idx];
    sh[t] = v; __syncthreads();
    for (int s = 1; s < 256; s <<= 1) {
        int add = (t >= s) ? sh[t - s] : 0;
        __syncthreads();
        sh[t] += add;
        __syncthreads();
    }
    part[idx] = sh[t] - v;             // block-local exclusive
    if (t == 255) bsum[blockIdx.x] = sh[255];
}

__global__ __launch_bounds__(256) void k_scan2(int* __restrict__ bsum, int nb)
{
    __shared__ int sh[256];
    int t = threadIdx.x;
    int v = (t < nb) ? bsum[t] : 0;
    sh[t] = v; __syncthreads();
    for (int s = 1; s < 256; s <<= 1) {
        int add = (t >= s) ? sh[t - s] : 0;
        __syncthreads();
        sh[t] += add;
        __syncthreads();
    }
    if (t < nb) bsum[t] = sh[t] - v;   // exclusive block offsets
}

__global__ __launch_bounds__(256) void k_scan3(int* __restrict__ part,
    const int* __restrict__ bsum, int* __restrict__ cursor, int nbins, int total)
{
    int idx = blockIdx.x * 256 + threadIdx.x;
    int v = part[idx] + bsum[blockIdx.x];
    part[idx] = v;
    cursor[idx] = v;
    if (idx == 0) part[nbins] = total;
}

// conformer edges: compute geometry, write into dst-sorted order
__global__ __launch_bounds__(256) void k_cperm(const float* __restrict__ pos,
    const int* __restrict__ ei, int* __restrict__ cursor,
    int* __restrict__ psrc, float* __restrict__ pd, float* __restrict__ pccut)
{
    int e = blockIdx.x * 256 + threadIdx.x;
    int s = ei[e], t = ei[EC + e];
    float dx = pos[s * 3 + 0] - pos[t * 3 + 0];
    float dy = pos[s * 3 + 1] - pos[t * 3 + 1];
    float dz = pos[s * 3 + 2] - pos[t * 3 + 2];
    float dd = sqrtf(dx * dx + dy * dy + dz * dz);
    int p = atomicAdd(&cursor[t], 1);
    psrc[p] = s;
    pd[p] = dd;
    pccut[p] = 0.5f * (cosf(dd * 0.314159265358979f) + 1.0f);
}

// molecular-graph edges: pack attr, write into dst-sorted order
__global__ __launch_bounds__(256) void k_gperm(const int* __restrict__ ei,
    const int* __restrict__ attr, int* __restrict__ cursor,
    int* __restrict__ pgsrc, int* __restrict__ pattr)
{
    int e = blockIdx.x * 256 + threadIdx.x;
    int s = ei[e], t = ei[EG + e];
    int p = atomicAdd(&cursor[t], 1);
    pgsrc[p] = s;
    pattr[p] = attr[e * 3] | (attr[e * 3 + 1] << 4) | (attr[e * 3 + 2] << 8);
}

// ---------------- gather-based aggregations (no atomics) ----------------

// HAGG[n][c] += sum_{e in rowptr[n..n+1) ∩ [e0,e1)} WE[e-e0][c] * cfh[psrc[e]][c]
__global__ __launch_bounds__(256) void k_cf_agg(const unsigned short* __restrict__ WE,
    const int* __restrict__ rowptr, const int* __restrict__ psrc,
    const float* __restrict__ cfh, float* __restrict__ hagg, int e0, int e1)
{
    int slot = threadIdx.x >> 7;
    int c = threadIdx.x & 127;
    int n = blockIdx.x * 2 + slot;
    int lo = rowptr[n], hi = rowptr[n + 1];
    if (lo < e0) lo = e0;
    if (hi > e1) hi = e1;
    if (lo >= hi) return;
    float acc = 0.f;
    for (int e = lo; e < hi; ++e) {
        int s = psrc[e];
        float w = bf2f(WE[(size_t)(e - e0) * F + c]);
        acc = fmaf(w, cfh[(size_t)s * F + c], acc);
    }
    hagg[(size_t)n * F + c] += acc;
}

// AGG[g] = (1+eps)*xa[g] + sum_{e in growptr[g..g+1)} relu(xa[pgsrc[e]] + bond_sum)
__global__ __launch_bounds__(256) void k_gin_agg(const float* __restrict__ xa,
    const float* __restrict__ bond, const int* __restrict__ growptr,
    const int* __restrict__ pgsrc, const int* __restrict__ pattr,
    const float* __restrict__ eps_p, float* __restrict__ agg)
{
    int g = blockIdx.x, h = threadIdx.x;
    int lo = growptr[g], hi = growptr[g + 1];
    float acc = 0.f;
    for (int e = lo; e < hi; ++e) {
        int s = pgsrc[e], a = pattr[e];
        float v = xa[(size_t)s * H + h]
                + bond[(a & 15) * H + h]
                + bond[(8 + ((a >> 4) & 15)) * H + h]
                + bond[(16 + (a >> 8)) * H + h];
        acc += fmaxf(v, 0.f);
    }
    agg[(size_t)g * H + h] = (1.0f + eps_p[0]) * xa[(size_t)g * H + h] + acc;
}

// ---------------- MFMA GEMM ----------------
// C[M,N] = A[M,K] @ B[K,N], tile 128x128, BK=64, 4 waves (2x2 of 64x64).
// ASRC: 0 = f32 A (convert on stage), 1 = gauss-generated from dgeo, 2 = bf16 A
// EPI:  0 = Cf=v+bias, 1 = relu, 2 = relu -> bf16 Cb,
//       4 = Cf[m][n] = relu(Cf[m][n] + v + bias + aux[(m&8191)*ldc+n])
//       5 = Cb[m][n] = bf16((v+bias)*aux[m])
template<int ASRC, int EPI>
__global__ __launch_bounds__(256) void mgemm(
    const float* __restrict__ Af, const unsigned short* __restrict__ Ab,
    const float* __restrict__ dgeo,
    const unsigned short* __restrict__ Bt,
    const float* __restrict__ bias,
    float* __restrict__ Cf, unsigned short* __restrict__ Cb,
    int K, int Kp, int ldc,
    const float* __restrict__ aux)
{
    __shared__ unsigned short As[128][72];
    __shared__ unsigned short Bs[128][72];
    const int tid = threadIdx.x;
    const int bm = blockIdx.y * 128;
    const int bn = blockIdx.x * 128;
    const int lane = tid & 63;
    const int wid = tid >> 6;
    const int wm = wid >> 1, wn = wid & 1;
    const int rsel = lane & 15, ksel = (lane >> 4) * 8;

    f32x4 acc[4][4];
#pragma unroll
    for (int a = 0; a < 4; ++a)
#pragma unroll
        for (int b = 0; b < 4; ++b) acc[a][b] = (f32x4){0.f, 0.f, 0.f, 0.f};

    for (int k0 = 0; k0 < Kp; k0 += 64) {
        // ---- stage B: Bt[N][Kp] bf16, 16B chunks ----
#pragma unroll
        for (int i = 0; i < 4; ++i) {
            int c = tid + i * 256;
            int row = c >> 3, kc = (c & 7) * 8;
            uint4 v = *(const uint4*)&Bt[(size_t)(bn + row) * Kp + k0 + kc];
            *(uint4*)&Bs[row][kc] = v;
        }
        // ---- stage A ----
        if constexpr (ASRC == 0) {
#pragma unroll
            for (int i = 0; i < 8; ++i) {
                int c = tid + i * 256;
                int row = c >> 4, kc = (c & 15) * 4;
                float4 v = *(const float4*)&Af[(size_t)(bm + row) * K + k0 + kc];
                ushort4 b;
                b.x = f2bf(v.x); b.y = f2bf(v.y); b.z = f2bf(v.z); b.w = f2bf(v.w);
                *(ushort4*)&As[row][kc] = b;
            }
        } else if constexpr (ASRC == 1) {
#pragma unroll
            for (int i = 0; i < 8; ++i) {
                int c = tid + i * 256;
                int row = c >> 4, kc = (c & 15) * 4;
                float dv = dgeo[bm + row];
                ushort4 b;
                unsigned short* bp = (unsigned short*)&b;
#pragma unroll
                for (int j = 0; j < 4; ++j) {
                    int k = k0 + kc + j;
                    float f = 0.f;
                    if (k < K) {
                        float t = dv - (float)k * (10.0f / 49.0f);
                        f = __expf(-12.005f * t * t);
                    }
                    bp[j] = f2bf(f);
                }
                *(ushort4*)&As[row][kc] = b;
            }
        } else {
#pragma unroll
            for (int i = 0; i < 4; ++i) {
                int c = tid + i * 256;
                int row = c >> 3, kc = (c & 7) * 8;
                uint4 v = *(const uint4*)&Ab[(size_t)(bm + row) * K + k0 + kc];
                *(uint4*)&As[row][kc] = v;
            }
        }
        __syncthreads();
        // ---- MFMA ----
#pragma unroll
        for (int kk = 0; kk < 64; kk += 32) {
            s16x8 af[4], bf[4];
#pragma unroll
            for (int mi = 0; mi < 4; ++mi)
                af[mi] = *(const s16x8*)&As[wm * 64 + mi * 16 + rsel][kk + ksel];
#pragma unroll
            for (int ni = 0; ni < 4; ++ni)
                bf[ni] = *(const s16x8*)&Bs[wn * 64 + ni * 16 + rsel][kk + ksel];
#pragma unroll
            for (int mi = 0; mi < 4; ++mi)
#pragma unroll
                for (int ni = 0; ni < 4; ++ni)
                    acc[mi][ni] = __builtin_amdgcn_mfma_f32_16x16x32_bf16(
                        af[mi], bf[ni], acc[mi][ni], 0, 0, 0);
        }
        __syncthreads();
    }

    // ---- epilogue ----
#pragma unroll
    for (int mi = 0; mi < 4; ++mi) {
#pragma unroll
        for (int r = 0; r < 4; ++r) {
            int m = bm + wm * 64 + mi * 16 + ((lane >> 4) << 2) + r;
            float cc = 0.f;
            if constexpr (EPI == 5) cc = aux[m];
#pragma unroll
            for (int ni = 0; ni < 4; ++ni) {
                int n = bn + wn * 64 + ni * 16 + (lane & 15);
                float v = acc[mi][ni][r];
                if (bias) v += bias[n];
                if constexpr (EPI == 0) {
                    Cf[(size_t)m * ldc + n] = v;
                } else if constexpr (EPI == 1) {
                    Cf[(size_t)m * ldc + n] = fmaxf(v, 0.f);
                } else if constexpr (EPI == 2) {
                    Cb[(size_t)m * ldc + n] = f2bf(fmaxf(v, 0.f));
                } else if constexpr (EPI == 4) {
                    size_t ix = (size_t)m * ldc + n;
                    float o = Cf[ix] + v + aux[(size_t)(m & (NG - 1)) * ldc + n];
                    Cf[ix] = fmaxf(o, 0.f);
                } else {  // EPI == 5
                    Cb[(size_t)m * ldc + n] = f2bf(v * cc);
                }
            }
        }
    }
}

// ---------------- launch ----------------
extern "C" void kernel_launch(void* const* d_in, const int* in_sizes, int n_in,
                              void* d_out, int out_size, void* d_ws, size_t ws_size,
                              hipStream_t stream)
{
    (void)in_sizes; (void)n_in; (void)out_size; (void)ws_size;
    const float* pos       = (const float*)d_in[0];
    const float* atom_emb  = (const float*)d_in[1];
    const float* vn_emb    = (const float*)d_in[2];
    const float* cf_lin1   = (const float*)d_in[3];
    const float* cf_mlp_w1 = (const float*)d_in[4];
    const float* cf_mlp_b1 = (const float*)d_in[5];
    const float* cf_mlp_w2 = (const float*)d_in[6];
    const float* cf_mlp_b2 = (const float*)d_in[7];
    const float* cf_lin2   = (const float*)d_in[8];
    const float* cf_lin2_b = (const float*)d_in[9];
    const float* lin_w     = (const float*)d_in[10];
    const float* lin_b     = (const float*)d_in[11];
    const float* bond_emb  = (const float*)d_in[12];
    const float* gin_eps   = (const float*)d_in[13];
    const float* gin_w1    = (const float*)d_in[14];
    const float* gin_b1    = (const float*)d_in[15];
    const float* gin_g1    = (const float*)d_in[16];
    const float* gin_be1   = (const float*)d_in[17];
    const float* gin_w2    = (const float*)d_in[18];
    const float* gin_b2    = (const float*)d_in[19];
    const float* bn_g      = (const float*)d_in[20];
    const float* bn_b      = (const float*)d_in[21];
    const float* vn_w1     = (const float*)d_in[22];
    const float* vn_b1     = (const float*)d_in[23];
    const float* vn_w2     = (const float*)d_in[24];
    const float* vn_b2     = (const float*)d_in[25];
    const float* out_w1    = (const float*)d_in[26];
    const float* out_b1    = (const float*)d_in[27];
    const float* out_w2    = (const float*)d_in[28];
    const float* out_b2    = (const float*)d_in[29];
    const int* x_atom      = (const int*)d_in[30];
    const int* pos_batch   = (const int*)d_in[32];
    const int* ei_conf     = (const int*)d_in[34];
    const int* ei_graph    = (const int*)d_in[35];
    const int* attr_graph  = (const int*)d_in[36];
    float* out = (float*)d_out;
    float* ws  = (float*)d_ws;

    size_t o = 0;
    float* X    = ws + o; o += (size_t)NC * H;
    float* CFH  = ws + o; o += (size_t)NC * F;
    float* HAGG = ws + o; o += (size_t)NC * F;
    float* XA   = ws + o; o += (size_t)NG * H;
    float* AGG  = ws + o; o += (size_t)NG * H;
    float* Z1   = ws + o; o += (size_t)NG * H;
    float* Z2   = ws + o; o += (size_t)NG * H;
    float* VN   = ws + o; o += (size_t)NCONF * H;
    float* TMP  = ws + o; o += (size_t)NCONF * H;
    float* TMP2 = ws + o; o += (size_t)NCONF * H;
    float* XM   = ws + o; o += (size_t)NMOL * H;
    float* Y1   = ws + o; o += (size_t)NMOL * H;
    float* STATS= ws + o; o += 512;
    float* PD   = ws + o; o += EC;
    float* PCC  = ws + o; o += EC;
    // bf16 regions
    unsigned short* T1 = (unsigned short*)(ws + o); o += (size_t)CE * F / 2;   // also H2 [NC,256]
    unsigned short* H2 = T1;
    unsigned short* WE = (unsigned short*)(ws + o); o += (size_t)CE * F / 2;
    // int region
    int* PSRC   = (int*)(ws + o); o += EC;
    int* PGSRC  = (int*)(ws + o); o += EG;
    int* PATTR  = (int*)(ws + o); o += EG;
    int* CNT    = (int*)(ws + o); o += NC;
    int* ROWC   = (int*)(ws + o); o += NC + 64;
    int* CURC   = (int*)(ws + o); o += NC;
    int* ROWG   = (int*)(ws + o); o += NG + 64;
    int* CURG   = (int*)(ws + o); o += NG;
    int* BSUM   = (int*)(ws + o); o += 256;
    // transposed bf16 weights
    unsigned short* WT = (unsigned short*)(ws + o);
    size_t wo = 0;
    unsigned short* lin1t = WT + wo; wo += (size_t)NLAYERS * 128 * 256;
    unsigned short* w1t   = WT + wo; wo += (size_t)NLAYERS * 128 * 64;
    unsigned short* w2t   = WT + wo; wo += (size_t)NLAYERS * 128 * 128;
    unsigned short* lin2t = WT + wo; wo += (size_t)NLAYERS * 256 * 128;
    unsigned short* linwt = WT + wo; wo += (size_t)NLAYERS * 256 * 256;
    unsigned short* g1t   = WT + wo; wo += (size_t)NLAYERS * 256 * 256;
    unsigned short* g2t   = WT + wo; wo += (size_t)NLAYERS * 256 * 256;
    unsigned short* vn1t  = WT + wo; wo += 256 * 256;
    unsigned short* vn2t  = WT + wo; wo += 256 * 256;
    unsigned short* ow1t  = WT + wo; wo += 256 * 256;

    // ---- weight prep ----
    for (int i = 0; i < NLAYERS; ++i) {
        k_wt<<<128, 256, 0, stream>>>(cf_lin1 + (size_t)i * H * F,   lin1t + (size_t)i * 128 * 256, 256, 128, 256);
        k_wt<<<128, 256, 0, stream>>>(cf_mlp_w1 + (size_t)i * NGAUSS * F, w1t + (size_t)i * 128 * 64, NGAUSS, 128, 64);
        k_wt<<<128, 256, 0, stream>>>(cf_mlp_w2 + (size_t)i * F * F, w2t + (size_t)i * 128 * 128, 128, 128, 128);
        k_wt<<<256, 256, 0, stream>>>(cf_lin2 + (size_t)i * F * H,   lin2t + (size_t)i * 256 * 128, 128, 256, 128);
        k_wt<<<256, 256, 0, stream>>>(lin_w + (size_t)i * H * H,     linwt + (size_t)i * 256 * 256, 256, 256, 256);
        k_wt<<<256, 256, 0, stream>>>(gin_w1 + (size_t)i * H * H,    g1t + (size_t)i * 256 * 256, 256, 256, 256);
        k_wt<<<256, 256, 0, stream>>>(gin_w2 + (size_t)i * H * H,    g2t + (size_t)i * 256 * 256, 256, 256, 256);
    }
    k_wt<<<256, 256, 0, stream>>>(vn_w1, vn1t, 256, 256, 256);
    k_wt<<<256, 256, 0, stream>>>(vn_w2, vn2t, 256, 256, 256);
    k_wt<<<256, 256, 0, stream>>>(out_w1, ow1t, 256, 256, 256);

    // ---- dst-sort both edge lists (once; content is launch-invariant) ----
    hipMemsetAsync(CNT, 0, NC * sizeof(int), stream);
    k_hist<<<EC / 256, 256, 0, stream>>>(ei_conf + EC, CNT, EC);
    k_scan1<<<NC / 256, 256, 0, stream>>>(CNT, ROWC, BSUM);
    k_scan2<<<1, 256, 0, stream>>>(BSUM, NC / 256);
    k_scan3<<<NC / 256, 256, 0, stream>>>(ROWC, BSUM, CURC, NC, EC);
    k_cperm<<<EC / 256, 256, 0, stream>>>(pos, ei_conf, CURC, PSRC, PD, PCC);

    hipMemsetAsync(CNT, 0, NG * sizeof(int), stream);
    k_hist<<<EG / 256, 256, 0, stream>>>(ei_graph + EG, CNT, EG);
    k_scan1<<<NG / 256, 256, 0, stream>>>(CNT, ROWG, BSUM);
    k_scan2<<<1, 256, 0, stream>>>(BSUM, NG / 256);
    k_scan3<<<NG / 256, 256, 0, stream>>>(ROWG, BSUM, CURG, NG, EG);
    k_gperm<<<EG / 256, 256, 0, stream>>>(ei_graph, attr_graph, CURG, PGSRC, PATTR);

    k_init_x<<<NC, 256, 0, stream>>>(atom_emb, x_atom, X);
    k_vninit<<<NCONF, 256, 0, stream>>>(vn_emb, VN);

    for (int i = 0; i < NLAYERS; ++i) {
        k_addvn<<<NC, 256, 0, stream>>>(X, VN, pos_batch);
        if (i < NLAYERS - 1) {
            k_vn_tmp<<<NCONF, 256, 0, stream>>>(X, VN, TMP);
            mgemm<0, 1><<<dim3(2, NCONF / 128), 256, 0, stream>>>(
                TMP, 0, 0, vn1t, vn_b1, TMP2, 0, 256, 256, 256, 0);
            mgemm<0, 1><<<dim3(2, NCONF / 128), 256, 0, stream>>>(
                TMP2, 0, 0, vn2t, vn_b2, VN, 0, 256, 256, 256, 0);
        }
        // ---- CFConv ----
        mgemm<0, 0><<<dim3(1, NC / 128), 256, 0, stream>>>(
            X, 0, 0, lin1t + (size_t)i * 128 * 256, nullptr, CFH, 0,
            256, 256, 128, 0);
        hipMemsetAsync(HAGG, 0, (size_t)NC * F * sizeof(float), stream);
        for (int c = 0; c < EC / CE; ++c) {
            int e0 = c * CE;
            mgemm<1, 2><<<dim3(1, CE / 128), 256, 0, stream>>>(
                0, 0, PD + e0, w1t + (size_t)i * 128 * 64, cf_mlp_b1 + i * F,
                0, T1, NGAUSS, 64, 128, 0);
            mgemm<2, 5><<<dim3(1, CE / 128), 256, 0, stream>>>(
                0, T1, 0, w2t + (size_t)i * 128 * 128, cf_mlp_b2 + i * F,
                0, WE, 128, 128, 128, PCC + e0);
            k_cf_agg<<<NC / 2, 256, 0, stream>>>(WE, ROWC, PSRC, CFH, HAGG,
                                                 e0, e0 + CE);
        }
        // ---- GIN (pre-update X) ----
        k_xa<<<NG, 256, 0, stream>>>(X, XA);
        k_gin_agg<<<NG, 256, 0, stream>>>(
            XA, bond_emb + (size_t)i * 3 * 8 * H, ROWG, PGSRC, PATTR,
            gin_eps + i, AGG);
        mgemm<0, 0><<<dim3(2, NG / 128), 256, 0, stream>>>(
            AGG, 0, 0, g1t + (size_t)i * 256 * 256, gin_b1 + i * H, Z1, 0,
            256, 256, 256, 0);
        hipMemsetAsync(STATS, 0, 2048, stream);
        k_bnstats<<<64, 256, 0, stream>>>(Z1, STATS);
        k_bnapply<true><<<NG, 256, 0, stream>>>(Z1, STATS, gin_g1 + i * H, gin_be1 + i * H);
        mgemm<0, 0><<<dim3(2, NG / 128), 256, 0, stream>>>(
            Z1, 0, 0, g2t + (size_t)i * 256 * 256, gin_b2 + i * H, Z2, 0,
            256, 256, 256, 0);
        hipMemsetAsync(STATS, 0, 2048, stream);
        k_bnstats<<<64, 256, 0, stream>>>(Z2, STATS);
        k_bnapply<false><<<NG, 256, 0, stream>>>(Z2, STATS, bn_g + i * H, bn_b + i * H);
        // ---- combine ----
        mgemm<0, 2><<<dim3(2, NC / 128), 256, 0, stream>>>(
            HAGG, 0, 0, lin2t + (size_t)i * 256 * 128, cf_lin2_b + i * H,
            0, H2, 128, 128, 256, 0);
        mgemm<2, 4><<<dim3(2, NC / 128), 256, 0, stream>>>(
            0, H2, 0, linwt + (size_t)i * 256 * 256, lin_b + i * H, X, 0,
            256, 256, 256, Z2);
    }

    k_molmax<<<NMOL, 256, 0, stream>>>(X, XM);
    mgemm<0, 1><<<dim3(2, NMOL / 128), 256, 0, stream>>>(
        XM, 0, 0, ow1t, out_b1, Y1, 0, 256, 256, 256, 0);
    k_head<<<NMOL, 256, 0, stream>>>(Y1, out_w2, out_b2, out);
}

// Round 4
// 2025.510 us; speedup vs baseline: 4.4983x; 1.5071x over previous
//
#include <hip/hip_runtime.h>
#include <math.h>

#define H 256
#define F 128
#define NLAYERS 4
#define NG 8192
#define NC 65536
#define EC 524288
#define EG 32768
#define NCONF 4096
#define NMOL 512
#define NGAUSS 50
#define NTAB 8192
#define TABSTEP 0.001953125f   // 16 / 8192
#define INVSTEP 512.0f

using s16x8 = __attribute__((ext_vector_type(8))) short;
using f32x4 = __attribute__((ext_vector_type(4))) float;

static __device__ __forceinline__ unsigned short f2bf(float f) {
    unsigned int u = __float_as_uint(f);
    u += 0x7fffu + ((u >> 16) & 1u);   // RNE (finite values)
    return (unsigned short)(u >> 16);
}
static __device__ __forceinline__ float bf2f(unsigned short b) {
    return __uint_as_float(((unsigned int)b) << 16);
}

// ---------------- elementwise / gather kernels ----------------

__global__ __launch_bounds__(256) void k_init_x(const float* __restrict__ atom_emb,
    const int* __restrict__ x_atom, float* __restrict__ x)
{
    int i = blockIdx.x, h = threadIdx.x;
    int g = i & (NG - 1);
    float s = 0.f;
#pragma unroll
    for (int f = 0; f < 9; ++f) {
        int a = x_atom[g * 9 + f];
        s += atom_emb[(f * 64 + a) * H + h];
    }
    x[(size_t)i * H + h] = s;
}

__global__ __launch_bounds__(256) void k_vninit(const float* __restrict__ vn_emb,
                                                float* __restrict__ vn)
{
    vn[(size_t)blockIdx.x * H + threadIdx.x] = vn_emb[threadIdx.x];
}

__global__ __launch_bounds__(256) void k_addvn(float* __restrict__ x,
    const float* __restrict__ vn, const int* __restrict__ pos_batch)
{
    int i = blockIdx.x;
    int c = pos_batch[i];
    x[(size_t)i * H + threadIdx.x] += vn[(size_t)c * H + threadIdx.x];
}

// tmp[c] = vn[c] + sum over 16 nodes of conformer c (c = m*8+r -> nodes r*NG+16m+t)
__global__ __launch_bounds__(256) void k_vn_tmp(const float* __restrict__ x,
    const float* __restrict__ vn, float* __restrict__ tmp)
{
    int c = blockIdx.x, h = threadIdx.x;
    int m = c >> 3, r = c & 7;
    size_t base = ((size_t)r * NG + m * 16) * H + h;
    float s = vn[(size_t)c * H + h];
#pragma unroll 4
    for (int t = 0; t < 16; ++t) s += x[base + (size_t)t * H];
    tmp[(size_t)c * H + h] = s;
}

__global__ __launch_bounds__(256) void k_xa(const float* __restrict__ x,
                                            float* __restrict__ xa)
{
    int g = blockIdx.x, h = threadIdx.x;
    size_t off = (size_t)g * H + h;
    float m = x[off];
#pragma unroll
    for (int r = 1; r < 8; ++r) m = fmaxf(m, x[off + (size_t)r * NG * H]);
    xa[off] = m;
}

__global__ __launch_bounds__(256) void k_bnstats(const float* __restrict__ z,
                                                 float* __restrict__ stats)
{
    int h = threadIdx.x;
    size_t r0 = (size_t)blockIdx.x * (NG / 64);
    float s = 0.f, q = 0.f;
    for (int r = 0; r < NG / 64; ++r) {
        float v = z[(r0 + r) * H + h];
        s += v; q = fmaf(v, v, q);
    }
    atomicAdd(&stats[h], s);
    atomicAdd(&stats[H + h], q);
}

template <bool RELU>
__global__ __launch_bounds__(256) void k_bnapply(float* __restrict__ z,
    const float* __restrict__ stats, const float* __restrict__ gamma,
    const float* __restrict__ beta)
{
    size_t i = (size_t)blockIdx.x * 256 + threadIdx.x;
    int h = threadIdx.x;
    float mean = stats[h] * (1.0f / NG);
    float var = stats[H + h] * (1.0f / NG) - mean * mean;
    float v = (z[i] - mean) * rsqrtf(var + 1e-5f) * gamma[h] + beta[h];
    if (RELU) v = fmaxf(v, 0.f);
    z[i] = v;
}

__global__ __launch_bounds__(256) void k_molmax(const float* __restrict__ x,
                                                float* __restrict__ xm)
{
    int m = blockIdx.x, h = threadIdx.x;
    float best = -3.4e38f;
    for (int r = 0; r < 8; ++r) {
        size_t base = ((size_t)r * NG + m * 16) * H + h;
#pragma unroll 4
        for (int t = 0; t < 16; ++t) best = fmaxf(best, x[base + (size_t)t * H]);
    }
    xm[(size_t)m * H + h] = best;
}

__global__ __launch_bounds__(256) void k_head(const float* __restrict__ y1,
    const float* __restrict__ w2, const float* __restrict__ b2,
    float* __restrict__ out)
{
    __shared__ float red[256];
    int m = blockIdx.x, h = threadIdx.x;
    red[h] = y1[(size_t)m * H + h] * w2[h];
    __syncthreads();
    for (int s = 128; s > 0; s >>= 1) {
        if (h < s) red[h] += red[h + s];
        __syncthreads();
    }
    if (h == 0) out[m] = red[0] + b2[0];
}

// weight transpose+convert: Wt[n*Kp+k] = bf16(W[k*N+n]), zero-padded to Kp
__global__ __launch_bounds__(256) void k_wt(const float* __restrict__ W,
    unsigned short* __restrict__ Wt, int K, int N, int Kp)
{
    int n = blockIdx.x;
    for (int k = threadIdx.x; k < Kp; k += 256)
        Wt[(size_t)n * Kp + k] = (k < K) ? f2bf(W[(size_t)k * N + n]) : (unsigned short)0;
}

// ---------------- counting sort by destination ----------------

__global__ __launch_bounds__(256) void k_hist(const int* __restrict__ dst,
                                              int* __restrict__ cnt, int ne)
{
    int e = blockIdx.x * 256 + threadIdx.x;
    if (e < ne) atomicAdd(&cnt[dst[e]], 1);
}

__global__ __launch_bounds__(256) void k_scan1(const int* __restrict__ cnt,
    int* __restrict__ part, int* __restrict__ bsum)
{
    __shared__ int sh[256];
    int t = threadIdx.x, idx = blockIdx.x * 256 + t;
    int v = cnt[idx];
    sh[t] = v; __syncthreads();
    for (int s = 1; s < 256; s <<= 1) {
        int add = (t >= s) ? sh[t - s] : 0;
        __syncthreads();
        sh[t] += add;
        __syncthreads();
    }
    part[idx] = sh[t] - v;             // block-local exclusive
    if (t == 255) bsum[blockIdx.x] = sh[255];
}

__global__ __launch_bounds__(256) void k_scan2(int* __restrict__ bsum, int nb)
{
    __shared__ int sh[256];
    int t = threadIdx.x;
    int v = (t < nb) ? bsum[t] : 0;
    sh[t] = v; __syncthreads();
    for (int s = 1; s < 256; s <<= 1) {
        int add = (t >= s) ? sh[t - s] : 0;
        __syncthreads();
        sh[t] += add;
        __syncthreads();
    }
    if (t < nb) bsum[t] = sh[t] - v;   // exclusive block offsets
}

__global__ __launch_bounds__(256) void k_scan3(int* __restrict__ part,
    const int* __restrict__ bsum, int* __restrict__ cursor, int nbins, int total)
{
    int idx = blockIdx.x * 256 + threadIdx.x;
    int v = part[idx] + bsum[blockIdx.x];
    part[idx] = v;
    cursor[idx] = v;
    if (idx == 0) part[nbins] = total;
}

// conformer edges: compute geometry, write into dst-sorted order
__global__ __launch_bounds__(256) void k_cperm(const float* __restrict__ pos,
    const int* __restrict__ ei, int* __restrict__ cursor,
    int* __restrict__ psrc, float* __restrict__ pd, float* __restrict__ pccut)
{
    int e = blockIdx.x * 256 + threadIdx.x;
    int s = ei[e], t = ei[EC + e];
    float dx = pos[s * 3 + 0] - pos[t * 3 + 0];
    float dy = pos[s * 3 + 1] - pos[t * 3 + 1];
    float dz = pos[s * 3 + 2] - pos[t * 3 + 2];
    float dd = sqrtf(dx * dx + dy * dy + dz * dz);
    int p = atomicAdd(&cursor[t], 1);
    psrc[p] = s;
    pd[p] = dd;
    pccut[p] = 0.5f * (cosf(dd * 0.314159265358979f) + 1.0f);
}

// molecular-graph edges: pack attr, write into dst-sorted order
__global__ __launch_bounds__(256) void k_gperm(const int* __restrict__ ei,
    const int* __restrict__ attr, int* __restrict__ cursor,
    int* __restrict__ pgsrc, int* __restrict__ pattr)
{
    int e = blockIdx.x * 256 + threadIdx.x;
    int s = ei[e], t = ei[EG + e];
    int p = atomicAdd(&cursor[t], 1);
    pgsrc[p] = s;
    pattr[p] = attr[e * 3] | (attr[e * 3 + 1] << 4) | (attr[e * 3 + 2] << 8);
}

// ---------------- gather-based aggregations (no atomics) ----------------

// HAGG[n][c] = sum_{e in rowptr[n..n+1)} lerp(TAB, d[e])[c] * ccut[e] * cfh[psrc[e]][c]
__global__ __launch_bounds__(256) void k_cf_agg(const unsigned short* __restrict__ tab,
    const int* __restrict__ rowptr, const int* __restrict__ psrc,
    const float* __restrict__ pd, const float* __restrict__ pcc,
    const unsigned short* __restrict__ cfh, float* __restrict__ hagg)
{
    int slot = threadIdx.x >> 7;
    int c = threadIdx.x & 127;
    int n = blockIdx.x * 2 + slot;
    int lo = rowptr[n], hi = rowptr[n + 1];
    float acc = 0.f;
    for (int e = lo; e < hi; ++e) {
        int s = psrc[e];
        float d = pd[e], cc = pcc[e];
        float u = fminf(d * INVSTEP, (float)(NTAB - 1));
        int it = (int)u;
        if (it > NTAB - 2) it = NTAB - 2;
        float fr = u - (float)it;
        float t0 = bf2f(tab[(size_t)it * F + c]);
        float t1 = bf2f(tab[(size_t)(it + 1) * F + c]);
        float w = (t0 + fr * (t1 - t0)) * cc;
        acc = fmaf(w, bf2f(cfh[(size_t)s * F + c]), acc);
    }
    hagg[(size_t)n * F + c] = acc;
}

// AGG[g] = (1+eps)*xa[g] + sum_{e in growptr[g..g+1)} relu(xa[pgsrc[e]] + bond_sum)
__global__ __launch_bounds__(256) void k_gin_agg(const float* __restrict__ xa,
    const float* __restrict__ bond, const int* __restrict__ growptr,
    const int* __restrict__ pgsrc, const int* __restrict__ pattr,
    const float* __restrict__ eps_p, float* __restrict__ agg)
{
    int g = blockIdx.x, h = threadIdx.x;
    int lo = growptr[g], hi = growptr[g + 1];
    float acc = 0.f;
    for (int e = lo; e < hi; ++e) {
        int s = pgsrc[e], a = pattr[e];
        float v = xa[(size_t)s * H + h]
                + bond[(a & 15) * H + h]
                + bond[(8 + ((a >> 4) & 15)) * H + h]
                + bond[(16 + (a >> 8)) * H + h];
        acc += fmaxf(v, 0.f);
    }
    agg[(size_t)g * H + h] = (1.0f + eps_p[0]) * xa[(size_t)g * H + h] + acc;
}

// ---------------- MFMA GEMM ----------------
// C[M,N] = A[M,K] @ B[K,N], tile 128x128, BK=64, 4 waves (2x2 of 64x64).
// ASRC: 0 = f32 A (convert on stage), 2 = bf16 A, 3 = gauss row from table index
// EPI:  0 = Cf=v+bias, 1 = relu->Cf, 2 = relu->bf16 Cb, 6 = plain->bf16 Cb
//       4 = Cf[m][n] = relu(Cf[m][n] + v + bias + aux[(m&8191)*ldc+n])
template<int ASRC, int EPI>
__global__ __launch_bounds__(256) void mgemm(
    const float* __restrict__ Af, const unsigned short* __restrict__ Ab,
    const unsigned short* __restrict__ Bt,
    const float* __restrict__ bias,
    float* __restrict__ Cf, unsigned short* __restrict__ Cb,
    int K, int Kp, int ldc,
    const float* __restrict__ aux)
{
    __shared__ unsigned short As[128][72];
    __shared__ unsigned short Bs[128][72];
    const int tid = threadIdx.x;
    const int bm = blockIdx.y * 128;
    const int bn = blockIdx.x * 128;
    const int lane = tid & 63;
    const int wid = tid >> 6;
    const int wm = wid >> 1, wn = wid & 1;
    const int rsel = lane & 15, ksel = (lane >> 4) * 8;

    f32x4 acc[4][4];
#pragma unroll
    for (int a = 0; a < 4; ++a)
#pragma unroll
        for (int b = 0; b < 4; ++b) acc[a][b] = (f32x4){0.f, 0.f, 0.f, 0.f};

    for (int k0 = 0; k0 < Kp; k0 += 64) {
        // ---- stage B: Bt[N][Kp] bf16, 16B chunks ----
#pragma unroll
        for (int i = 0; i < 4; ++i) {
            int c = tid + i * 256;
            int row = c >> 3, kc = (c & 7) * 8;
            uint4 v = *(const uint4*)&Bt[(size_t)(bn + row) * Kp + k0 + kc];
            *(uint4*)&Bs[row][kc] = v;
        }
        // ---- stage A ----
        if constexpr (ASRC == 0) {
#pragma unroll
            for (int i = 0; i < 8; ++i) {
                int c = tid + i * 256;
                int row = c >> 4, kc = (c & 15) * 4;
                float4 v = *(const float4*)&Af[(size_t)(bm + row) * K + k0 + kc];
                ushort4 b;
                b.x = f2bf(v.x); b.y = f2bf(v.y); b.z = f2bf(v.z); b.w = f2bf(v.w);
                *(ushort4*)&As[row][kc] = b;
            }
        } else if constexpr (ASRC == 3) {
#pragma unroll
            for (int i = 0; i < 8; ++i) {
                int c = tid + i * 256;
                int row = c >> 4, kc = (c & 15) * 4;
                float dv = (float)(bm + row) * TABSTEP;
                ushort4 b;
                unsigned short* bp = (unsigned short*)&b;
#pragma unroll
                for (int j = 0; j < 4; ++j) {
                    int k = k0 + kc + j;
                    float f = 0.f;
                    if (k < K) {
                        float t = dv - (float)k * (10.0f / 49.0f);
                        f = __expf(-12.005f * t * t);
                    }
                    bp[j] = f2bf(f);
                }
                *(ushort4*)&As[row][kc] = b;
            }
        } else {
#pragma unroll
            for (int i = 0; i < 4; ++i) {
                int c = tid + i * 256;
                int row = c >> 3, kc = (c & 7) * 8;
                uint4 v = *(const uint4*)&Ab[(size_t)(bm + row) * K + k0 + kc];
                *(uint4*)&As[row][kc] = v;
            }
        }
        __syncthreads();
        // ---- MFMA ----
#pragma unroll
        for (int kk = 0; kk < 64; kk += 32) {
            s16x8 af[4], bf[4];
#pragma unroll
            for (int mi = 0; mi < 4; ++mi)
                af[mi] = *(const s16x8*)&As[wm * 64 + mi * 16 + rsel][kk + ksel];
#pragma unroll
            for (int ni = 0; ni < 4; ++ni)
                bf[ni] = *(const s16x8*)&Bs[wn * 64 + ni * 16 + rsel][kk + ksel];
#pragma unroll
            for (int mi = 0; mi < 4; ++mi)
#pragma unroll
                for (int ni = 0; ni < 4; ++ni)
                    acc[mi][ni] = __builtin_amdgcn_mfma_f32_16x16x32_bf16(
                        af[mi], bf[ni], acc[mi][ni], 0, 0, 0);
        }
        __syncthreads();
    }

    // ---- epilogue ----
#pragma unroll
    for (int mi = 0; mi < 4; ++mi) {
#pragma unroll
        for (int r = 0; r < 4; ++r) {
            int m = bm + wm * 64 + mi * 16 + ((lane >> 4) << 2) + r;
#pragma unroll
            for (int ni = 0; ni < 4; ++ni) {
                int n = bn + wn * 64 + ni * 16 + (lane & 15);
                float v = acc[mi][ni][r];
                if (bias) v += bias[n];
                if constexpr (EPI == 0) {
                    Cf[(size_t)m * ldc + n] = v;
                } else if constexpr (EPI == 1) {
                    Cf[(size_t)m * ldc + n] = fmaxf(v, 0.f);
                } else if constexpr (EPI == 2) {
                    Cb[(size_t)m * ldc + n] = f2bf(fmaxf(v, 0.f));
                } else if constexpr (EPI == 4) {
                    size_t ix = (size_t)m * ldc + n;
                    float o = Cf[ix] + v + aux[(size_t)(m & (NG - 1)) * ldc + n];
                    Cf[ix] = fmaxf(o, 0.f);
                } else {  // EPI == 6
                    Cb[(size_t)m * ldc + n] = f2bf(v);
                }
            }
        }
    }
}

// ---------------- launch ----------------
extern "C" void kernel_launch(void* const* d_in, const int* in_sizes, int n_in,
                              void* d_out, int out_size, void* d_ws, size_t ws_size,
                              hipStream_t stream)
{
    (void)in_sizes; (void)n_in; (void)out_size; (void)ws_size;
    const float* pos       = (const float*)d_in[0];
    const float* atom_emb  = (const float*)d_in[1];
    const float* vn_emb    = (const float*)d_in[2];
    const float* cf_lin1   = (const float*)d_in[3];
    const float* cf_mlp_w1 = (const float*)d_in[4];
    const float* cf_mlp_b1 = (const float*)d_in[5];
    const float* cf_mlp_w2 = (const float*)d_in[6];
    const float* cf_mlp_b2 = (const float*)d_in[7];
    const float* cf_lin2   = (const float*)d_in[8];
    const float* cf_lin2_b = (const float*)d_in[9];
    const float* lin_w     = (const float*)d_in[10];
    const float* lin_b     = (const float*)d_in[11];
    const float* bond_emb  = (const float*)d_in[12];
    const float* gin_eps   = (const float*)d_in[13];
    const float* gin_w1    = (const float*)d_in[14];
    const float* gin_b1    = (const float*)d_in[15];
    const float* gin_g1    = (const float*)d_in[16];
    const float* gin_be1   = (const float*)d_in[17];
    const float* gin_w2    = (const float*)d_in[18];
    const float* gin_b2    = (const float*)d_in[19];
    const float* bn_g      = (const float*)d_in[20];
    const float* bn_b      = (const float*)d_in[21];
    const float* vn_w1     = (const float*)d_in[22];
    const float* vn_b1     = (const float*)d_in[23];
    const float* vn_w2     = (const float*)d_in[24];
    const float* vn_b2     = (const float*)d_in[25];
    const float* out_w1    = (const float*)d_in[26];
    const float* out_b1    = (const float*)d_in[27];
    const float* out_w2    = (const float*)d_in[28];
    const float* out_b2    = (const float*)d_in[29];
    const int* x_atom      = (const int*)d_in[30];
    const int* pos_batch   = (const int*)d_in[32];
    const int* ei_conf     = (const int*)d_in[34];
    const int* ei_graph    = (const int*)d_in[35];
    const int* attr_graph  = (const int*)d_in[36];
    float* out = (float*)d_out;
    float* ws  = (float*)d_ws;

    size_t o = 0;
    float* X    = ws + o; o += (size_t)NC * H;
    float* HAGG = ws + o; o += (size_t)NC * F;
    float* XA   = ws + o; o += (size_t)NG * H;
    float* AGG  = ws + o; o += (size_t)NG * H;
    float* Z1   = ws + o; o += (size_t)NG * H;
    float* Z2   = ws + o; o += (size_t)NG * H;
    float* VN   = ws + o; o += (size_t)NCONF * H;
    float* TMP  = ws + o; o += (size_t)NCONF * H;
    float* TMP2 = ws + o; o += (size_t)NCONF * H;
    float* XM   = ws + o; o += (size_t)NMOL * H;
    float* Y1   = ws + o; o += (size_t)NMOL * H;
    float* STATS= ws + o; o += 512;
    float* PD   = ws + o; o += EC;
    float* PCC  = ws + o; o += EC;
    // bf16 regions
    unsigned short* CFH = (unsigned short*)(ws + o); o += (size_t)NC * F / 2;
    unsigned short* H2  = (unsigned short*)(ws + o); o += (size_t)NC * H / 2;
    unsigned short* TT1 = (unsigned short*)(ws + o); o += (size_t)NTAB * F / 2;
    unsigned short* TAB = (unsigned short*)(ws + o); o += (size_t)NTAB * F / 2;
    // int region
    int* PSRC   = (int*)(ws + o); o += EC;
    int* PGSRC  = (int*)(ws + o); o += EG;
    int* PATTR  = (int*)(ws + o); o += EG;
    int* CNT    = (int*)(ws + o); o += NC;
    int* ROWC   = (int*)(ws + o); o += NC + 64;
    int* CURC   = (int*)(ws + o); o += NC;
    int* ROWG   = (int*)(ws + o); o += NG + 64;
    int* CURG   = (int*)(ws + o); o += NG;
    int* BSUM   = (int*)(ws + o); o += 256;
    // transposed bf16 weights
    unsigned short* WT = (unsigned short*)(ws + o);
    size_t wo = 0;
    unsigned short* lin1t = WT + wo; wo += (size_t)NLAYERS * 128 * 256;
    unsigned short* w1t   = WT + wo; wo += (size_t)NLAYERS * 128 * 64;
    unsigned short* w2t   = WT + wo; wo += (size_t)NLAYERS * 128 * 128;
    unsigned short* lin2t = WT + wo; wo += (size_t)NLAYERS * 256 * 128;
    unsigned short* linwt = WT + wo; wo += (size_t)NLAYERS * 256 * 256;
    unsigned short* g1t   = WT + wo; wo += (size_t)NLAYERS * 256 * 256;
    unsigned short* g2t   = WT + wo; wo += (size_t)NLAYERS * 256 * 256;
    unsigned short* vn1t  = WT + wo; wo += 256 * 256;
    unsigned short* vn2t  = WT + wo; wo += 256 * 256;
    unsigned short* ow1t  = WT + wo; wo += 256 * 256;

    // ---- weight prep ----
    for (int i = 0; i < NLAYERS; ++i) {
        k_wt<<<128, 256, 0, stream>>>(cf_lin1 + (size_t)i * H * F,   lin1t + (size_t)i * 128 * 256, 256, 128, 256);
        k_wt<<<128, 256, 0, stream>>>(cf_mlp_w1 + (size_t)i * NGAUSS * F, w1t + (size_t)i * 128 * 64, NGAUSS, 128, 64);
        k_wt<<<128, 256, 0, stream>>>(cf_mlp_w2 + (size_t)i * F * F, w2t + (size_t)i * 128 * 128, 128, 128, 128);
        k_wt<<<256, 256, 0, stream>>>(cf_lin2 + (size_t)i * F * H,   lin2t + (size_t)i * 256 * 128, 128, 256, 128);
        k_wt<<<256, 256, 0, stream>>>(lin_w + (size_t)i * H * H,     linwt + (size_t)i * 256 * 256, 256, 256, 256);
        k_wt<<<256, 256, 0, stream>>>(gin_w1 + (size_t)i * H * H,    g1t + (size_t)i * 256 * 256, 256, 256, 256);
        k_wt<<<256, 256, 0, stream>>>(gin_w2 + (size_t)i * H * H,    g2t + (size_t)i * 256 * 256, 256, 256, 256);
    }
    k_wt<<<256, 256, 0, stream>>>(vn_w1, vn1t, 256, 256, 256);
    k_wt<<<256, 256, 0, stream>>>(vn_w2, vn2t, 256, 256, 256);
    k_wt<<<256, 256, 0, stream>>>(out_w1, ow1t, 256, 256, 256);

    // ---- dst-sort both edge lists (once; content is launch-invariant) ----
    hipMemsetAsync(CNT, 0, NC * sizeof(int), stream);
    k_hist<<<EC / 256, 256, 0, stream>>>(ei_conf + EC, CNT, EC);
    k_scan1<<<NC / 256, 256, 0, stream>>>(CNT, ROWC, BSUM);
    k_scan2<<<1, 256, 0, stream>>>(BSUM, NC / 256);
    k_scan3<<<NC / 256, 256, 0, stream>>>(ROWC, BSUM, CURC, NC, EC);
    k_cperm<<<EC / 256, 256, 0, stream>>>(pos, ei_conf, CURC, PSRC, PD, PCC);

    hipMemsetAsync(CNT, 0, NG * sizeof(int), stream);
    k_hist<<<EG / 256, 256, 0, stream>>>(ei_graph + EG, CNT, EG);
    k_scan1<<<NG / 256, 256, 0, stream>>>(CNT, ROWG, BSUM);
    k_scan2<<<1, 256, 0, stream>>>(BSUM, NG / 256);
    k_scan3<<<NG / 256, 256, 0, stream>>>(ROWG, BSUM, CURG, NG, EG);
    k_gperm<<<EG / 256, 256, 0, stream>>>(ei_graph, attr_graph, CURG, PGSRC, PATTR);

    k_init_x<<<NC, 256, 0, stream>>>(atom_emb, x_atom, X);
    k_vninit<<<NCONF, 256, 0, stream>>>(vn_emb, VN);

    for (int i = 0; i < NLAYERS; ++i) {
        k_addvn<<<NC, 256, 0, stream>>>(X, VN, pos_batch);
        if (i < NLAYERS - 1) {
            k_vn_tmp<<<NCONF, 256, 0, stream>>>(X, VN, TMP);
            mgemm<0, 1><<<dim3(2, NCONF / 128), 256, 0, stream>>>(
                TMP, 0, vn1t, vn_b1, TMP2, 0, 256, 256, 256, 0);
            mgemm<0, 1><<<dim3(2, NCONF / 128), 256, 0, stream>>>(
                TMP2, 0, vn2t, vn_b2, VN, 0, 256, 256, 256, 0);
        }
        // ---- CFConv ----
        // edge-MLP lookup table for this layer: TAB[i] = mlp(gauss(i*step))
        mgemm<3, 2><<<dim3(1, NTAB / 128), 256, 0, stream>>>(
            0, 0, w1t + (size_t)i * 128 * 64, cf_mlp_b1 + i * F,
            0, TT1, NGAUSS, 64, 128, 0);
        mgemm<2, 6><<<dim3(1, NTAB / 128), 256, 0, stream>>>(
            0, TT1, w2t + (size_t)i * 128 * 128, cf_mlp_b2 + i * F,
            0, TAB, 128, 128, 128, 0);
        // cfh = x @ cf_lin1 (bf16)
        mgemm<0, 6><<<dim3(1, NC / 128), 256, 0, stream>>>(
            X, 0, lin1t + (size_t)i * 128 * 256, nullptr, 0, CFH,
            256, 256, 128, 0);
        // per-node gather-aggregate with table interp (pure write, no atomics)
        k_cf_agg<<<NC / 2, 256, 0, stream>>>(TAB, ROWC, PSRC, PD, PCC, CFH, HAGG);
        // ---- GIN (pre-update X) ----
        k_xa<<<NG, 256, 0, stream>>>(X, XA);
        k_gin_agg<<<NG, 256, 0, stream>>>(
            XA, bond_emb + (size_t)i * 3 * 8 * H, ROWG, PGSRC, PATTR,
            gin_eps + i, AGG);
        mgemm<0, 0><<<dim3(2, NG / 128), 256, 0, stream>>>(
            AGG, 0, g1t + (size_t)i * 256 * 256, gin_b1 + i * H, Z1, 0,
            256, 256, 256, 0);
        hipMemsetAsync(STATS, 0, 2048, stream);
        k_bnstats<<<64, 256, 0, stream>>>(Z1, STATS);
        k_bnapply<true><<<NG, 256, 0, stream>>>(Z1, STATS, gin_g1 + i * H, gin_be1 + i * H);
        mgemm<0, 0><<<dim3(2, NG / 128), 256, 0, stream>>>(
            Z1, 0, g2t + (size_t)i * 256 * 256, gin_b2 + i * H, Z2, 0,
            256, 256, 256, 0);
        hipMemsetAsync(STATS, 0, 2048, stream);
        k_bnstats<<<64, 256, 0, stream>>>(Z2, STATS);
        k_bnapply<false><<<NG, 256, 0, stream>>>(Z2, STATS, bn_g + i * H, bn_b + i * H);
        // ---- combine ----
        mgemm<0, 2><<<dim3(2, NC / 128), 256, 0, stream>>>(
            HAGG, 0, lin2t + (size_t)i * 256 * 128, cf_lin2_b + i * H,
            0, H2, 128, 128, 256, 0);
        mgemm<2, 4><<<dim3(2, NC / 128), 256, 0, stream>>>(
            0, H2, linwt + (size_t)i * 256 * 256, lin_b + i * H, X, 0,
            256, 256, 256, Z2);
    }

    k_molmax<<<NMOL, 256, 0, stream>>>(X, XM);
    mgemm<0, 1><<<dim3(2, NMOL / 128), 256, 0, stream>>>(
        XM, 0, ow1t, out_b1, Y1, 0, 256, 256, 256, 0);
    k_head<<<NMOL, 256, 0, stream>>>(Y1, out_w2, out_b2, out);
}

// Round 5
// 1629.502 us; speedup vs baseline: 5.5916x; 1.2430x over previous
//
#include <hip/hip_runtime.h>
#include <math.h>

#define H 256
#define F 128
#define NLAYERS 4
#define NG 8192
#define NC 65536
#define EC 524288
#define EG 32768
#define NCONF 4096
#define NMOL 512
#define NGAUSS 50
#define NTAB 8192
#define TABSTEP 0.001953125f   // 16 / 8192
#define INVSTEP 512.0f

using s16x8 = __attribute__((ext_vector_type(8))) short;
using f32x4 = __attribute__((ext_vector_type(4))) float;

static __device__ __forceinline__ unsigned short f2bf(float f) {
    unsigned int u = __float_as_uint(f);
    u += 0x7fffu + ((u >> 16) & 1u);   // RNE (finite values)
    return (unsigned short)(u >> 16);
}
static __device__ __forceinline__ float bf2f(unsigned short b) {
    return __uint_as_float(((unsigned int)b) << 16);
}
static __device__ __forceinline__ float bflo(unsigned int u) {
    return __uint_as_float(u << 16);
}
static __device__ __forceinline__ float bfhi(unsigned int u) {
    return __uint_as_float(u & 0xffff0000u);
}

// ---------------- elementwise / fused kernels ----------------

__global__ __launch_bounds__(256) void k_init_x(const float* __restrict__ atom_emb,
    const int* __restrict__ x_atom, float* __restrict__ x)
{
    int i = blockIdx.x, h = threadIdx.x;
    int g = i & (NG - 1);
    float s = 0.f;
#pragma unroll
    for (int f = 0; f < 9; ++f) {
        int a = x_atom[g * 9 + f];
        s += atom_emb[(f * 64 + a) * H + h];
    }
    x[(size_t)i * H + h] = s;
}

__global__ __launch_bounds__(256) void k_vninit(const float* __restrict__ vn_emb,
                                                float* __restrict__ vn)
{
    vn[(size_t)blockIdx.x * H + threadIdx.x] = vn_emb[threadIdx.x];
}

// fused per-molecule: X += VN[pos_batch]; TMP[c] = vn[c]+sum_t X'; XA[g] = max_r X'
// block = molecule m; rows i = r*NG + m*16 + t ; conformer c = m*8+r ; graph g = m*16+t
template <bool DOTMP>
__global__ __launch_bounds__(256) void k_pre(float* __restrict__ X,
    const float* __restrict__ vn, float* __restrict__ tmp, float* __restrict__ xa)
{
    int m = blockIdx.x, h = threadIdx.x;
    float xam[16];
#pragma unroll
    for (int t = 0; t < 16; ++t) xam[t] = -3.4e38f;
#pragma unroll 2
    for (int r = 0; r < 8; ++r) {
        float vv = vn[(size_t)(m * 8 + r) * H + h];
        float ts = vv;
        size_t base = ((size_t)r * NG + m * 16) * H + h;
#pragma unroll
        for (int t = 0; t < 16; ++t) {
            float v = X[base + (size_t)t * H] + vv;
            X[base + (size_t)t * H] = v;
            xam[t] = fmaxf(xam[t], v);
            ts += v;
        }
        if (DOTMP) tmp[(size_t)(m * 8 + r) * H + h] = ts;
    }
#pragma unroll
    for (int t = 0; t < 16; ++t)
        xa[(size_t)(m * 16 + t) * H + h] = xam[t];
}

__global__ __launch_bounds__(256) void k_bnstats(const float* __restrict__ z,
                                                 float* __restrict__ stats)
{
    int h = threadIdx.x;
    size_t r0 = (size_t)blockIdx.x * (NG / 64);
    float s = 0.f, q = 0.f;
    for (int r = 0; r < NG / 64; ++r) {
        float v = z[(r0 + r) * H + h];
        s += v; q = fmaf(v, v, q);
    }
    atomicAdd(&stats[h], s);
    atomicAdd(&stats[H + h], q);
}

template <bool RELU>
__global__ __launch_bounds__(256) void k_bnapply(float* __restrict__ z,
    const float* __restrict__ stats, const float* __restrict__ gamma,
    const float* __restrict__ beta)
{
    size_t i = (size_t)blockIdx.x * 256 + threadIdx.x;
    int h = threadIdx.x;
    float mean = stats[h] * (1.0f / NG);
    float var = stats[H + h] * (1.0f / NG) - mean * mean;
    float v = (z[i] - mean) * rsqrtf(var + 1e-5f) * gamma[h] + beta[h];
    if (RELU) v = fmaxf(v, 0.f);
    z[i] = v;
}

__global__ __launch_bounds__(256) void k_molmax(const float* __restrict__ x,
                                                float* __restrict__ xm)
{
    int m = blockIdx.x, h = threadIdx.x;
    float best = -3.4e38f;
    for (int r = 0; r < 8; ++r) {
        size_t base = ((size_t)r * NG + m * 16) * H + h;
#pragma unroll 4
        for (int t = 0; t < 16; ++t) best = fmaxf(best, x[base + (size_t)t * H]);
    }
    xm[(size_t)m * H + h] = best;
}

__global__ __launch_bounds__(256) void k_head(const float* __restrict__ y1,
    const float* __restrict__ w2, const float* __restrict__ b2,
    float* __restrict__ out)
{
    __shared__ float red[256];
    int m = blockIdx.x, h = threadIdx.x;
    red[h] = y1[(size_t)m * H + h] * w2[h];
    __syncthreads();
    for (int s = 128; s > 0; s >>= 1) {
        if (h < s) red[h] += red[h + s];
        __syncthreads();
    }
    if (h == 0) out[m] = red[0] + b2[0];
}

// weight transpose+convert: Wt[n*Kp+k] = bf16(W[k*N+n]), zero-padded to Kp
__global__ __launch_bounds__(256) void k_wt(const float* __restrict__ W,
    unsigned short* __restrict__ Wt, int K, int N, int Kp)
{
    int n = blockIdx.x;
    for (int k = threadIdx.x; k < Kp; k += 256)
        Wt[(size_t)n * Kp + k] = (k < K) ? f2bf(W[(size_t)k * N + n]) : (unsigned short)0;
}

// ---------------- counting sort by destination ----------------

__global__ __launch_bounds__(256) void k_hist(const int* __restrict__ dst,
                                              int* __restrict__ cnt, int ne)
{
    int e = blockIdx.x * 256 + threadIdx.x;
    if (e < ne) atomicAdd(&cnt[dst[e]], 1);
}

__global__ __launch_bounds__(256) void k_scan1(const int* __restrict__ cnt,
    int* __restrict__ part, int* __restrict__ bsum)
{
    __shared__ int sh[256];
    int t = threadIdx.x, idx = blockIdx.x * 256 + t;
    int v = cnt[idx];
    sh[t] = v; __syncthreads();
    for (int s = 1; s < 256; s <<= 1) {
        int add = (t >= s) ? sh[t - s] : 0;
        __syncthreads();
        sh[t] += add;
        __syncthreads();
    }
    part[idx] = sh[t] - v;             // block-local exclusive
    if (t == 255) bsum[blockIdx.x] = sh[255];
}

__global__ __launch_bounds__(256) void k_scan2(int* __restrict__ bsum, int nb)
{
    __shared__ int sh[256];
    int t = threadIdx.x;
    int v = (t < nb) ? bsum[t] : 0;
    sh[t] = v; __syncthreads();
    for (int s = 1; s < 256; s <<= 1) {
        int add = (t >= s) ? sh[t - s] : 0;
        __syncthreads();
        sh[t] += add;
        __syncthreads();
    }
    if (t < nb) bsum[t] = sh[t] - v;   // exclusive block offsets
}

__global__ __launch_bounds__(256) void k_scan3(int* __restrict__ part,
    const int* __restrict__ bsum, int* __restrict__ cursor, int nbins, int total)
{
    int idx = blockIdx.x * 256 + threadIdx.x;
    int v = part[idx] + bsum[blockIdx.x];
    part[idx] = v;
    cursor[idx] = v;
    if (idx == 0) part[nbins] = total;
}

// conformer edges: compute geometry, write into dst-sorted order; (d,ccut) packed
__global__ __launch_bounds__(256) void k_cperm(const float* __restrict__ pos,
    const int* __restrict__ ei, int* __restrict__ cursor,
    int* __restrict__ psrc, float2* __restrict__ pdcc)
{
    int e = blockIdx.x * 256 + threadIdx.x;
    int s = ei[e], t = ei[EC + e];
    float dx = pos[s * 3 + 0] - pos[t * 3 + 0];
    float dy = pos[s * 3 + 1] - pos[t * 3 + 1];
    float dz = pos[s * 3 + 2] - pos[t * 3 + 2];
    float dd = sqrtf(dx * dx + dy * dy + dz * dz);
    int p = atomicAdd(&cursor[t], 1);
    psrc[p] = s;
    pdcc[p] = make_float2(dd, 0.5f * (cosf(dd * 0.314159265358979f) + 1.0f));
}

// molecular-graph edges: pack attr, write into dst-sorted order
__global__ __launch_bounds__(256) void k_gperm(const int* __restrict__ ei,
    const int* __restrict__ attr, int* __restrict__ cursor,
    int* __restrict__ pgsrc, int* __restrict__ pattr)
{
    int e = blockIdx.x * 256 + threadIdx.x;
    int s = ei[e], t = ei[EG + e];
    int p = atomicAdd(&cursor[t], 1);
    pgsrc[p] = s;
    pattr[p] = attr[e * 3] | (attr[e * 3 + 1] << 4) | (attr[e * 3 + 2] << 8);
}

// ---------------- gather-based aggregations (no atomics) ----------------

// 4 channels/thread; 8 nodes/block.
// HAGG[n][c] = sum_e lerp(TAB,d)[c] * ccut * cfh[psrc[e]][c]   (bf16 out)
__global__ __launch_bounds__(256) void k_cf_agg(const unsigned short* __restrict__ tab,
    const int* __restrict__ rowptr, const int* __restrict__ psrc,
    const float2* __restrict__ pdcc,
    const unsigned short* __restrict__ cfh, unsigned short* __restrict__ hagg)
{
    int slot = threadIdx.x >> 5;
    int c4 = (threadIdx.x & 31) << 2;
    int n = blockIdx.x * 8 + slot;
    int lo = rowptr[n], hi = rowptr[n + 1];
    float a0 = 0.f, a1 = 0.f, a2 = 0.f, a3 = 0.f;
    for (int e = lo; e < hi; ++e) {
        int s = psrc[e];
        float2 dc = pdcc[e];
        float u = fminf(dc.x * INVSTEP, (float)(NTAB - 1));
        int it = (int)u;
        if (it > NTAB - 2) it = NTAB - 2;
        float fr = u - (float)it;
        uint2 T0 = *(const uint2*)&tab[(size_t)it * F + c4];
        uint2 T1 = *(const uint2*)&tab[(size_t)(it + 1) * F + c4];
        uint2 HV = *(const uint2*)&cfh[(size_t)s * F + c4];
        float w0 = bflo(T0.x) + fr * (bflo(T1.x) - bflo(T0.x));
        float w1 = bfhi(T0.x) + fr * (bfhi(T1.x) - bfhi(T0.x));
        float w2 = bflo(T0.y) + fr * (bflo(T1.y) - bflo(T0.y));
        float w3 = bfhi(T0.y) + fr * (bfhi(T1.y) - bfhi(T0.y));
        a0 = fmaf(w0 * dc.y, bflo(HV.x), a0);
        a1 = fmaf(w1 * dc.y, bfhi(HV.x), a1);
        a2 = fmaf(w2 * dc.y, bflo(HV.y), a2);
        a3 = fmaf(w3 * dc.y, bfhi(HV.y), a3);
    }
    ushort4 o;
    o.x = f2bf(a0); o.y = f2bf(a1); o.z = f2bf(a2); o.w = f2bf(a3);
    *(ushort4*)&hagg[(size_t)n * F + c4] = o;
}

// AGG[g] = (1+eps)*xa[g] + sum_{e} relu(xa[pgsrc[e]] + bond_sum)
__global__ __launch_bounds__(256) void k_gin_agg(const float* __restrict__ xa,
    const float* __restrict__ bond, const int* __restrict__ growptr,
    const int* __restrict__ pgsrc, const int* __restrict__ pattr,
    const float* __restrict__ eps_p, float* __restrict__ agg)
{
    int g = blockIdx.x, h = threadIdx.x;
    int lo = growptr[g], hi = growptr[g + 1];
    float acc = 0.f;
    for (int e = lo; e < hi; ++e) {
        int s = pgsrc[e], a = pattr[e];
        float v = xa[(size_t)s * H + h]
                + bond[(a & 15) * H + h]
                + bond[(8 + ((a >> 4) & 15)) * H + h]
                + bond[(16 + (a >> 8)) * H + h];
        acc += fmaxf(v, 0.f);
    }
    agg[(size_t)g * H + h] = (1.0f + eps_p[0]) * xa[(size_t)g * H + h] + acc;
}

// ---------------- MFMA GEMM ----------------
// C[M,N] = A[M,K] @ B[K,N], tile 128x128, BK=64, 4 waves (2x2 of 64x64).
// ASRC: 0 = f32 A (convert on stage), 2 = bf16 A, 3 = gauss row from table index
// EPI:  0 = Cf=v+bias, 1 = relu->Cf, 2 = relu->bf16 Cb, 6 = plain->bf16 Cb
//       4 = Cf[m][n] = relu(Cf[m][n] + v + bias + aux[(m&8191)*ldc+n])
template<int ASRC, int EPI>
__global__ __launch_bounds__(256) void mgemm(
    const float* __restrict__ Af, const unsigned short* __restrict__ Ab,
    const unsigned short* __restrict__ Bt,
    const float* __restrict__ bias,
    float* __restrict__ Cf, unsigned short* __restrict__ Cb,
    int K, int Kp, int ldc,
    const float* __restrict__ aux)
{
    __shared__ unsigned short As[128][72];
    __shared__ unsigned short Bs[128][72];
    const int tid = threadIdx.x;
    const int bm = blockIdx.y * 128;
    const int bn = blockIdx.x * 128;
    const int lane = tid & 63;
    const int wid = tid >> 6;
    const int wm = wid >> 1, wn = wid & 1;
    const int rsel = lane & 15, ksel = (lane >> 4) * 8;

    f32x4 acc[4][4];
#pragma unroll
    for (int a = 0; a < 4; ++a)
#pragma unroll
        for (int b = 0; b < 4; ++b) acc[a][b] = (f32x4){0.f, 0.f, 0.f, 0.f};

    for (int k0 = 0; k0 < Kp; k0 += 64) {
        // ---- stage B: Bt[N][Kp] bf16, 16B chunks ----
#pragma unroll
        for (int i = 0; i < 4; ++i) {
            int c = tid + i * 256;
            int row = c >> 3, kc = (c & 7) * 8;
            uint4 v = *(const uint4*)&Bt[(size_t)(bn + row) * Kp + k0 + kc];
            *(uint4*)&Bs[row][kc] = v;
        }
        // ---- stage A ----
        if constexpr (ASRC == 0) {
#pragma unroll
            for (int i = 0; i < 8; ++i) {
                int c = tid + i * 256;
                int row = c >> 4, kc = (c & 15) * 4;
                float4 v = *(const float4*)&Af[(size_t)(bm + row) * K + k0 + kc];
                ushort4 b;
                b.x = f2bf(v.x); b.y = f2bf(v.y); b.z = f2bf(v.z); b.w = f2bf(v.w);
                *(ushort4*)&As[row][kc] = b;
            }
        } else if constexpr (ASRC == 3) {
#pragma unroll
            for (int i = 0; i < 8; ++i) {
                int c = tid + i * 256;
                int row = c >> 4, kc = (c & 15) * 4;
                float dv = (float)(bm + row) * TABSTEP;
                ushort4 b;
                unsigned short* bp = (unsigned short*)&b;
#pragma unroll
                for (int j = 0; j < 4; ++j) {
                    int k = k0 + kc + j;
                    float f = 0.f;
                    if (k < K) {
                        float t = dv - (float)k * (10.0f / 49.0f);
                        f = __expf(-12.005f * t * t);
                    }
                    bp[j] = f2bf(f);
                }
                *(ushort4*)&As[row][kc] = b;
            }
        } else {
#pragma unroll
            for (int i = 0; i < 4; ++i) {
                int c = tid + i * 256;
                int row = c >> 3, kc = (c & 7) * 8;
                uint4 v = *(const uint4*)&Ab[(size_t)(bm + row) * K + k0 + kc];
                *(uint4*)&As[row][kc] = v;
            }
        }
        __syncthreads();
        // ---- MFMA ----
#pragma unroll
        for (int kk = 0; kk < 64; kk += 32) {
            s16x8 af[4], bf[4];
#pragma unroll
            for (int mi = 0; mi < 4; ++mi)
                af[mi] = *(const s16x8*)&As[wm * 64 + mi * 16 + rsel][kk + ksel];
#pragma unroll
            for (int ni = 0; ni < 4; ++ni)
                bf[ni] = *(const s16x8*)&Bs[wn * 64 + ni * 16 + rsel][kk + ksel];
#pragma unroll
            for (int mi = 0; mi < 4; ++mi)
#pragma unroll
                for (int ni = 0; ni < 4; ++ni)
                    acc[mi][ni] = __builtin_amdgcn_mfma_f32_16x16x32_bf16(
                        af[mi], bf[ni], acc[mi][ni], 0, 0, 0);
        }
        __syncthreads();
    }

    // ---- epilogue ----
#pragma unroll
    for (int mi = 0; mi < 4; ++mi) {
#pragma unroll
        for (int r = 0; r < 4; ++r) {
            int m = bm + wm * 64 + mi * 16 + ((lane >> 4) << 2) + r;
#pragma unroll
            for (int ni = 0; ni < 4; ++ni) {
                int n = bn + wn * 64 + ni * 16 + (lane & 15);
                float v = acc[mi][ni][r];
                if (bias) v += bias[n];
                if constexpr (EPI == 0) {
                    Cf[(size_t)m * ldc + n] = v;
                } else if constexpr (EPI == 1) {
                    Cf[(size_t)m * ldc + n] = fmaxf(v, 0.f);
                } else if constexpr (EPI == 2) {
                    Cb[(size_t)m * ldc + n] = f2bf(fmaxf(v, 0.f));
                } else if constexpr (EPI == 4) {
                    size_t ix = (size_t)m * ldc + n;
                    float o = Cf[ix] + v + aux[(size_t)(m & (NG - 1)) * ldc + n];
                    Cf[ix] = fmaxf(o, 0.f);
                } else {  // EPI == 6
                    Cb[(size_t)m * ldc + n] = f2bf(v);
                }
            }
        }
    }
}

// ---------------- launch ----------------
extern "C" void kernel_launch(void* const* d_in, const int* in_sizes, int n_in,
                              void* d_out, int out_size, void* d_ws, size_t ws_size,
                              hipStream_t stream)
{
    (void)in_sizes; (void)n_in; (void)out_size; (void)ws_size;
    const float* pos       = (const float*)d_in[0];
    const float* atom_emb  = (const float*)d_in[1];
    const float* vn_emb    = (const float*)d_in[2];
    const float* cf_lin1   = (const float*)d_in[3];
    const float* cf_mlp_w1 = (const float*)d_in[4];
    const float* cf_mlp_b1 = (const float*)d_in[5];
    const float* cf_mlp_w2 = (const float*)d_in[6];
    const float* cf_mlp_b2 = (const float*)d_in[7];
    const float* cf_lin2   = (const float*)d_in[8];
    const float* cf_lin2_b = (const float*)d_in[9];
    const float* lin_w     = (const float*)d_in[10];
    const float* lin_b     = (const float*)d_in[11];
    const float* bond_emb  = (const float*)d_in[12];
    const float* gin_eps   = (const float*)d_in[13];
    const float* gin_w1    = (const float*)d_in[14];
    const float* gin_b1    = (const float*)d_in[15];
    const float* gin_g1    = (const float*)d_in[16];
    const float* gin_be1   = (const float*)d_in[17];
    const float* gin_w2    = (const float*)d_in[18];
    const float* gin_b2    = (const float*)d_in[19];
    const float* bn_g      = (const float*)d_in[20];
    const float* bn_b      = (const float*)d_in[21];
    const float* vn_w1     = (const float*)d_in[22];
    const float* vn_b1     = (const float*)d_in[23];
    const float* vn_w2     = (const float*)d_in[24];
    const float* vn_b2     = (const float*)d_in[25];
    const float* out_w1    = (const float*)d_in[26];
    const float* out_b1    = (const float*)d_in[27];
    const float* out_w2    = (const float*)d_in[28];
    const float* out_b2    = (const float*)d_in[29];
    const int* x_atom      = (const int*)d_in[30];
    const int* pos_batch   = (const int*)d_in[32];
    const int* ei_conf     = (const int*)d_in[34];
    const int* ei_graph    = (const int*)d_in[35];
    const int* attr_graph  = (const int*)d_in[36];
    float* out = (float*)d_out;
    float* ws  = (float*)d_ws;

    size_t o = 0;
    float* X    = ws + o; o += (size_t)NC * H;
    float* XA   = ws + o; o += (size_t)NG * H;
    float* AGG  = ws + o; o += (size_t)NG * H;
    float* Z1   = ws + o; o += (size_t)NG * H;
    float* Z2   = ws + o; o += (size_t)NG * H;
    float* VN   = ws + o; o += (size_t)NCONF * H;
    float* TMP  = ws + o; o += (size_t)NCONF * H;
    float* TMP2 = ws + o; o += (size_t)NCONF * H;
    float* XM   = ws + o; o += (size_t)NMOL * H;
    float* Y1   = ws + o; o += (size_t)NMOL * H;
    float* STATS= ws + o; o += 512;
    float* PDCC = ws + o; o += (size_t)2 * EC;      // float2[EC]
    // bf16 regions
    unsigned short* CFH  = (unsigned short*)(ws + o); o += (size_t)NC * F / 2;
    unsigned short* HAGG = (unsigned short*)(ws + o); o += (size_t)NC * F / 2;
    unsigned short* H2   = (unsigned short*)(ws + o); o += (size_t)NC * H / 2;
    unsigned short* TT1  = (unsigned short*)(ws + o); o += (size_t)NTAB * F / 2;
    unsigned short* TAB  = (unsigned short*)(ws + o); o += (size_t)NTAB * F / 2;
    // int region
    int* PSRC   = (int*)(ws + o); o += EC;
    int* PGSRC  = (int*)(ws + o); o += EG;
    int* PATTR  = (int*)(ws + o); o += EG;
    int* CNT    = (int*)(ws + o); o += NC;
    int* ROWC   = (int*)(ws + o); o += NC + 64;
    int* CURC   = (int*)(ws + o); o += NC;
    int* ROWG   = (int*)(ws + o); o += NG + 64;
    int* CURG   = (int*)(ws + o); o += NG;
    int* BSUM   = (int*)(ws + o); o += 256;
    // transposed bf16 weights
    unsigned short* WT = (unsigned short*)(ws + o);
    size_t wo = 0;
    unsigned short* lin1t = WT + wo; wo += (size_t)NLAYERS * 128 * 256;
    unsigned short* w1t   = WT + wo; wo += (size_t)NLAYERS * 128 * 64;
    unsigned short* w2t   = WT + wo; wo += (size_t)NLAYERS * 128 * 128;
    unsigned short* lin2t = WT + wo; wo += (size_t)NLAYERS * 256 * 128;
    unsigned short* linwt = WT + wo; wo += (size_t)NLAYERS * 256 * 256;
    unsigned short* g1t   = WT + wo; wo += (size_t)NLAYERS * 256 * 256;
    unsigned short* g2t   = WT + wo; wo += (size_t)NLAYERS * 256 * 256;
    unsigned short* vn1t  = WT + wo; wo += 256 * 256;
    unsigned short* vn2t  = WT + wo; wo += 256 * 256;
    unsigned short* ow1t  = WT + wo; wo += 256 * 256;

    // ---- weight prep ----
    for (int i = 0; i < NLAYERS; ++i) {
        k_wt<<<128, 256, 0, stream>>>(cf_lin1 + (size_t)i * H * F,   lin1t + (size_t)i * 128 * 256, 256, 128, 256);
        k_wt<<<128, 256, 0, stream>>>(cf_mlp_w1 + (size_t)i * NGAUSS * F, w1t + (size_t)i * 128 * 64, NGAUSS, 128, 64);
        k_wt<<<128, 256, 0, stream>>>(cf_mlp_w2 + (size_t)i * F * F, w2t + (size_t)i * 128 * 128, 128, 128, 128);
        k_wt<<<256, 256, 0, stream>>>(cf_lin2 + (size_t)i * F * H,   lin2t + (size_t)i * 256 * 128, 128, 256, 128);
        k_wt<<<256, 256, 0, stream>>>(lin_w + (size_t)i * H * H,     linwt + (size_t)i * 256 * 256, 256, 256, 256);
        k_wt<<<256, 256, 0, stream>>>(gin_w1 + (size_t)i * H * H,    g1t + (size_t)i * 256 * 256, 256, 256, 256);
        k_wt<<<256, 256, 0, stream>>>(gin_w2 + (size_t)i * H * H,    g2t + (size_t)i * 256 * 256, 256, 256, 256);
    }
    k_wt<<<256, 256, 0, stream>>>(vn_w1, vn1t, 256, 256, 256);
    k_wt<<<256, 256, 0, stream>>>(vn_w2, vn2t, 256, 256, 256);
    k_wt<<<256, 256, 0, stream>>>(out_w1, ow1t, 256, 256, 256);

    // ---- dst-sort both edge lists (once; content is launch-invariant) ----
    hipMemsetAsync(CNT, 0, NC * sizeof(int), stream);
    k_hist<<<EC / 256, 256, 0, stream>>>(ei_conf + EC, CNT, EC);
    k_scan1<<<NC / 256, 256, 0, stream>>>(CNT, ROWC, BSUM);
    k_scan2<<<1, 256, 0, stream>>>(BSUM, NC / 256);
    k_scan3<<<NC / 256, 256, 0, stream>>>(ROWC, BSUM, CURC, NC, EC);
    k_cperm<<<EC / 256, 256, 0, stream>>>(pos, ei_conf, CURC, PSRC, (float2*)PDCC);

    hipMemsetAsync(CNT, 0, NG * sizeof(int), stream);
    k_hist<<<EG / 256, 256, 0, stream>>>(ei_graph + EG, CNT, EG);
    k_scan1<<<NG / 256, 256, 0, stream>>>(CNT, ROWG, BSUM);
    k_scan2<<<1, 256, 0, stream>>>(BSUM, NG / 256);
    k_scan3<<<NG / 256, 256, 0, stream>>>(ROWG, BSUM, CURG, NG, EG);
    k_gperm<<<EG / 256, 256, 0, stream>>>(ei_graph, attr_graph, CURG, PGSRC, PATTR);

    k_init_x<<<NC, 256, 0, stream>>>(atom_emb, x_atom, X);
    k_vninit<<<NCONF, 256, 0, stream>>>(vn_emb, VN);

    for (int i = 0; i < NLAYERS; ++i) {
        // fused addvn + vn_tmp + xa
        if (i < NLAYERS - 1) {
            k_pre<true><<<NMOL, 256, 0, stream>>>(X, VN, TMP, XA);
            mgemm<0, 1><<<dim3(2, NCONF / 128), 256, 0, stream>>>(
                TMP, 0, vn1t, vn_b1, TMP2, 0, 256, 256, 256, 0);
            mgemm<0, 1><<<dim3(2, NCONF / 128), 256, 0, stream>>>(
                TMP2, 0, vn2t, vn_b2, VN, 0, 256, 256, 256, 0);
        } else {
            k_pre<false><<<NMOL, 256, 0, stream>>>(X, VN, TMP, XA);
        }
        // ---- CFConv ----
        // edge-MLP lookup table for this layer: TAB[i] = mlp(gauss(i*step))
        mgemm<3, 2><<<dim3(1, NTAB / 128), 256, 0, stream>>>(
            0, 0, w1t + (size_t)i * 128 * 64, cf_mlp_b1 + i * F,
            0, TT1, NGAUSS, 64, 128, 0);
        mgemm<2, 6><<<dim3(1, NTAB / 128), 256, 0, stream>>>(
            0, TT1, w2t + (size_t)i * 128 * 128, cf_mlp_b2 + i * F,
            0, TAB, 128, 128, 128, 0);
        // cfh = x @ cf_lin1 (bf16)
        mgemm<0, 6><<<dim3(1, NC / 128), 256, 0, stream>>>(
            X, 0, lin1t + (size_t)i * 128 * 256, nullptr, 0, CFH,
            256, 256, 128, 0);
        // per-node gather-aggregate with table interp (pure write, no atomics)
        k_cf_agg<<<NC / 8, 256, 0, stream>>>(TAB, ROWC, PSRC, (const float2*)PDCC,
                                             CFH, HAGG);
        // ---- GIN ----
        k_gin_agg<<<NG, 256, 0, stream>>>(
            XA, bond_emb + (size_t)i * 3 * 8 * H, ROWG, PGSRC, PATTR,
            gin_eps + i, AGG);
        mgemm<0, 0><<<dim3(2, NG / 128), 256, 0, stream>>>(
            AGG, 0, g1t + (size_t)i * 256 * 256, gin_b1 + i * H, Z1, 0,
            256, 256, 256, 0);
        hipMemsetAsync(STATS, 0, 2048, stream);
        k_bnstats<<<64, 256, 0, stream>>>(Z1, STATS);
        k_bnapply<true><<<NG, 256, 0, stream>>>(Z1, STATS, gin_g1 + i * H, gin_be1 + i * H);
        mgemm<0, 0><<<dim3(2, NG / 128), 256, 0, stream>>>(
            Z1, 0, g2t + (size_t)i * 256 * 256, gin_b2 + i * H, Z2, 0,
            256, 256, 256, 0);
        hipMemsetAsync(STATS, 0, 2048, stream);
        k_bnstats<<<64, 256, 0, stream>>>(Z2, STATS);
        k_bnapply<false><<<NG, 256, 0, stream>>>(Z2, STATS, bn_g + i * H, bn_b + i * H);
        // ---- combine ----
        mgemm<2, 2><<<dim3(2, NC / 128), 256, 0, stream>>>(
            0, HAGG, lin2t + (size_t)i * 256 * 128, cf_lin2_b + i * H,
            0, H2, 128, 128, 256, 0);
        mgemm<2, 4><<<dim3(2, NC / 128), 256, 0, stream>>>(
            0, H2, linwt + (size_t)i * 256 * 256, lin_b + i * H, X, 0,
            256, 256, 256, Z2);
    }

    k_molmax<<<NMOL, 256, 0, stream>>>(X, XM);
    mgemm<0, 1><<<dim3(2, NMOL / 128), 256, 0, stream>>>(
        XM, 0, ow1t, out_b1, Y1, 0, 256, 256, 256, 0);
    k_head<<<NMOL, 256, 0, stream>>>(Y1, out_w2, out_b2, out);
}

// Round 6
// 1290.628 us; speedup vs baseline: 7.0597x; 1.2626x over previous
//
#include <hip/hip_runtime.h>
#include <math.h>

#define H 256
#define F 128
#define NLAYERS 4
#define NG 8192
#define NC 65536
#define EC 524288
#define EG 32768
#define NCONF 4096
#define NMOL 512
#define NGAUSS 50
#define NTAB 8192
#define TABSTEP 0.001953125f   // 16 / 8192
#define INVSTEP 512.0f

using s16x8 = __attribute__((ext_vector_type(8))) short;
using f32x4 = __attribute__((ext_vector_type(4))) float;

static __device__ __forceinline__ unsigned short f2bf(float f) {
    unsigned int u = __float_as_uint(f);
    u += 0x7fffu + ((u >> 16) & 1u);   // RNE (finite values)
    return (unsigned short)(u >> 16);
}
static __device__ __forceinline__ float bf2f(unsigned short b) {
    return __uint_as_float(((unsigned int)b) << 16);
}
static __device__ __forceinline__ float bflo(unsigned int u) {
    return __uint_as_float(u << 16);
}
static __device__ __forceinline__ float bfhi(unsigned int u) {
    return __uint_as_float(u & 0xffff0000u);
}

// ---------------- elementwise / fused kernels ----------------

__global__ __launch_bounds__(256) void k_init_x(const float* __restrict__ atom_emb,
    const int* __restrict__ x_atom, unsigned short* __restrict__ x)
{
    int i = blockIdx.x, h = threadIdx.x;
    int g = i & (NG - 1);
    float s = 0.f;
#pragma unroll
    for (int f = 0; f < 9; ++f) {
        int a = x_atom[g * 9 + f];
        s += atom_emb[(f * 64 + a) * H + h];
    }
    x[(size_t)i * H + h] = f2bf(s);
}

__global__ __launch_bounds__(256) void k_vninit(const float* __restrict__ vn_emb,
                                                float* __restrict__ vn)
{
    vn[(size_t)blockIdx.x * H + threadIdx.x] = vn_emb[threadIdx.x];
}

// fused per-molecule: X += VN[pos_batch]; TMP[c] = vn[c]+sum_t X'; XA[g] = max_r X'
// block = molecule m; rows i = r*NG + m*16 + t ; conformer c = m*8+r ; graph g = m*16+t
template <bool DOTMP>
__global__ __launch_bounds__(256) void k_pre(unsigned short* __restrict__ X,
    const float* __restrict__ vn, float* __restrict__ tmp,
    unsigned short* __restrict__ xa)
{
    int m = blockIdx.x, h = threadIdx.x;
    float xam[16];
#pragma unroll
    for (int t = 0; t < 16; ++t) xam[t] = -3.4e38f;
#pragma unroll 2
    for (int r = 0; r < 8; ++r) {
        float vv = vn[(size_t)(m * 8 + r) * H + h];
        float ts = vv;
        size_t base = ((size_t)r * NG + m * 16) * H + h;
#pragma unroll
        for (int t = 0; t < 16; ++t) {
            float v = bf2f(X[base + (size_t)t * H]) + vv;
            X[base + (size_t)t * H] = f2bf(v);
            xam[t] = fmaxf(xam[t], v);
            ts += v;
        }
        if (DOTMP) tmp[(size_t)(m * 8 + r) * H + h] = ts;
    }
#pragma unroll
    for (int t = 0; t < 16; ++t)
        xa[(size_t)(m * 16 + t) * H + h] = f2bf(xam[t]);
}

__global__ __launch_bounds__(256) void k_bnstats(const float* __restrict__ z,
                                                 float* __restrict__ stats)
{
    int h = threadIdx.x;
    size_t r0 = (size_t)blockIdx.x * (NG / 64);
    float s = 0.f, q = 0.f;
    for (int r = 0; r < NG / 64; ++r) {
        float v = z[(r0 + r) * H + h];
        s += v; q = fmaf(v, v, q);
    }
    atomicAdd(&stats[h], s);
    atomicAdd(&stats[H + h], q);
}

template <bool RELU>
__global__ __launch_bounds__(256) void k_bnapply(float* __restrict__ z,
    const float* __restrict__ stats, const float* __restrict__ gamma,
    const float* __restrict__ beta)
{
    size_t i = (size_t)blockIdx.x * 256 + threadIdx.x;
    int h = threadIdx.x;
    float mean = stats[h] * (1.0f / NG);
    float var = stats[H + h] * (1.0f / NG) - mean * mean;
    float v = (z[i] - mean) * rsqrtf(var + 1e-5f) * gamma[h] + beta[h];
    if (RELU) v = fmaxf(v, 0.f);
    z[i] = v;
}

__global__ __launch_bounds__(256) void k_molmax(const unsigned short* __restrict__ x,
                                                float* __restrict__ xm)
{
    int m = blockIdx.x, h = threadIdx.x;
    float best = -3.4e38f;
    for (int r = 0; r < 8; ++r) {
        size_t base = ((size_t)r * NG + m * 16) * H + h;
#pragma unroll 4
        for (int t = 0; t < 16; ++t) best = fmaxf(best, bf2f(x[base + (size_t)t * H]));
    }
    xm[(size_t)m * H + h] = best;
}

__global__ __launch_bounds__(256) void k_head(const float* __restrict__ y1,
    const float* __restrict__ w2, const float* __restrict__ b2,
    float* __restrict__ out)
{
    __shared__ float red[256];
    int m = blockIdx.x, h = threadIdx.x;
    red[h] = y1[(size_t)m * H + h] * w2[h];
    __syncthreads();
    for (int s = 128; s > 0; s >>= 1) {
        if (h < s) red[h] += red[h + s];
        __syncthreads();
    }
    if (h == 0) out[m] = red[0] + b2[0];
}

// weight transpose+convert: Wt[n*Kp+k] = bf16(W[k*N+n]), zero-padded to Kp
__global__ __launch_bounds__(256) void k_wt(const float* __restrict__ W,
    unsigned short* __restrict__ Wt, int K, int N, int Kp)
{
    int n = blockIdx.x;
    for (int k = threadIdx.x; k < Kp; k += 256)
        Wt[(size_t)n * Kp + k] = (k < K) ? f2bf(W[(size_t)k * N + n]) : (unsigned short)0;
}

// ---------------- counting sort by destination ----------------

__global__ __launch_bounds__(256) void k_hist(const int* __restrict__ dst,
                                              int* __restrict__ cnt, int ne)
{
    int e = blockIdx.x * 256 + threadIdx.x;
    if (e < ne) atomicAdd(&cnt[dst[e]], 1);
}

__global__ __launch_bounds__(256) void k_scan1(const int* __restrict__ cnt,
    int* __restrict__ part, int* __restrict__ bsum)
{
    __shared__ int sh[256];
    int t = threadIdx.x, idx = blockIdx.x * 256 + t;
    int v = cnt[idx];
    sh[t] = v; __syncthreads();
    for (int s = 1; s < 256; s <<= 1) {
        int add = (t >= s) ? sh[t - s] : 0;
        __syncthreads();
        sh[t] += add;
        __syncthreads();
    }
    part[idx] = sh[t] - v;             // block-local exclusive
    if (t == 255) bsum[blockIdx.x] = sh[255];
}

__global__ __launch_bounds__(256) void k_scan2(int* __restrict__ bsum, int nb)
{
    __shared__ int sh[256];
    int t = threadIdx.x;
    int v = (t < nb) ? bsum[t] : 0;
    sh[t] = v; __syncthreads();
    for (int s = 1; s < 256; s <<= 1) {
        int add = (t >= s) ? sh[t - s] : 0;
        __syncthreads();
        sh[t] += add;
        __syncthreads();
    }
    if (t < nb) bsum[t] = sh[t] - v;   // exclusive block offsets
}

__global__ __launch_bounds__(256) void k_scan3(int* __restrict__ part,
    const int* __restrict__ bsum, int* __restrict__ cursor, int nbins, int total)
{
    int idx = blockIdx.x * 256 + threadIdx.x;
    int v = part[idx] + bsum[blockIdx.x];
    part[idx] = v;
    cursor[idx] = v;
    if (idx == 0) part[nbins] = total;
}

// conformer edges: compute geometry, write into dst-sorted order; (d,ccut) packed
__global__ __launch_bounds__(256) void k_cperm(const float* __restrict__ pos,
    const int* __restrict__ ei, int* __restrict__ cursor,
    int* __restrict__ psrc, float2* __restrict__ pdcc)
{
    int e = blockIdx.x * 256 + threadIdx.x;
    int s = ei[e], t = ei[EC + e];
    float dx = pos[s * 3 + 0] - pos[t * 3 + 0];
    float dy = pos[s * 3 + 1] - pos[t * 3 + 1];
    float dz = pos[s * 3 + 2] - pos[t * 3 + 2];
    float dd = sqrtf(dx * dx + dy * dy + dz * dz);
    int p = atomicAdd(&cursor[t], 1);
    psrc[p] = s;
    pdcc[p] = make_float2(dd, 0.5f * (cosf(dd * 0.314159265358979f) + 1.0f));
}

// molecular-graph edges: pack attr, write into dst-sorted order
__global__ __launch_bounds__(256) void k_gperm(const int* __restrict__ ei,
    const int* __restrict__ attr, int* __restrict__ cursor,
    int* __restrict__ pgsrc, int* __restrict__ pattr)
{
    int e = blockIdx.x * 256 + threadIdx.x;
    int s = ei[e], t = ei[EG + e];
    int p = atomicAdd(&cursor[t], 1);
    pgsrc[p] = s;
    pattr[p] = attr[e * 3] | (attr[e * 3 + 1] << 4) | (attr[e * 3 + 2] << 8);
}

// ---------------- gather-based aggregations (no atomics) ----------------

// 4 channels/thread; 8 nodes/block.
// HAGG[n][c] = sum_e lerp(TAB,d)[c] * ccut * cfh[psrc[e]][c]   (bf16 out)
__global__ __launch_bounds__(256) void k_cf_agg(const unsigned short* __restrict__ tab,
    const int* __restrict__ rowptr, const int* __restrict__ psrc,
    const float2* __restrict__ pdcc,
    const unsigned short* __restrict__ cfh, unsigned short* __restrict__ hagg)
{
    int slot = threadIdx.x >> 5;
    int c4 = (threadIdx.x & 31) << 2;
    int n = blockIdx.x * 8 + slot;
    int lo = rowptr[n], hi = rowptr[n + 1];
    float a0 = 0.f, a1 = 0.f, a2 = 0.f, a3 = 0.f;
    for (int e = lo; e < hi; ++e) {
        int s = psrc[e];
        float2 dc = pdcc[e];
        float u = fminf(dc.x * INVSTEP, (float)(NTAB - 1));
        int it = (int)u;
        if (it > NTAB - 2) it = NTAB - 2;
        float fr = u - (float)it;
        uint2 T0 = *(const uint2*)&tab[(size_t)it * F + c4];
        uint2 T1 = *(const uint2*)&tab[(size_t)(it + 1) * F + c4];
        uint2 HV = *(const uint2*)&cfh[(size_t)s * F + c4];
        float w0 = bflo(T0.x) + fr * (bflo(T1.x) - bflo(T0.x));
        float w1 = bfhi(T0.x) + fr * (bfhi(T1.x) - bfhi(T0.x));
        float w2 = bflo(T0.y) + fr * (bflo(T1.y) - bflo(T0.y));
        float w3 = bfhi(T0.y) + fr * (bfhi(T1.y) - bfhi(T0.y));
        a0 = fmaf(w0 * dc.y, bflo(HV.x), a0);
        a1 = fmaf(w1 * dc.y, bfhi(HV.x), a1);
        a2 = fmaf(w2 * dc.y, bflo(HV.y), a2);
        a3 = fmaf(w3 * dc.y, bfhi(HV.y), a3);
    }
    ushort4 o;
    o.x = f2bf(a0); o.y = f2bf(a1); o.z = f2bf(a2); o.w = f2bf(a3);
    *(ushort4*)&hagg[(size_t)n * F + c4] = o;
}

// AGG[g] = (1+eps)*xa[g] + sum_{e} relu(xa[pgsrc[e]] + bond_sum)
__global__ __launch_bounds__(256) void k_gin_agg(const unsigned short* __restrict__ xa,
    const float* __restrict__ bond, const int* __restrict__ growptr,
    const int* __restrict__ pgsrc, const int* __restrict__ pattr,
    const float* __restrict__ eps_p, float* __restrict__ agg)
{
    int g = blockIdx.x, h = threadIdx.x;
    int lo = growptr[g], hi = growptr[g + 1];
    float acc = 0.f;
    for (int e = lo; e < hi; ++e) {
        int s = pgsrc[e], a = pattr[e];
        float v = bf2f(xa[(size_t)s * H + h])
                + bond[(a & 15) * H + h]
                + bond[(8 + ((a >> 4) & 15)) * H + h]
                + bond[(16 + (a >> 8)) * H + h];
        acc += fmaxf(v, 0.f);
    }
    agg[(size_t)g * H + h] = (1.0f + eps_p[0]) * bf2f(xa[(size_t)g * H + h]) + acc;
}

// ---------------- MFMA GEMM ----------------
// C[M,N] = A[M,K] @ B[K,N], tile 128x128, BK=64, 4 waves (2x2 of 64x64).
// ASRC: 0 = f32 A (convert on stage), 2 = bf16 A, 3 = gauss row from table index
// EPI:  0 = Cf=v+bias, 1 = relu->Cf, 2 = relu->bf16 Cb, 6 = plain->bf16 Cb
template<int ASRC, int EPI>
__global__ __launch_bounds__(256) void mgemm(
    const float* __restrict__ Af, const unsigned short* __restrict__ Ab,
    const unsigned short* __restrict__ Bt,
    const float* __restrict__ bias,
    float* __restrict__ Cf, unsigned short* __restrict__ Cb,
    int K, int Kp, int ldc)
{
    __shared__ unsigned short As[128][72];
    __shared__ unsigned short Bs[128][72];
    const int tid = threadIdx.x;
    const int bm = blockIdx.y * 128;
    const int bn = blockIdx.x * 128;
    const int lane = tid & 63;
    const int wid = tid >> 6;
    const int wm = wid >> 1, wn = wid & 1;
    const int rsel = lane & 15, ksel = (lane >> 4) * 8;

    f32x4 acc[4][4];
#pragma unroll
    for (int a = 0; a < 4; ++a)
#pragma unroll
        for (int b = 0; b < 4; ++b) acc[a][b] = (f32x4){0.f, 0.f, 0.f, 0.f};

    for (int k0 = 0; k0 < Kp; k0 += 64) {
        // ---- stage B: Bt[N][Kp] bf16, 16B chunks ----
#pragma unroll
        for (int i = 0; i < 4; ++i) {
            int c = tid + i * 256;
            int row = c >> 3, kc = (c & 7) * 8;
            uint4 v = *(const uint4*)&Bt[(size_t)(bn + row) * Kp + k0 + kc];
            *(uint4*)&Bs[row][kc] = v;
        }
        // ---- stage A ----
        if constexpr (ASRC == 0) {
#pragma unroll
            for (int i = 0; i < 8; ++i) {
                int c = tid + i * 256;
                int row = c >> 4, kc = (c & 15) * 4;
                float4 v = *(const float4*)&Af[(size_t)(bm + row) * K + k0 + kc];
                ushort4 b;
                b.x = f2bf(v.x); b.y = f2bf(v.y); b.z = f2bf(v.z); b.w = f2bf(v.w);
                *(ushort4*)&As[row][kc] = b;
            }
        } else if constexpr (ASRC == 3) {
#pragma unroll
            for (int i = 0; i < 8; ++i) {
                int c = tid + i * 256;
                int row = c >> 4, kc = (c & 15) * 4;
                float dv = (float)(bm + row) * TABSTEP;
                ushort4 b;
                unsigned short* bp = (unsigned short*)&b;
#pragma unroll
                for (int j = 0; j < 4; ++j) {
                    int k = k0 + kc + j;
                    float f = 0.f;
                    if (k < K) {
                        float t = dv - (float)k * (10.0f / 49.0f);
                        f = __expf(-12.005f * t * t);
                    }
                    bp[j] = f2bf(f);
                }
                *(ushort4*)&As[row][kc] = b;
            }
        } else {
#pragma unroll
            for (int i = 0; i < 4; ++i) {
                int c = tid + i * 256;
                int row = c >> 3, kc = (c & 7) * 8;
                uint4 v = *(const uint4*)&Ab[(size_t)(bm + row) * K + k0 + kc];
                *(uint4*)&As[row][kc] = v;
            }
        }
        __syncthreads();
        // ---- MFMA ----
#pragma unroll
        for (int kk = 0; kk < 64; kk += 32) {
            s16x8 af[4], bf[4];
#pragma unroll
            for (int mi = 0; mi < 4; ++mi)
                af[mi] = *(const s16x8*)&As[wm * 64 + mi * 16 + rsel][kk + ksel];
#pragma unroll
            for (int ni = 0; ni < 4; ++ni)
                bf[ni] = *(const s16x8*)&Bs[wn * 64 + ni * 16 + rsel][kk + ksel];
#pragma unroll
            for (int mi = 0; mi < 4; ++mi)
#pragma unroll
                for (int ni = 0; ni < 4; ++ni)
                    acc[mi][ni] = __builtin_amdgcn_mfma_f32_16x16x32_bf16(
                        af[mi], bf[ni], acc[mi][ni], 0, 0, 0);
        }
        __syncthreads();
    }

    // ---- epilogue ----
#pragma unroll
    for (int mi = 0; mi < 4; ++mi) {
#pragma unroll
        for (int r = 0; r < 4; ++r) {
            int m = bm + wm * 64 + mi * 16 + ((lane >> 4) << 2) + r;
#pragma unroll
            for (int ni = 0; ni < 4; ++ni) {
                int n = bn + wn * 64 + ni * 16 + (lane & 15);
                float v = acc[mi][ni][r];
                if (bias) v += bias[n];
                if constexpr (EPI == 0) {
                    Cf[(size_t)m * ldc + n] = v;
                } else if constexpr (EPI == 1) {
                    Cf[(size_t)m * ldc + n] = fmaxf(v, 0.f);
                } else if constexpr (EPI == 2) {
                    Cb[(size_t)m * ldc + n] = f2bf(fmaxf(v, 0.f));
                } else {  // EPI == 6
                    Cb[(size_t)m * ldc + n] = f2bf(v);
                }
            }
        }
    }
}

// ---------------- fused combine: X = relu(X + relu(HAGG@lin2+b2)@linw + b + Z2) ----
// 512 threads, 8 waves (2 m x 4 n), tile 128 rows x 256 cols, H2 kept in LDS.
__global__ __launch_bounds__(512) void k_combine(
    const unsigned short* __restrict__ HAGG,   // [NC][128] bf16
    const unsigned short* __restrict__ lin2t,  // [256][128] bf16 (n-major)
    const float* __restrict__ lin2b,           // [256]
    const unsigned short* __restrict__ linwt,  // [256][256] bf16 (n-major)
    const float* __restrict__ linb,            // [256]
    const float* __restrict__ Z2,              // [NG][256] f32
    unsigned short* __restrict__ X)            // [NC][256] bf16 (RMW)
{
    __shared__ unsigned short As[128][72];
    __shared__ unsigned short Bs[256][72];
    __shared__ unsigned short H2s[128][264];   // 264 odd*8 -> conflict-free reads
    const int tid = threadIdx.x;
    const int bm = blockIdx.x * 128;
    const int lane = tid & 63;
    const int wid = tid >> 6;
    const int wm = wid >> 2, wn = wid & 3;
    const int rsel = lane & 15, ksel = (lane >> 4) * 8;

    f32x4 acc[4][4];
#pragma unroll
    for (int a = 0; a < 4; ++a)
#pragma unroll
        for (int b = 0; b < 4; ++b) acc[a][b] = (f32x4){0.f, 0.f, 0.f, 0.f};

    // ---- stage 1: H2 = relu(HAGG @ lin2 + b2), K = 128 ----
    for (int k0 = 0; k0 < 128; k0 += 64) {
#pragma unroll
        for (int i = 0; i < 2; ++i) {
            int c = tid + i * 512;
            int row = c >> 3, kc = (c & 7) * 8;
            *(uint4*)&As[row][kc] =
                *(const uint4*)&HAGG[(size_t)(bm + row) * 128 + k0 + kc];
        }
#pragma unroll
        for (int i = 0; i < 4; ++i) {
            int c = tid + i * 512;
            int row = c >> 3, kc = (c & 7) * 8;
            *(uint4*)&Bs[row][kc] = *(const uint4*)&lin2t[(size_t)row * 128 + k0 + kc];
        }
        __syncthreads();
#pragma unroll
        for (int kk = 0; kk < 64; kk += 32) {
            s16x8 af[4], bf[4];
#pragma unroll
            for (int mi = 0; mi < 4; ++mi)
                af[mi] = *(const s16x8*)&As[wm * 64 + mi * 16 + rsel][kk + ksel];
#pragma unroll
            for (int ni = 0; ni < 4; ++ni)
                bf[ni] = *(const s16x8*)&Bs[wn * 64 + ni * 16 + rsel][kk + ksel];
#pragma unroll
            for (int mi = 0; mi < 4; ++mi)
#pragma unroll
                for (int ni = 0; ni < 4; ++ni)
                    acc[mi][ni] = __builtin_amdgcn_mfma_f32_16x16x32_bf16(
                        af[mi], bf[ni], acc[mi][ni], 0, 0, 0);
        }
        __syncthreads();
    }
    // epilogue 1 -> LDS (bf16, relu+bias)
#pragma unroll
    for (int mi = 0; mi < 4; ++mi)
#pragma unroll
        for (int r = 0; r < 4; ++r) {
            int mrow = wm * 64 + mi * 16 + ((lane >> 4) << 2) + r;
#pragma unroll
            for (int ni = 0; ni < 4; ++ni) {
                int n = wn * 64 + ni * 16 + (lane & 15);
                H2s[mrow][n] = f2bf(fmaxf(acc[mi][ni][r] + lin2b[n], 0.f));
            }
        }

    // ---- stage 2: X = relu(X + H2 @ linw + b + Z2), K = 256, A from LDS ----
#pragma unroll
    for (int a = 0; a < 4; ++a)
#pragma unroll
        for (int b = 0; b < 4; ++b) acc[a][b] = (f32x4){0.f, 0.f, 0.f, 0.f};
    for (int k0 = 0; k0 < 256; k0 += 64) {
#pragma unroll
        for (int i = 0; i < 4; ++i) {
            int c = tid + i * 512;
            int row = c >> 3, kc = (c & 7) * 8;
            *(uint4*)&Bs[row][kc] = *(const uint4*)&linwt[(size_t)row * 256 + k0 + kc];
        }
        __syncthreads();   // covers H2s writes (first iter) + Bs staging
#pragma unroll
        for (int kk = 0; kk < 64; kk += 32) {
            s16x8 af[4], bf[4];
#pragma unroll
            for (int mi = 0; mi < 4; ++mi)
                af[mi] = *(const s16x8*)&H2s[wm * 64 + mi * 16 + rsel][k0 + kk + ksel];
#pragma unroll
            for (int ni = 0; ni < 4; ++ni)
                bf[ni] = *(const s16x8*)&Bs[wn * 64 + ni * 16 + rsel][kk + ksel];
#pragma unroll
            for (int mi = 0; mi < 4; ++mi)
#pragma unroll
                for (int ni = 0; ni < 4; ++ni)
                    acc[mi][ni] = __builtin_amdgcn_mfma_f32_16x16x32_bf16(
                        af[mi], bf[ni], acc[mi][ni], 0, 0, 0);
        }
        __syncthreads();
    }
    // epilogue 2: RMW X (bf16) + bias + Z2 gather + relu
#pragma unroll
    for (int mi = 0; mi < 4; ++mi)
#pragma unroll
        for (int r = 0; r < 4; ++r) {
            int m = bm + wm * 64 + mi * 16 + ((lane >> 4) << 2) + r;
            const float* z2row = &Z2[(size_t)(m & (NG - 1)) * 256];
#pragma unroll
            for (int ni = 0; ni < 4; ++ni) {
                int n = wn * 64 + ni * 16 + (lane & 15);
                size_t ix = (size_t)m * 256 + n;
                float o = bf2f(X[ix]) + acc[mi][ni][r] + linb[n] + z2row[n];
                X[ix] = f2bf(fmaxf(o, 0.f));
            }
        }
}

// ---------------- launch ----------------
extern "C" void kernel_launch(void* const* d_in, const int* in_sizes, int n_in,
                              void* d_out, int out_size, void* d_ws, size_t ws_size,
                              hipStream_t stream)
{
    (void)in_sizes; (void)n_in; (void)out_size; (void)ws_size;
    const float* pos       = (const float*)d_in[0];
    const float* atom_emb  = (const float*)d_in[1];
    const float* vn_emb    = (const float*)d_in[2];
    const float* cf_lin1   = (const float*)d_in[3];
    const float* cf_mlp_w1 = (const float*)d_in[4];
    const float* cf_mlp_b1 = (const float*)d_in[5];
    const float* cf_mlp_w2 = (const float*)d_in[6];
    const float* cf_mlp_b2 = (const float*)d_in[7];
    const float* cf_lin2   = (const float*)d_in[8];
    const float* cf_lin2_b = (const float*)d_in[9];
    const float* lin_w     = (const float*)d_in[10];
    const float* lin_b     = (const float*)d_in[11];
    const float* bond_emb  = (const float*)d_in[12];
    const float* gin_eps   = (const float*)d_in[13];
    const float* gin_w1    = (const float*)d_in[14];
    const float* gin_b1    = (const float*)d_in[15];
    const float* gin_g1    = (const float*)d_in[16];
    const float* gin_be1   = (const float*)d_in[17];
    const float* gin_w2    = (const float*)d_in[18];
    const float* gin_b2    = (const float*)d_in[19];
    const float* bn_g      = (const float*)d_in[20];
    const float* bn_b      = (const float*)d_in[21];
    const float* vn_w1     = (const float*)d_in[22];
    const float* vn_b1     = (const float*)d_in[23];
    const float* vn_w2     = (const float*)d_in[24];
    const float* vn_b2     = (const float*)d_in[25];
    const float* out_w1    = (const float*)d_in[26];
    const float* out_b1    = (const float*)d_in[27];
    const float* out_w2    = (const float*)d_in[28];
    const float* out_b2    = (const float*)d_in[29];
    const int* x_atom      = (const int*)d_in[30];
    const int* ei_conf     = (const int*)d_in[34];
    const int* ei_graph    = (const int*)d_in[35];
    const int* attr_graph  = (const int*)d_in[36];
    float* out = (float*)d_out;
    float* ws  = (float*)d_ws;

    size_t o = 0;
    float* AGG  = ws + o; o += (size_t)NG * H;
    float* Z1   = ws + o; o += (size_t)NG * H;
    float* Z2   = ws + o; o += (size_t)NG * H;
    float* VN   = ws + o; o += (size_t)NCONF * H;
    float* TMP  = ws + o; o += (size_t)NCONF * H;
    float* TMP2 = ws + o; o += (size_t)NCONF * H;
    float* XM   = ws + o; o += (size_t)NMOL * H;
    float* Y1   = ws + o; o += (size_t)NMOL * H;
    float* STATS= ws + o; o += 512;
    float* PDCC = ws + o; o += (size_t)2 * EC;      // float2[EC]
    // bf16 regions
    unsigned short* XB   = (unsigned short*)(ws + o); o += (size_t)NC * H / 2;
    unsigned short* XA   = (unsigned short*)(ws + o); o += (size_t)NG * H / 2;
    unsigned short* CFH  = (unsigned short*)(ws + o); o += (size_t)NC * F / 2;
    unsigned short* HAGG = (unsigned short*)(ws + o); o += (size_t)NC * F / 2;
    unsigned short* TT1  = (unsigned short*)(ws + o); o += (size_t)NTAB * F / 2;
    unsigned short* TAB  = (unsigned short*)(ws + o); o += (size_t)NTAB * F / 2;
    // int region
    int* PSRC   = (int*)(ws + o); o += EC;
    int* PGSRC  = (int*)(ws + o); o += EG;
    int* PATTR  = (int*)(ws + o); o += EG;
    int* CNT    = (int*)(ws + o); o += NC;
    int* ROWC   = (int*)(ws + o); o += NC + 64;
    int* CURC   = (int*)(ws + o); o += NC;
    int* ROWG   = (int*)(ws + o); o += NG + 64;
    int* CURG   = (int*)(ws + o); o += NG;
    int* BSUM   = (int*)(ws + o); o += 256;
    // transposed bf16 weights
    unsigned short* WT = (unsigned short*)(ws + o);
    size_t wo = 0;
    unsigned short* lin1t = WT + wo; wo += (size_t)NLAYERS * 128 * 256;
    unsigned short* w1t   = WT + wo; wo += (size_t)NLAYERS * 128 * 64;
    unsigned short* w2t   = WT + wo; wo += (size_t)NLAYERS * 128 * 128;
    unsigned short* lin2t = WT + wo; wo += (size_t)NLAYERS * 256 * 128;
    unsigned short* linwt = WT + wo; wo += (size_t)NLAYERS * 256 * 256;
    unsigned short* g1t   = WT + wo; wo += (size_t)NLAYERS * 256 * 256;
    unsigned short* g2t   = WT + wo; wo += (size_t)NLAYERS * 256 * 256;
    unsigned short* vn1t  = WT + wo; wo += 256 * 256;
    unsigned short* vn2t  = WT + wo; wo += 256 * 256;
    unsigned short* ow1t  = WT + wo; wo += 256 * 256;

    // ---- weight prep ----
    for (int i = 0; i < NLAYERS; ++i) {
        k_wt<<<128, 256, 0, stream>>>(cf_lin1 + (size_t)i * H * F,   lin1t + (size_t)i * 128 * 256, 256, 128, 256);
        k_wt<<<128, 256, 0, stream>>>(cf_mlp_w1 + (size_t)i * NGAUSS * F, w1t + (size_t)i * 128 * 64, NGAUSS, 128, 64);
        k_wt<<<128, 256, 0, stream>>>(cf_mlp_w2 + (size_t)i * F * F, w2t + (size_t)i * 128 * 128, 128, 128, 128);
        k_wt<<<256, 256, 0, stream>>>(cf_lin2 + (size_t)i * F * H,   lin2t + (size_t)i * 256 * 128, 128, 256, 128);
        k_wt<<<256, 256, 0, stream>>>(lin_w + (size_t)i * H * H,     linwt + (size_t)i * 256 * 256, 256, 256, 256);
        k_wt<<<256, 256, 0, stream>>>(gin_w1 + (size_t)i * H * H,    g1t + (size_t)i * 256 * 256, 256, 256, 256);
        k_wt<<<256, 256, 0, stream>>>(gin_w2 + (size_t)i * H * H,    g2t + (size_t)i * 256 * 256, 256, 256, 256);
    }
    k_wt<<<256, 256, 0, stream>>>(vn_w1, vn1t, 256, 256, 256);
    k_wt<<<256, 256, 0, stream>>>(vn_w2, vn2t, 256, 256, 256);
    k_wt<<<256, 256, 0, stream>>>(out_w1, ow1t, 256, 256, 256);

    // ---- dst-sort both edge lists (once; content is launch-invariant) ----
    hipMemsetAsync(CNT, 0, NC * sizeof(int), stream);
    k_hist<<<EC / 256, 256, 0, stream>>>(ei_conf + EC, CNT, EC);
    k_scan1<<<NC / 256, 256, 0, stream>>>(CNT, ROWC, BSUM);
    k_scan2<<<1, 256, 0, stream>>>(BSUM, NC / 256);
    k_scan3<<<NC / 256, 256, 0, stream>>>(ROWC, BSUM, CURC, NC, EC);
    k_cperm<<<EC / 256, 256, 0, stream>>>(pos, ei_conf, CURC, PSRC, (float2*)PDCC);

    hipMemsetAsync(CNT, 0, NG * sizeof(int), stream);
    k_hist<<<EG / 256, 256, 0, stream>>>(ei_graph + EG, CNT, EG);
    k_scan1<<<NG / 256, 256, 0, stream>>>(CNT, ROWG, BSUM);
    k_scan2<<<1, 256, 0, stream>>>(BSUM, NG / 256);
    k_scan3<<<NG / 256, 256, 0, stream>>>(ROWG, BSUM, CURG, NG, EG);
    k_gperm<<<EG / 256, 256, 0, stream>>>(ei_graph, attr_graph, CURG, PGSRC, PATTR);

    k_init_x<<<NC, 256, 0, stream>>>(atom_emb, x_atom, XB);
    k_vninit<<<NCONF, 256, 0, stream>>>(vn_emb, VN);

    for (int i = 0; i < NLAYERS; ++i) {
        // fused addvn + vn_tmp + xa
        if (i < NLAYERS - 1) {
            k_pre<true><<<NMOL, 256, 0, stream>>>(XB, VN, TMP, XA);
            mgemm<0, 1><<<dim3(2, NCONF / 128), 256, 0, stream>>>(
                TMP, 0, vn1t, vn_b1, TMP2, 0, 256, 256, 256);
            mgemm<0, 1><<<dim3(2, NCONF / 128), 256, 0, stream>>>(
                TMP2, 0, vn2t, vn_b2, VN, 0, 256, 256, 256);
        } else {
            k_pre<false><<<NMOL, 256, 0, stream>>>(XB, VN, TMP, XA);
        }
        // ---- CFConv ----
        // edge-MLP lookup table for this layer: TAB[i] = mlp(gauss(i*step))
        mgemm<3, 2><<<dim3(1, NTAB / 128), 256, 0, stream>>>(
            0, 0, w1t + (size_t)i * 128 * 64, cf_mlp_b1 + i * F,
            0, TT1, NGAUSS, 64, 128);
        mgemm<2, 6><<<dim3(1, NTAB / 128), 256, 0, stream>>>(
            0, TT1, w2t + (size_t)i * 128 * 128, cf_mlp_b2 + i * F,
            0, TAB, 128, 128, 128);
        // cfh = x @ cf_lin1 (bf16 in, bf16 out)
        mgemm<2, 6><<<dim3(1, NC / 128), 256, 0, stream>>>(
            0, XB, lin1t + (size_t)i * 128 * 256, nullptr, 0, CFH,
            256, 256, 128);
        // per-node gather-aggregate with table interp (pure write, no atomics)
        k_cf_agg<<<NC / 8, 256, 0, stream>>>(TAB, ROWC, PSRC, (const float2*)PDCC,
                                             CFH, HAGG);
        // ---- GIN ----
        k_gin_agg<<<NG, 256, 0, stream>>>(
            XA, bond_emb + (size_t)i * 3 * 8 * H, ROWG, PGSRC, PATTR,
            gin_eps + i, AGG);
        mgemm<0, 0><<<dim3(2, NG / 128), 256, 0, stream>>>(
            AGG, 0, g1t + (size_t)i * 256 * 256, gin_b1 + i * H, Z1, 0,
            256, 256, 256);
        hipMemsetAsync(STATS, 0, 2048, stream);
        k_bnstats<<<64, 256, 0, stream>>>(Z1, STATS);
        k_bnapply<true><<<NG, 256, 0, stream>>>(Z1, STATS, gin_g1 + i * H, gin_be1 + i * H);
        mgemm<0, 0><<<dim3(2, NG / 128), 256, 0, stream>>>(
            Z1, 0, g2t + (size_t)i * 256 * 256, gin_b2 + i * H, Z2, 0,
            256, 256, 256);
        hipMemsetAsync(STATS, 0, 2048, stream);
        k_bnstats<<<64, 256, 0, stream>>>(Z2, STATS);
        k_bnapply<false><<<NG, 256, 0, stream>>>(Z2, STATS, bn_g + i * H, bn_b + i * H);
        // ---- fused combine ----
        k_combine<<<NC / 128, 512, 0, stream>>>(
            HAGG, lin2t + (size_t)i * 256 * 128, cf_lin2_b + i * H,
            linwt + (size_t)i * 256 * 256, lin_b + i * H, Z2, XB);
    }

    k_molmax<<<NMOL, 256, 0, stream>>>(XB, XM);
    mgemm<0, 1><<<dim3(2, NMOL / 128), 256, 0, stream>>>(
        XM, 0, ow1t, out_b1, Y1, 0, 256, 256, 256);
    k_head<<<NMOL, 256, 0, stream>>>(Y1, out_w2, out_b2, out);
}

// Round 8
// 984.892 us; speedup vs baseline: 9.2512x; 1.3104x over previous
//
#include <hip/hip_runtime.h>
#include <math.h>

#define H 256
#define F 128
#define NLAYERS 4
#define NG 8192
#define NC 65536
#define EC 524288
#define EG 32768
#define NCONF 4096
#define NMOL 512
#define NGAUSS 50
#define NTAB 8192
#define TABSTEP 0.001953125f   // 16 / 8192
#define INVSTEP 512.0f

using s16x8 = __attribute__((ext_vector_type(8))) short;
using f32x4 = __attribute__((ext_vector_type(4))) float;

static __device__ __forceinline__ unsigned short f2bf(float f) {
    unsigned int u = __float_as_uint(f);
    u += 0x7fffu + ((u >> 16) & 1u);   // RNE (finite values)
    return (unsigned short)(u >> 16);
}
static __device__ __forceinline__ float bf2f(unsigned short b) {
    return __uint_as_float(((unsigned int)b) << 16);
}
static __device__ __forceinline__ float bflo(unsigned int u) {
    return __uint_as_float(u << 16);
}
static __device__ __forceinline__ float bfhi(unsigned int u) {
    return __uint_as_float(u & 0xffff0000u);
}

// ---------------- elementwise / fused kernels ----------------

__global__ __launch_bounds__(256) void k_init_x(const float* __restrict__ atom_emb,
    const int* __restrict__ x_atom, unsigned short* __restrict__ x)
{
    int i = blockIdx.x, h = threadIdx.x;
    int g = i & (NG - 1);
    float s = 0.f;
#pragma unroll
    for (int f = 0; f < 9; ++f) {
        int a = x_atom[g * 9 + f];
        s += atom_emb[(f * 64 + a) * H + h];
    }
    x[(size_t)i * H + h] = f2bf(s);
}

__global__ __launch_bounds__(256) void k_vninit(const float* __restrict__ vn_emb,
                                                float* __restrict__ vn)
{
    vn[(size_t)blockIdx.x * H + threadIdx.x] = vn_emb[threadIdx.x];
}

// fused per-molecule: X += VN[pos_batch]; TMP[c] = vn[c]+sum_t X'; XA[g] = max_r X'
template <bool DOTMP>
__global__ __launch_bounds__(256) void k_pre(unsigned short* __restrict__ X,
    const float* __restrict__ vn, float* __restrict__ tmp,
    unsigned short* __restrict__ xa)
{
    int m = blockIdx.x, h = threadIdx.x;
    float xam[16];
#pragma unroll
    for (int t = 0; t < 16; ++t) xam[t] = -3.4e38f;
#pragma unroll 2
    for (int r = 0; r < 8; ++r) {
        float vv = vn[(size_t)(m * 8 + r) * H + h];
        float ts = vv;
        size_t base = ((size_t)r * NG + m * 16) * H + h;
#pragma unroll
        for (int t = 0; t < 16; ++t) {
            float v = bf2f(X[base + (size_t)t * H]) + vv;
            X[base + (size_t)t * H] = f2bf(v);
            xam[t] = fmaxf(xam[t], v);
            ts += v;
        }
        if (DOTMP) tmp[(size_t)(m * 8 + r) * H + h] = ts;
    }
#pragma unroll
    for (int t = 0; t < 16; ++t)
        xa[(size_t)(m * 16 + t) * H + h] = f2bf(xam[t]);
}

// stats[n],stats[256+n] -> scale/shift
__global__ __launch_bounds__(256) void k_bnprep(const float* __restrict__ stats,
    const float* __restrict__ gamma, const float* __restrict__ beta,
    float* __restrict__ scale, float* __restrict__ shift)
{
    int n = threadIdx.x;
    float mean = stats[n] * (1.0f / NG);
    float var = stats[256 + n] * (1.0f / NG) - mean * mean;
    float sc = gamma[n] * rsqrtf(var + 1e-5f);
    scale[n] = sc;
    shift[n] = beta[n] - mean * sc;
}

__global__ __launch_bounds__(256) void k_molmax(const unsigned short* __restrict__ x,
                                                float* __restrict__ xm)
{
    int m = blockIdx.x, h = threadIdx.x;
    float best = -3.4e38f;
    for (int r = 0; r < 8; ++r) {
        size_t base = ((size_t)r * NG + m * 16) * H + h;
#pragma unroll 4
        for (int t = 0; t < 16; ++t) best = fmaxf(best, bf2f(x[base + (size_t)t * H]));
    }
    xm[(size_t)m * H + h] = best;
}

__global__ __launch_bounds__(256) void k_head(const float* __restrict__ y1,
    const float* __restrict__ w2, const float* __restrict__ b2,
    float* __restrict__ out)
{
    __shared__ float red[256];
    int m = blockIdx.x, h = threadIdx.x;
    red[h] = y1[(size_t)m * H + h] * w2[h];
    __syncthreads();
    for (int s = 128; s > 0; s >>= 1) {
        if (h < s) red[h] += red[h + s];
        __syncthreads();
    }
    if (h == 0) out[m] = red[0] + b2[0];
}

// weight transpose+convert with layer grid: Wt[l][n][k] = bf16(W[l][k][n])
__global__ __launch_bounds__(256) void k_wt(const float* __restrict__ W,
    unsigned short* __restrict__ Wt, int K, int N, int Kp)
{
    int l = blockIdx.y;
    W += (size_t)l * K * N;
    Wt += (size_t)l * N * Kp;
    int n = blockIdx.x;
    for (int k = threadIdx.x; k < Kp; k += 256)
        Wt[(size_t)n * Kp + k] = (k < K) ? f2bf(W[(size_t)k * N + n]) : (unsigned short)0;
}

// ---------------- counting sort by destination ----------------

__global__ __launch_bounds__(256) void k_hist(const int* __restrict__ dst,
                                              int* __restrict__ cnt, int ne)
{
    int e = blockIdx.x * 256 + threadIdx.x;
    if (e < ne) atomicAdd(&cnt[dst[e]], 1);
}

__global__ __launch_bounds__(256) void k_scan1(const int* __restrict__ cnt,
    int* __restrict__ part, int* __restrict__ bsum)
{
    __shared__ int sh[256];
    int t = threadIdx.x, idx = blockIdx.x * 256 + t;
    int v = cnt[idx];
    sh[t] = v; __syncthreads();
    for (int s = 1; s < 256; s <<= 1) {
        int add = (t >= s) ? sh[t - s] : 0;
        __syncthreads();
        sh[t] += add;
        __syncthreads();
    }
    part[idx] = sh[t] - v;
    if (t == 255) bsum[blockIdx.x] = sh[255];
}

__global__ __launch_bounds__(256) void k_scan2(int* __restrict__ bsum, int nb)
{
    __shared__ int sh[256];
    int t = threadIdx.x;
    int v = (t < nb) ? bsum[t] : 0;
    sh[t] = v; __syncthreads();
    for (int s = 1; s < 256; s <<= 1) {
        int add = (t >= s) ? sh[t - s] : 0;
        __syncthreads();
        sh[t] += add;
        __syncthreads();
    }
    if (t < nb) bsum[t] = sh[t] - v;
}

__global__ __launch_bounds__(256) void k_scan3(int* __restrict__ part,
    const int* __restrict__ bsum, int* __restrict__ cursor, int nbins, int total)
{
    int idx = blockIdx.x * 256 + threadIdx.x;
    int v = part[idx] + bsum[blockIdx.x];
    part[idx] = v;
    cursor[idx] = v;
    if (idx == 0) part[nbins] = total;
}

__global__ __launch_bounds__(256) void k_cperm(const float* __restrict__ pos,
    const int* __restrict__ ei, int* __restrict__ cursor,
    int* __restrict__ psrc, float2* __restrict__ pdcc)
{
    int e = blockIdx.x * 256 + threadIdx.x;
    int s = ei[e], t = ei[EC + e];
    float dx = pos[s * 3 + 0] - pos[t * 3 + 0];
    float dy = pos[s * 3 + 1] - pos[t * 3 + 1];
    float dz = pos[s * 3 + 2] - pos[t * 3 + 2];
    float dd = sqrtf(dx * dx + dy * dy + dz * dz);
    int p = atomicAdd(&cursor[t], 1);
    psrc[p] = s;
    pdcc[p] = make_float2(dd, 0.5f * (cosf(dd * 0.314159265358979f) + 1.0f));
}

__global__ __launch_bounds__(256) void k_gperm(const int* __restrict__ ei,
    const int* __restrict__ attr, int* __restrict__ cursor,
    int* __restrict__ pgsrc, int* __restrict__ pattr)
{
    int e = blockIdx.x * 256 + threadIdx.x;
    int s = ei[e], t = ei[EG + e];
    int p = atomicAdd(&cursor[t], 1);
    pgsrc[p] = s;
    pattr[p] = attr[e * 3] | (attr[e * 3 + 1] << 4) | (attr[e * 3 + 2] << 8);
}

// ---------------- gather-based aggregations (no atomics) ----------------

// 8 channels/thread, 16 lanes/node, 16 nodes/block. Nearest-neighbor table.
__global__ __launch_bounds__(256) void k_cf_agg(const unsigned short* __restrict__ tab,
    const int* __restrict__ rowptr, const int* __restrict__ psrc,
    const float2* __restrict__ pdcc,
    const unsigned short* __restrict__ cfh, unsigned short* __restrict__ hagg)
{
    int slot = threadIdx.x >> 4;
    int c8 = (threadIdx.x & 15) << 3;
    int n = blockIdx.x * 16 + slot;
    int lo = rowptr[n], hi = rowptr[n + 1];
    float a[8] = {0.f, 0.f, 0.f, 0.f, 0.f, 0.f, 0.f, 0.f};
    for (int e = lo; e < hi; ++e) {
        int s = psrc[e];
        float2 dc = pdcc[e];
        float u = dc.x * INVSTEP + 0.5f;
        int it = (int)u;
        if (it > NTAB - 1) it = NTAB - 1;
        uint4 T = *(const uint4*)&tab[(size_t)it * F + c8];
        uint4 HV = *(const uint4*)&cfh[(size_t)s * F + c8];
        float cc = dc.y;
        a[0] = fmaf(bflo(T.x) * cc, bflo(HV.x), a[0]);
        a[1] = fmaf(bfhi(T.x) * cc, bfhi(HV.x), a[1]);
        a[2] = fmaf(bflo(T.y) * cc, bflo(HV.y), a[2]);
        a[3] = fmaf(bfhi(T.y) * cc, bfhi(HV.y), a[3]);
        a[4] = fmaf(bflo(T.z) * cc, bflo(HV.z), a[4]);
        a[5] = fmaf(bfhi(T.z) * cc, bfhi(HV.z), a[5]);
        a[6] = fmaf(bflo(T.w) * cc, bflo(HV.w), a[6]);
        a[7] = fmaf(bfhi(T.w) * cc, bfhi(HV.w), a[7]);
    }
    uint4 o;
    o.x = ((unsigned)f2bf(a[1]) << 16) | f2bf(a[0]);
    o.y = ((unsigned)f2bf(a[3]) << 16) | f2bf(a[2]);
    o.z = ((unsigned)f2bf(a[5]) << 16) | f2bf(a[4]);
    o.w = ((unsigned)f2bf(a[7]) << 16) | f2bf(a[6]);
    *(uint4*)&hagg[(size_t)n * F + c8] = o;
}

// AGG[g] = bf16((1+eps)*xa[g] + sum_e relu(xa[pgsrc[e]] + bond_sum))
__global__ __launch_bounds__(256) void k_gin_agg(const unsigned short* __restrict__ xa,
    const float* __restrict__ bond, const int* __restrict__ growptr,
    const int* __restrict__ pgsrc, const int* __restrict__ pattr,
    const float* __restrict__ eps_p, unsigned short* __restrict__ agg)
{
    int g = blockIdx.x, h = threadIdx.x;
    int lo = growptr[g], hi = growptr[g + 1];
    float acc = 0.f;
    for (int e = lo; e < hi; ++e) {
        int s = pgsrc[e], a = pattr[e];
        float v = bf2f(xa[(size_t)s * H + h])
                + bond[(a & 15) * H + h]
                + bond[(8 + ((a >> 4) & 15)) * H + h]
                + bond[(16 + (a >> 8)) * H + h];
        acc += fmaxf(v, 0.f);
    }
    agg[(size_t)g * H + h] =
        f2bf((1.0f + eps_p[0]) * bf2f(xa[(size_t)g * H + h]) + acc);
}

// ---------------- MFMA GEMM ----------------
// tile 128x128, BK=64, 4 waves.
// ASRC: 0 = f32 A, 2 = bf16 A, 4 = f32 A with scale/shift+relu (fused BN)
// EPI:  1 = relu->Cf, 6 = ->bf16 Cb, 7 = ->Cf + column stats atomics
template<int ASRC, int EPI>
__global__ __launch_bounds__(256) void mgemm(
    const float* __restrict__ Af, const unsigned short* __restrict__ Ab,
    const unsigned short* __restrict__ Bt,
    const float* __restrict__ bias,
    float* __restrict__ Cf, unsigned short* __restrict__ Cb,
    int K, int Kp, int ldc,
    const float* __restrict__ sca, const float* __restrict__ sha,
    float* __restrict__ stats_out)
{
    __shared__ unsigned short As[128][72];
    __shared__ unsigned short Bs[128][72];
    const int tid = threadIdx.x;
    const int bm = blockIdx.y * 128;
    const int bn = blockIdx.x * 128;
    const int lane = tid & 63;
    const int wid = tid >> 6;
    const int wm = wid >> 1, wn = wid & 1;
    const int rsel = lane & 15, ksel = (lane >> 4) * 8;

    f32x4 acc[4][4];
#pragma unroll
    for (int a = 0; a < 4; ++a)
#pragma unroll
        for (int b = 0; b < 4; ++b) acc[a][b] = (f32x4){0.f, 0.f, 0.f, 0.f};

    for (int k0 = 0; k0 < Kp; k0 += 64) {
#pragma unroll
        for (int i = 0; i < 4; ++i) {
            int c = tid + i * 256;
            int row = c >> 3, kc = (c & 7) * 8;
            *(uint4*)&Bs[row][kc] =
                *(const uint4*)&Bt[(size_t)(bn + row) * Kp + k0 + kc];
        }
        if constexpr (ASRC == 0 || ASRC == 4) {
#pragma unroll
            for (int i = 0; i < 8; ++i) {
                int c = tid + i * 256;
                int row = c >> 4, kc = (c & 15) * 4;
                float4 v = *(const float4*)&Af[(size_t)(bm + row) * K + k0 + kc];
                if constexpr (ASRC == 4) {
                    float4 s4 = *(const float4*)&sca[k0 + kc];
                    float4 h4 = *(const float4*)&sha[k0 + kc];
                    v.x = fmaxf(fmaf(v.x, s4.x, h4.x), 0.f);
                    v.y = fmaxf(fmaf(v.y, s4.y, h4.y), 0.f);
                    v.z = fmaxf(fmaf(v.z, s4.z, h4.z), 0.f);
                    v.w = fmaxf(fmaf(v.w, s4.w, h4.w), 0.f);
                }
                ushort4 b;
                b.x = f2bf(v.x); b.y = f2bf(v.y); b.z = f2bf(v.z); b.w = f2bf(v.w);
                *(ushort4*)&As[row][kc] = b;
            }
        } else {
#pragma unroll
            for (int i = 0; i < 4; ++i) {
                int c = tid + i * 256;
                int row = c >> 3, kc = (c & 7) * 8;
                *(uint4*)&As[row][kc] =
                    *(const uint4*)&Ab[(size_t)(bm + row) * K + k0 + kc];
            }
        }
        __syncthreads();
#pragma unroll
        for (int kk = 0; kk < 64; kk += 32) {
            s16x8 af[4], bf[4];
#pragma unroll
            for (int mi = 0; mi < 4; ++mi)
                af[mi] = *(const s16x8*)&As[wm * 64 + mi * 16 + rsel][kk + ksel];
#pragma unroll
            for (int ni = 0; ni < 4; ++ni)
                bf[ni] = *(const s16x8*)&Bs[wn * 64 + ni * 16 + rsel][kk + ksel];
#pragma unroll
            for (int mi = 0; mi < 4; ++mi)
#pragma unroll
                for (int ni = 0; ni < 4; ++ni)
                    acc[mi][ni] = __builtin_amdgcn_mfma_f32_16x16x32_bf16(
                        af[mi], bf[ni], acc[mi][ni], 0, 0, 0);
        }
        __syncthreads();
    }

    float colS[4] = {0.f, 0.f, 0.f, 0.f};
    float colQ[4] = {0.f, 0.f, 0.f, 0.f};
#pragma unroll
    for (int mi = 0; mi < 4; ++mi) {
#pragma unroll
        for (int r = 0; r < 4; ++r) {
            int m = bm + wm * 64 + mi * 16 + ((lane >> 4) << 2) + r;
#pragma unroll
            for (int ni = 0; ni < 4; ++ni) {
                int n = bn + wn * 64 + ni * 16 + (lane & 15);
                float v = acc[mi][ni][r];
                if (bias) v += bias[n];
                if constexpr (EPI == 1) {
                    Cf[(size_t)m * ldc + n] = fmaxf(v, 0.f);
                } else if constexpr (EPI == 6) {
                    Cb[(size_t)m * ldc + n] = f2bf(v);
                } else {  // EPI == 7
                    Cf[(size_t)m * ldc + n] = v;
                    colS[ni] += v;
                    colQ[ni] = fmaf(v, v, colQ[ni]);
                }
            }
        }
    }
    if constexpr (EPI == 7) {
        float* cs = (float*)&As[0][0];
        cs[tid] = 0.f;
        __syncthreads();
#pragma unroll
        for (int ni = 0; ni < 4; ++ni) {
            int nl = wn * 64 + ni * 16 + (lane & 15);
            atomicAdd(&cs[nl], colS[ni]);
            atomicAdd(&cs[128 + nl], colQ[ni]);
        }
        __syncthreads();
        if (tid < 128) {
            atomicAdd(&stats_out[bn + tid], cs[tid]);
            atomicAdd(&stats_out[256 + bn + tid], cs[128 + tid]);
        }
    }
}

// ---------------- fused table build: TAB[l][i] = mlp_l(gauss(i*step)) ----------------
__global__ __launch_bounds__(256) void k_tab(
    const unsigned short* __restrict__ w1t,  // [L][128][64]
    const float* __restrict__ b1,            // [L][128]
    const unsigned short* __restrict__ w2t,  // [L][128][128]
    const float* __restrict__ b2,            // [L][128]
    unsigned short* __restrict__ tab)        // [L][NTAB][128]
{
    __shared__ unsigned short As[128][72];
    __shared__ unsigned short Bs[128][72];
    __shared__ unsigned short T1s[128][152];
    const int l = blockIdx.y;
    w1t += (size_t)l * 128 * 64;  b1 += l * 128;
    w2t += (size_t)l * 128 * 128; b2 += l * 128;
    tab += (size_t)l * NTAB * F;
    const int tid = threadIdx.x;
    const int bm = blockIdx.x * 128;
    const int lane = tid & 63, wid = tid >> 6;
    const int wm = wid >> 1, wn = wid & 1;
    const int rsel = lane & 15, ksel = (lane >> 4) * 8;

    f32x4 acc[4][4];
#pragma unroll
    for (int a = 0; a < 4; ++a)
#pragma unroll
        for (int b = 0; b < 4; ++b) acc[a][b] = (f32x4){0.f, 0.f, 0.f, 0.f};

    // stage 1: A = gauss rows (K=50 pad 64), B = w1t
#pragma unroll
    for (int i = 0; i < 8; ++i) {
        int c = tid + i * 256;
        int row = c >> 4, kc = (c & 15) * 4;
        float dv = (float)(bm + row) * TABSTEP;
        ushort4 b;
        unsigned short* bp = (unsigned short*)&b;
#pragma unroll
        for (int j = 0; j < 4; ++j) {
            int k = kc + j;
            float f = 0.f;
            if (k < NGAUSS) {
                float t = dv - (float)k * (10.0f / 49.0f);
                f = __expf(-12.005f * t * t);
            }
            bp[j] = f2bf(f);
        }
        *(ushort4*)&As[row][kc] = b;
    }
    // 128 rows x 8 chunks = 1024 chunks -> i < 4 with 256 threads (r7 bug: was i < 2)
#pragma unroll
    for (int i = 0; i < 4; ++i) {
        int c = tid + i * 256;
        int row = c >> 3, kc = (c & 7) * 8;
        *(uint4*)&Bs[row][kc] = *(const uint4*)&w1t[(size_t)row * 64 + kc];
    }
    __syncthreads();
#pragma unroll
    for (int kk = 0; kk < 64; kk += 32) {
        s16x8 af[4], bf[4];
#pragma unroll
        for (int mi = 0; mi < 4; ++mi)
            af[mi] = *(const s16x8*)&As[wm * 64 + mi * 16 + rsel][kk + ksel];
#pragma unroll
        for (int ni = 0; ni < 4; ++ni)
            bf[ni] = *(const s16x8*)&Bs[wn * 64 + ni * 16 + rsel][kk + ksel];
#pragma unroll
        for (int mi = 0; mi < 4; ++mi)
#pragma unroll
            for (int ni = 0; ni < 4; ++ni)
                acc[mi][ni] = __builtin_amdgcn_mfma_f32_16x16x32_bf16(
                    af[mi], bf[ni], acc[mi][ni], 0, 0, 0);
    }
    __syncthreads();
#pragma unroll
    for (int mi = 0; mi < 4; ++mi)
#pragma unroll
        for (int r = 0; r < 4; ++r) {
            int mrow = wm * 64 + mi * 16 + ((lane >> 4) << 2) + r;
#pragma unroll
            for (int ni = 0; ni < 4; ++ni) {
                int n = wn * 64 + ni * 16 + (lane & 15);
                T1s[mrow][n] = f2bf(fmaxf(acc[mi][ni][r] + b1[n], 0.f));
            }
        }
#pragma unroll
    for (int a = 0; a < 4; ++a)
#pragma unroll
        for (int b = 0; b < 4; ++b) acc[a][b] = (f32x4){0.f, 0.f, 0.f, 0.f};
    // stage 2: A = T1s (K=128), B = w2t
    for (int k0 = 0; k0 < 128; k0 += 64) {
        // 128 rows x 8 chunks = 1024 chunks -> i < 4 (r7 bug: was i < 2)
#pragma unroll
        for (int i = 0; i < 4; ++i) {
            int c = tid + i * 256;
            int row = c >> 3, kc = (c & 7) * 8;
            *(uint4*)&Bs[row][kc] = *(const uint4*)&w2t[(size_t)row * 128 + k0 + kc];
        }
        __syncthreads();
#pragma unroll
        for (int kk = 0; kk < 64; kk += 32) {
            s16x8 af[4], bf[4];
#pragma unroll
            for (int mi = 0; mi < 4; ++mi)
                af[mi] = *(const s16x8*)&T1s[wm * 64 + mi * 16 + rsel][k0 + kk + ksel];
#pragma unroll
            for (int ni = 0; ni < 4; ++ni)
                bf[ni] = *(const s16x8*)&Bs[wn * 64 + ni * 16 + rsel][kk + ksel];
#pragma unroll
            for (int mi = 0; mi < 4; ++mi)
#pragma unroll
                for (int ni = 0; ni < 4; ++ni)
                    acc[mi][ni] = __builtin_amdgcn_mfma_f32_16x16x32_bf16(
                        af[mi], bf[ni], acc[mi][ni], 0, 0, 0);
        }
        __syncthreads();
    }
#pragma unroll
    for (int mi = 0; mi < 4; ++mi)
#pragma unroll
        for (int r = 0; r < 4; ++r) {
            int m = bm + wm * 64 + mi * 16 + ((lane >> 4) << 2) + r;
#pragma unroll
            for (int ni = 0; ni < 4; ++ni) {
                int n = wn * 64 + ni * 16 + (lane & 15);
                tab[(size_t)m * F + n] = f2bf(acc[mi][ni][r] + b2[n]);
            }
        }
}

// ---------------- fused vn MLP: VN = relu(relu(TMP@w1+b1)@w2+b2) ----------------
__global__ __launch_bounds__(512) void k_vnmlp(
    const float* __restrict__ TMP,
    const unsigned short* __restrict__ w1, const float* __restrict__ b1,
    const unsigned short* __restrict__ w2, const float* __restrict__ b2,
    float* __restrict__ VN)
{
    __shared__ unsigned short As[128][72];
    __shared__ unsigned short Bs[256][72];
    __shared__ unsigned short Ts[128][264];
    const int tid = threadIdx.x;
    const int bm = blockIdx.x * 128;
    const int lane = tid & 63, wid = tid >> 6;
    const int wm = wid >> 2, wn = wid & 3;
    const int rsel = lane & 15, ksel = (lane >> 4) * 8;

    f32x4 acc[4][4];
#pragma unroll
    for (int a = 0; a < 4; ++a)
#pragma unroll
        for (int b = 0; b < 4; ++b) acc[a][b] = (f32x4){0.f, 0.f, 0.f, 0.f};
    for (int k0 = 0; k0 < 256; k0 += 64) {
#pragma unroll
        for (int i = 0; i < 4; ++i) {
            int c = tid + i * 512;
            int row = c >> 4, kc = (c & 15) * 4;
            float4 v = *(const float4*)&TMP[(size_t)(bm + row) * 256 + k0 + kc];
            ushort4 b;
            b.x = f2bf(v.x); b.y = f2bf(v.y); b.z = f2bf(v.z); b.w = f2bf(v.w);
            *(ushort4*)&As[row][kc] = b;
        }
#pragma unroll
        for (int i = 0; i < 4; ++i) {
            int c = tid + i * 512;
            int row = c >> 3, kc = (c & 7) * 8;
            *(uint4*)&Bs[row][kc] = *(const uint4*)&w1[(size_t)row * 256 + k0 + kc];
        }
        __syncthreads();
#pragma unroll
        for (int kk = 0; kk < 64; kk += 32) {
            s16x8 af[4], bf[4];
#pragma unroll
            for (int mi = 0; mi < 4; ++mi)
                af[mi] = *(const s16x8*)&As[wm * 64 + mi * 16 + rsel][kk + ksel];
#pragma unroll
            for (int ni = 0; ni < 4; ++ni)
                bf[ni] = *(const s16x8*)&Bs[wn * 64 + ni * 16 + rsel][kk + ksel];
#pragma unroll
            for (int mi = 0; mi < 4; ++mi)
#pragma unroll
                for (int ni = 0; ni < 4; ++ni)
                    acc[mi][ni] = __builtin_amdgcn_mfma_f32_16x16x32_bf16(
                        af[mi], bf[ni], acc[mi][ni], 0, 0, 0);
        }
        __syncthreads();
    }
#pragma unroll
    for (int mi = 0; mi < 4; ++mi)
#pragma unroll
        for (int r = 0; r < 4; ++r) {
            int mrow = wm * 64 + mi * 16 + ((lane >> 4) << 2) + r;
#pragma unroll
            for (int ni = 0; ni < 4; ++ni) {
                int n = wn * 64 + ni * 16 + (lane & 15);
                Ts[mrow][n] = f2bf(fmaxf(acc[mi][ni][r] + b1[n], 0.f));
            }
        }
#pragma unroll
    for (int a = 0; a < 4; ++a)
#pragma unroll
        for (int b = 0; b < 4; ++b) acc[a][b] = (f32x4){0.f, 0.f, 0.f, 0.f};
    for (int k0 = 0; k0 < 256; k0 += 64) {
#pragma unroll
        for (int i = 0; i < 4; ++i) {
            int c = tid + i * 512;
            int row = c >> 3, kc = (c & 7) * 8;
            *(uint4*)&Bs[row][kc] = *(const uint4*)&w2[(size_t)row * 256 + k0 + kc];
        }
        __syncthreads();
#pragma unroll
        for (int kk = 0; kk < 64; kk += 32) {
            s16x8 af[4], bf[4];
#pragma unroll
            for (int mi = 0; mi < 4; ++mi)
                af[mi] = *(const s16x8*)&Ts[wm * 64 + mi * 16 + rsel][k0 + kk + ksel];
#pragma unroll
            for (int ni = 0; ni < 4; ++ni)
                bf[ni] = *(const s16x8*)&Bs[wn * 64 + ni * 16 + rsel][kk + ksel];
#pragma unroll
            for (int mi = 0; mi < 4; ++mi)
#pragma unroll
                for (int ni = 0; ni < 4; ++ni)
                    acc[mi][ni] = __builtin_amdgcn_mfma_f32_16x16x32_bf16(
                        af[mi], bf[ni], acc[mi][ni], 0, 0, 0);
        }
        __syncthreads();
    }
#pragma unroll
    for (int mi = 0; mi < 4; ++mi)
#pragma unroll
        for (int r = 0; r < 4; ++r) {
            int m = bm + wm * 64 + mi * 16 + ((lane >> 4) << 2) + r;
#pragma unroll
            for (int ni = 0; ni < 4; ++ni) {
                int n = wn * 64 + ni * 16 + (lane & 15);
                VN[(size_t)m * 256 + n] = fmaxf(acc[mi][ni][r] + b2[n], 0.f);
            }
        }
}

// ---------------- fused combine (with Z2-BN): X = relu(X + relu(HAGG@lin2+b2)@linw + b + bn(Z2)) ----
__global__ __launch_bounds__(512) void k_combine(
    const unsigned short* __restrict__ HAGG,
    const unsigned short* __restrict__ lin2t, const float* __restrict__ lin2b,
    const unsigned short* __restrict__ linwt, const float* __restrict__ linb,
    const float* __restrict__ Z2,
    const float* __restrict__ scb, const float* __restrict__ shb,
    unsigned short* __restrict__ X)
{
    __shared__ unsigned short As[128][72];
    __shared__ unsigned short Bs[256][72];
    __shared__ unsigned short H2s[128][264];
    const int tid = threadIdx.x;
    const int bm = blockIdx.x * 128;
    const int lane = tid & 63;
    const int wid = tid >> 6;
    const int wm = wid >> 2, wn = wid & 3;
    const int rsel = lane & 15, ksel = (lane >> 4) * 8;

    f32x4 acc[4][4];
#pragma unroll
    for (int a = 0; a < 4; ++a)
#pragma unroll
        for (int b = 0; b < 4; ++b) acc[a][b] = (f32x4){0.f, 0.f, 0.f, 0.f};

    for (int k0 = 0; k0 < 128; k0 += 64) {
#pragma unroll
        for (int i = 0; i < 2; ++i) {
            int c = tid + i * 512;
            int row = c >> 3, kc = (c & 7) * 8;
            *(uint4*)&As[row][kc] =
                *(const uint4*)&HAGG[(size_t)(bm + row) * 128 + k0 + kc];
        }
#pragma unroll
        for (int i = 0; i < 4; ++i) {
            int c = tid + i * 512;
            int row = c >> 3, kc = (c & 7) * 8;
            *(uint4*)&Bs[row][kc] = *(const uint4*)&lin2t[(size_t)row * 128 + k0 + kc];
        }
        __syncthreads();
#pragma unroll
        for (int kk = 0; kk < 64; kk += 32) {
            s16x8 af[4], bf[4];
#pragma unroll
            for (int mi = 0; mi < 4; ++mi)
                af[mi] = *(const s16x8*)&As[wm * 64 + mi * 16 + rsel][kk + ksel];
#pragma unroll
            for (int ni = 0; ni < 4; ++ni)
                bf[ni] = *(const s16x8*)&Bs[wn * 64 + ni * 16 + rsel][kk + ksel];
#pragma unroll
            for (int mi = 0; mi < 4; ++mi)
#pragma unroll
                for (int ni = 0; ni < 4; ++ni)
                    acc[mi][ni] = __builtin_amdgcn_mfma_f32_16x16x32_bf16(
                        af[mi], bf[ni], acc[mi][ni], 0, 0, 0);
        }
        __syncthreads();
    }
#pragma unroll
    for (int mi = 0; mi < 4; ++mi)
#pragma unroll
        for (int r = 0; r < 4; ++r) {
            int mrow = wm * 64 + mi * 16 + ((lane >> 4) << 2) + r;
#pragma unroll
            for (int ni = 0; ni < 4; ++ni) {
                int n = wn * 64 + ni * 16 + (lane & 15);
                H2s[mrow][n] = f2bf(fmaxf(acc[mi][ni][r] + lin2b[n], 0.f));
            }
        }

#pragma unroll
    for (int a = 0; a < 4; ++a)
#pragma unroll
        for (int b = 0; b < 4; ++b) acc[a][b] = (f32x4){0.f, 0.f, 0.f, 0.f};
    for (int k0 = 0; k0 < 256; k0 += 64) {
#pragma unroll
        for (int i = 0; i < 4; ++i) {
            int c = tid + i * 512;
            int row = c >> 3, kc = (c & 7) * 8;
            *(uint4*)&Bs[row][kc] = *(const uint4*)&linwt[(size_t)row * 256 + k0 + kc];
        }
        __syncthreads();
#pragma unroll
        for (int kk = 0; kk < 64; kk += 32) {
            s16x8 af[4], bf[4];
#pragma unroll
            for (int mi = 0; mi < 4; ++mi)
                af[mi] = *(const s16x8*)&H2s[wm * 64 + mi * 16 + rsel][k0 + kk + ksel];
#pragma unroll
            for (int ni = 0; ni < 4; ++ni)
                bf[ni] = *(const s16x8*)&Bs[wn * 64 + ni * 16 + rsel][kk + ksel];
#pragma unroll
            for (int mi = 0; mi < 4; ++mi)
#pragma unroll
                for (int ni = 0; ni < 4; ++ni)
                    acc[mi][ni] = __builtin_amdgcn_mfma_f32_16x16x32_bf16(
                        af[mi], bf[ni], acc[mi][ni], 0, 0, 0);
        }
        __syncthreads();
    }
#pragma unroll
    for (int mi = 0; mi < 4; ++mi)
#pragma unroll
        for (int r = 0; r < 4; ++r) {
            int m = bm + wm * 64 + mi * 16 + ((lane >> 4) << 2) + r;
            const float* z2row = &Z2[(size_t)(m & (NG - 1)) * 256];
#pragma unroll
            for (int ni = 0; ni < 4; ++ni) {
                int n = wn * 64 + ni * 16 + (lane & 15);
                size_t ix = (size_t)m * 256 + n;
                float z2v = fmaf(z2row[n], scb[n], shb[n]);
                float o = bf2f(X[ix]) + acc[mi][ni][r] + linb[n] + z2v;
                X[ix] = f2bf(fmaxf(o, 0.f));
            }
        }
}

// ---------------- launch ----------------
extern "C" void kernel_launch(void* const* d_in, const int* in_sizes, int n_in,
                              void* d_out, int out_size, void* d_ws, size_t ws_size,
                              hipStream_t stream)
{
    (void)in_sizes; (void)n_in; (void)out_size; (void)ws_size;
    const float* pos       = (const float*)d_in[0];
    const float* atom_emb  = (const float*)d_in[1];
    const float* vn_emb    = (const float*)d_in[2];
    const float* cf_lin1   = (const float*)d_in[3];
    const float* cf_mlp_w1 = (const float*)d_in[4];
    const float* cf_mlp_b1 = (const float*)d_in[5];
    const float* cf_mlp_w2 = (const float*)d_in[6];
    const float* cf_mlp_b2 = (const float*)d_in[7];
    const float* cf_lin2   = (const float*)d_in[8];
    const float* cf_lin2_b = (const float*)d_in[9];
    const float* lin_w     = (const float*)d_in[10];
    const float* lin_b     = (const float*)d_in[11];
    const float* bond_emb  = (const float*)d_in[12];
    const float* gin_eps   = (const float*)d_in[13];
    const float* gin_w1    = (const float*)d_in[14];
    const float* gin_b1    = (const float*)d_in[15];
    const float* gin_g1    = (const float*)d_in[16];
    const float* gin_be1   = (const float*)d_in[17];
    const float* gin_w2    = (const float*)d_in[18];
    const float* gin_b2    = (const float*)d_in[19];
    const float* bn_g      = (const float*)d_in[20];
    const float* bn_b      = (const float*)d_in[21];
    const float* vn_w1     = (const float*)d_in[22];
    const float* vn_b1     = (const float*)d_in[23];
    const float* vn_w2     = (const float*)d_in[24];
    const float* vn_b2     = (const float*)d_in[25];
    const float* out_w1    = (const float*)d_in[26];
    const float* out_b1    = (const float*)d_in[27];
    const float* out_w2    = (const float*)d_in[28];
    const float* out_b2    = (const float*)d_in[29];
    const int* x_atom      = (const int*)d_in[30];
    const int* ei_conf     = (const int*)d_in[34];
    const int* ei_graph    = (const int*)d_in[35];
    const int* attr_graph  = (const int*)d_in[36];
    float* out = (float*)d_out;
    float* ws  = (float*)d_ws;

    size_t o = 0;
    float* Z1   = ws + o; o += (size_t)NG * H;
    float* Z2   = ws + o; o += (size_t)NG * H;
    float* VN   = ws + o; o += (size_t)NCONF * H;
    float* TMP  = ws + o; o += (size_t)NCONF * H;
    float* XM   = ws + o; o += (size_t)NMOL * H;
    float* Y1   = ws + o; o += (size_t)NMOL * H;
    float* STATS= ws + o; o += 1024;
    float* SCA  = ws + o; o += 256;
    float* SHA  = ws + o; o += 256;
    float* SCB  = ws + o; o += 256;
    float* SHB  = ws + o; o += 256;
    float* PDCC = ws + o; o += (size_t)2 * EC;
    // bf16 regions
    unsigned short* XB   = (unsigned short*)(ws + o); o += (size_t)NC * H / 2;
    unsigned short* XA   = (unsigned short*)(ws + o); o += (size_t)NG * H / 2;
    unsigned short* AGGB = (unsigned short*)(ws + o); o += (size_t)NG * H / 2;
    unsigned short* CFH  = (unsigned short*)(ws + o); o += (size_t)NC * F / 2;
    unsigned short* HAGG = (unsigned short*)(ws + o); o += (size_t)NC * F / 2;
    unsigned short* TAB  = (unsigned short*)(ws + o); o += (size_t)NLAYERS * NTAB * F / 2;
    // int region
    int* PSRC   = (int*)(ws + o); o += EC;
    int* PGSRC  = (int*)(ws + o); o += EG;
    int* PATTR  = (int*)(ws + o); o += EG;
    int* CNT    = (int*)(ws + o); o += NC;
    int* ROWC   = (int*)(ws + o); o += NC + 64;
    int* CURC   = (int*)(ws + o); o += NC;
    int* ROWG   = (int*)(ws + o); o += NG + 64;
    int* CURG   = (int*)(ws + o); o += NG;
    int* BSUM   = (int*)(ws + o); o += 256;
    // transposed bf16 weights
    unsigned short* WT = (unsigned short*)(ws + o);
    size_t wo = 0;
    unsigned short* lin1t = WT + wo; wo += (size_t)NLAYERS * 128 * 256;
    unsigned short* w1t   = WT + wo; wo += (size_t)NLAYERS * 128 * 64;
    unsigned short* w2t   = WT + wo; wo += (size_t)NLAYERS * 128 * 128;
    unsigned short* lin2t = WT + wo; wo += (size_t)NLAYERS * 256 * 128;
    unsigned short* linwt = WT + wo; wo += (size_t)NLAYERS * 256 * 256;
    unsigned short* g1t   = WT + wo; wo += (size_t)NLAYERS * 256 * 256;
    unsigned short* g2t   = WT + wo; wo += (size_t)NLAYERS * 256 * 256;
    unsigned short* vn1t  = WT + wo; wo += 256 * 256;
    unsigned short* vn2t  = WT + wo; wo += 256 * 256;
    unsigned short* ow1t  = WT + wo; wo += 256 * 256;

    // ---- weight prep (layer-gridded) ----
    k_wt<<<dim3(128, NLAYERS), 256, 0, stream>>>(cf_lin1,   lin1t, 256, 128, 256);
    k_wt<<<dim3(128, NLAYERS), 256, 0, stream>>>(cf_mlp_w1, w1t,    50, 128,  64);
    k_wt<<<dim3(128, NLAYERS), 256, 0, stream>>>(cf_mlp_w2, w2t,   128, 128, 128);
    k_wt<<<dim3(256, NLAYERS), 256, 0, stream>>>(cf_lin2,   lin2t, 128, 256, 128);
    k_wt<<<dim3(256, NLAYERS), 256, 0, stream>>>(lin_w,     linwt, 256, 256, 256);
    k_wt<<<dim3(256, NLAYERS), 256, 0, stream>>>(gin_w1,    g1t,   256, 256, 256);
    k_wt<<<dim3(256, NLAYERS), 256, 0, stream>>>(gin_w2,    g2t,   256, 256, 256);
    k_wt<<<dim3(256, 1), 256, 0, stream>>>(vn_w1,  vn1t, 256, 256, 256);
    k_wt<<<dim3(256, 1), 256, 0, stream>>>(vn_w2,  vn2t, 256, 256, 256);
    k_wt<<<dim3(256, 1), 256, 0, stream>>>(out_w1, ow1t, 256, 256, 256);
    // all 4 layers' edge-MLP tables
    k_tab<<<dim3(NTAB / 128, NLAYERS), 256, 0, stream>>>(
        w1t, cf_mlp_b1, w2t, cf_mlp_b2, TAB);

    // ---- dst-sort both edge lists ----
    hipMemsetAsync(CNT, 0, NC * sizeof(int), stream);
    k_hist<<<EC / 256, 256, 0, stream>>>(ei_conf + EC, CNT, EC);
    k_scan1<<<NC / 256, 256, 0, stream>>>(CNT, ROWC, BSUM);
    k_scan2<<<1, 256, 0, stream>>>(BSUM, NC / 256);
    k_scan3<<<NC / 256, 256, 0, stream>>>(ROWC, BSUM, CURC, NC, EC);
    k_cperm<<<EC / 256, 256, 0, stream>>>(pos, ei_conf, CURC, PSRC, (float2*)PDCC);

    hipMemsetAsync(CNT, 0, NG * sizeof(int), stream);
    k_hist<<<EG / 256, 256, 0, stream>>>(ei_graph + EG, CNT, EG);
    k_scan1<<<NG / 256, 256, 0, stream>>>(CNT, ROWG, BSUM);
    k_scan2<<<1, 256, 0, stream>>>(BSUM, NG / 256);
    k_scan3<<<NG / 256, 256, 0, stream>>>(ROWG, BSUM, CURG, NG, EG);
    k_gperm<<<EG / 256, 256, 0, stream>>>(ei_graph, attr_graph, CURG, PGSRC, PATTR);

    k_init_x<<<NC, 256, 0, stream>>>(atom_emb, x_atom, XB);
    k_vninit<<<NCONF, 256, 0, stream>>>(vn_emb, VN);

    for (int i = 0; i < NLAYERS; ++i) {
        if (i < NLAYERS - 1) {
            k_pre<true><<<NMOL, 256, 0, stream>>>(XB, VN, TMP, XA);
            k_vnmlp<<<NCONF / 128, 512, 0, stream>>>(TMP, vn1t, vn_b1, vn2t, vn_b2, VN);
        } else {
            k_pre<false><<<NMOL, 256, 0, stream>>>(XB, VN, TMP, XA);
        }
        // ---- CFConv ----
        mgemm<2, 6><<<dim3(1, NC / 128), 256, 0, stream>>>(
            0, XB, lin1t + (size_t)i * 128 * 256, nullptr, 0, CFH,
            256, 256, 128, 0, 0, 0);
        k_cf_agg<<<NC / 16, 256, 0, stream>>>(TAB + (size_t)i * NTAB * F,
            ROWC, PSRC, (const float2*)PDCC, CFH, HAGG);
        // ---- GIN ----
        k_gin_agg<<<NG, 256, 0, stream>>>(
            XA, bond_emb + (size_t)i * 3 * 8 * H, ROWG, PGSRC, PATTR,
            gin_eps + i, AGGB);
        hipMemsetAsync(STATS, 0, 4096, stream);
        mgemm<2, 7><<<dim3(2, NG / 128), 256, 0, stream>>>(
            0, AGGB, g1t + (size_t)i * 256 * 256, gin_b1 + i * H, Z1, 0,
            256, 256, 256, 0, 0, STATS);
        k_bnprep<<<1, 256, 0, stream>>>(STATS, gin_g1 + i * H, gin_be1 + i * H,
                                        SCA, SHA);
        mgemm<4, 7><<<dim3(2, NG / 128), 256, 0, stream>>>(
            Z1, 0, g2t + (size_t)i * 256 * 256, gin_b2 + i * H, Z2, 0,
            256, 256, 256, SCA, SHA, STATS + 512);
        k_bnprep<<<1, 256, 0, stream>>>(STATS + 512, bn_g + i * H, bn_b + i * H,
                                        SCB, SHB);
        // ---- fused combine (applies Z2 BN inline) ----
        k_combine<<<NC / 128, 512, 0, stream>>>(
            HAGG, lin2t + (size_t)i * 256 * 128, cf_lin2_b + i * H,
            linwt + (size_t)i * 256 * 256, lin_b + i * H, Z2, SCB, SHB, XB);
    }

    k_molmax<<<NMOL, 256, 0, stream>>>(XB, XM);
    mgemm<0, 1><<<dim3(2, NMOL / 128), 256, 0, stream>>>(
        XM, 0, ow1t, out_b1, Y1, 0, 256, 256, 256, 0, 0, 0);
    k_head<<<NMOL, 256, 0, stream>>>(Y1, out_w2, out_b2, out);
}

// Round 9
// 946.609 us; speedup vs baseline: 9.6254x; 1.0404x over previous
//
#include <hip/hip_runtime.h>
#include <math.h>

#define H 256
#define F 128
#define NLAYERS 4
#define NG 8192
#define NC 65536
#define EC 524288
#define EG 32768
#define NCONF 4096
#define NMOL 512
#define NGAUSS 50
#define NTAB 8192
#define TABSTEP 0.001953125f   // 16 / 8192
#define INVSTEP 512.0f

using s16x8 = __attribute__((ext_vector_type(8))) short;
using f32x4 = __attribute__((ext_vector_type(4))) float;

static __device__ __forceinline__ unsigned short f2bf(float f) {
    unsigned int u = __float_as_uint(f);
    u += 0x7fffu + ((u >> 16) & 1u);   // RNE (finite values)
    return (unsigned short)(u >> 16);
}
static __device__ __forceinline__ float bf2f(unsigned short b) {
    return __uint_as_float(((unsigned int)b) << 16);
}
static __device__ __forceinline__ float bflo(unsigned int u) {
    return __uint_as_float(u << 16);
}
static __device__ __forceinline__ float bfhi(unsigned int u) {
    return __uint_as_float(u & 0xffff0000u);
}
// conformer id of node row i: r = i>>13, j = i&8191, c = (j>>4)*8 + r
static __device__ __forceinline__ int conf_of(int i) {
    return (((i & (NG - 1)) >> 4) << 3) + (i >> 13);
}

// ---------------- init: X (no vn), SUMX0, VN0 ----------------
// block = conformer c (4096); rows i = r*NG + m*16 + t
__global__ __launch_bounds__(256) void k_init_x(const float* __restrict__ atom_emb,
    const int* __restrict__ x_atom, const float* __restrict__ vn_emb,
    unsigned short* __restrict__ x, float* __restrict__ sumx,
    float* __restrict__ vn0)
{
    int c = blockIdx.x, h = threadIdx.x;
    int m = c >> 3, r = c & 7;
    float sum = 0.f;
    for (int t = 0; t < 16; ++t) {
        int g = m * 16 + t;
        float s = 0.f;
#pragma unroll
        for (int f = 0; f < 9; ++f) {
            int a = x_atom[g * 9 + f];
            s += atom_emb[(f * 64 + a) * H + h];
        }
        x[((size_t)r * NG + g) * H + h] = f2bf(s);
        sum += s;
    }
    sumx[(size_t)c * H + h] = sum;
    vn0[(size_t)c * H + h] = vn_emb[h];
}

// XA[g] = max_r (X[r*NG+g] + VN[conf]) ; block = molecule
__global__ __launch_bounds__(256) void k_xa2(const unsigned short* __restrict__ X,
    const float* __restrict__ vn, unsigned short* __restrict__ xa)
{
    int m = blockIdx.x, h = threadIdx.x;
    float xam[16];
#pragma unroll
    for (int t = 0; t < 16; ++t) xam[t] = -3.4e38f;
#pragma unroll 2
    for (int r = 0; r < 8; ++r) {
        float vv = vn[(size_t)(m * 8 + r) * H + h];
        size_t base = ((size_t)r * NG + m * 16) * H + h;
#pragma unroll
        for (int t = 0; t < 16; ++t)
            xam[t] = fmaxf(xam[t], bf2f(X[base + (size_t)t * H]) + vv);
    }
#pragma unroll
    for (int t = 0; t < 16; ++t)
        xa[(size_t)(m * 16 + t) * H + h] = f2bf(xam[t]);
}

__global__ __launch_bounds__(256) void k_bnprep(const float* __restrict__ stats,
    const float* __restrict__ gamma, const float* __restrict__ beta,
    float* __restrict__ scale, float* __restrict__ shift)
{
    int n = threadIdx.x;
    float mean = stats[n] * (1.0f / NG);
    float var = stats[256 + n] * (1.0f / NG) - mean * mean;
    float sc = gamma[n] * rsqrtf(var + 1e-5f);
    scale[n] = sc;
    shift[n] = beta[n] - mean * sc;
}

__global__ __launch_bounds__(256) void k_molmax(const unsigned short* __restrict__ x,
                                                float* __restrict__ xm)
{
    int m = blockIdx.x, h = threadIdx.x;
    float best = -3.4e38f;
    for (int r = 0; r < 8; ++r) {
        size_t base = ((size_t)r * NG + m * 16) * H + h;
#pragma unroll 4
        for (int t = 0; t < 16; ++t) best = fmaxf(best, bf2f(x[base + (size_t)t * H]));
    }
    xm[(size_t)m * H + h] = best;
}

__global__ __launch_bounds__(256) void k_head(const float* __restrict__ y1,
    const float* __restrict__ w2, const float* __restrict__ b2,
    float* __restrict__ out)
{
    __shared__ float red[256];
    int m = blockIdx.x, h = threadIdx.x;
    red[h] = y1[(size_t)m * H + h] * w2[h];
    __syncthreads();
    for (int s = 128; s > 0; s >>= 1) {
        if (h < s) red[h] += red[h + s];
        __syncthreads();
    }
    if (h == 0) out[m] = red[0] + b2[0];
}

// ---------------- all weight transposes in ONE dispatch (6400 blocks) ----------------
__global__ __launch_bounds__(256) void k_wprep(
    const float* __restrict__ cf_lin1, const float* __restrict__ cf_mlp_w1,
    const float* __restrict__ cf_mlp_w2, const float* __restrict__ cf_lin2,
    const float* __restrict__ lin_w, const float* __restrict__ gin_w1,
    const float* __restrict__ gin_w2, const float* __restrict__ vn_w1,
    const float* __restrict__ vn_w2, const float* __restrict__ out_w1,
    unsigned short* __restrict__ lin1t, unsigned short* __restrict__ w1t,
    unsigned short* __restrict__ w2t, unsigned short* __restrict__ lin2t,
    unsigned short* __restrict__ linwt, unsigned short* __restrict__ g1t,
    unsigned short* __restrict__ g2t, unsigned short* __restrict__ vn1t,
    unsigned short* __restrict__ vn2t, unsigned short* __restrict__ ow1t)
{
    int b = blockIdx.x;
    const float* W; unsigned short* Wt; int K, N, Kp, l, n;
    if (b < 512)      { b -= 0;    l = b >> 7; n = b & 127; W = cf_lin1;   Wt = lin1t; K = 256; N = 128; Kp = 256; }
    else if (b < 1024){ b -= 512;  l = b >> 7; n = b & 127; W = cf_mlp_w1; Wt = w1t;   K = 50;  N = 128; Kp = 64;  }
    else if (b < 1536){ b -= 1024; l = b >> 7; n = b & 127; W = cf_mlp_w2; Wt = w2t;   K = 128; N = 128; Kp = 128; }
    else if (b < 2560){ b -= 1536; l = b >> 8; n = b & 255; W = cf_lin2;   Wt = lin2t; K = 128; N = 256; Kp = 128; }
    else if (b < 3584){ b -= 2560; l = b >> 8; n = b & 255; W = lin_w;     Wt = linwt; K = 256; N = 256; Kp = 256; }
    else if (b < 4608){ b -= 3584; l = b >> 8; n = b & 255; W = gin_w1;    Wt = g1t;   K = 256; N = 256; Kp = 256; }
    else if (b < 5632){ b -= 4608; l = b >> 8; n = b & 255; W = gin_w2;    Wt = g2t;   K = 256; N = 256; Kp = 256; }
    else if (b < 5888){ l = 0; n = b - 5632; W = vn_w1;  Wt = vn1t; K = 256; N = 256; Kp = 256; }
    else if (b < 6144){ l = 0; n = b - 5888; W = vn_w2;  Wt = vn2t; K = 256; N = 256; Kp = 256; }
    else              { l = 0; n = b - 6144; W = out_w1; Wt = ow1t; K = 256; N = 256; Kp = 256; }
    W  += (size_t)l * K * N;
    Wt += (size_t)l * N * Kp;
    for (int k = threadIdx.x; k < Kp; k += 256)
        Wt[(size_t)n * Kp + k] = (k < K) ? f2bf(W[(size_t)k * N + n]) : (unsigned short)0;
}

// ---------------- combined counting sort (both edge lists) ----------------

__global__ __launch_bounds__(256) void k_hist2(const int* __restrict__ ei_conf,
    const int* __restrict__ ei_graph, int* __restrict__ cnt)
{
    int idx = blockIdx.x * 256 + threadIdx.x;
    if (idx < EC) atomicAdd(&cnt[ei_conf[EC + idx]], 1);
    else {
        int j = idx - EC;
        if (j < EG) atomicAdd(&cnt[NC + ei_graph[EG + j]], 1);
    }
}

// blocks 0..255: conf bins; 256..287: graph bins
__global__ __launch_bounds__(256) void k_scan1m(const int* __restrict__ cnt,
    int* __restrict__ rowc, int* __restrict__ rowg,
    int* __restrict__ bsumc, int* __restrict__ bsumg)
{
    __shared__ int sh[256];
    int t = threadIdx.x, b = blockIdx.x;
    const int* src; int* part; int* bsum; int bb;
    if (b < 256) { src = cnt; part = rowc; bsum = bsumc; bb = b; }
    else         { src = cnt + NC; part = rowg; bsum = bsumg; bb = b - 256; }
    int idx = bb * 256 + t;
    int v = src[idx];
    sh[t] = v; __syncthreads();
    for (int s = 1; s < 256; s <<= 1) {
        int add = (t >= s) ? sh[t - s] : 0;
        __syncthreads();
        sh[t] += add;
        __syncthreads();
    }
    part[idx] = sh[t] - v;
    if (t == 255) bsum[bb] = sh[255];
}

// block 0: conf bsum (256); block 1: graph bsum (32)
__global__ __launch_bounds__(256) void k_scan2m(int* __restrict__ bsumc,
                                                int* __restrict__ bsumg)
{
    __shared__ int sh[256];
    int t = threadIdx.x;
    int* bs = (blockIdx.x == 0) ? bsumc : bsumg;
    int nb = (blockIdx.x == 0) ? 256 : 32;
    int v = (t < nb) ? bs[t] : 0;
    sh[t] = v; __syncthreads();
    for (int s = 1; s < 256; s <<= 1) {
        int add = (t >= s) ? sh[t - s] : 0;
        __syncthreads();
        sh[t] += add;
        __syncthreads();
    }
    if (t < nb) bs[t] = sh[t] - v;
}

__global__ __launch_bounds__(256) void k_scan3m(int* __restrict__ rowc,
    int* __restrict__ rowg, const int* __restrict__ bsumc,
    const int* __restrict__ bsumg, int* __restrict__ curc, int* __restrict__ curg)
{
    int t = threadIdx.x, b = blockIdx.x;
    if (b < 256) {
        int idx = b * 256 + t;
        int v = rowc[idx] + bsumc[b];
        rowc[idx] = v; curc[idx] = v;
        if (idx == 0) rowc[NC] = EC;
    } else {
        int bb = b - 256;
        int idx = bb * 256 + t;
        int v = rowg[idx] + bsumg[bb];
        rowg[idx] = v; curg[idx] = v;
        if (idx == 0) rowg[NG] = EG;
    }
}

__global__ __launch_bounds__(256) void k_perm2(const float* __restrict__ pos,
    const int* __restrict__ ei_conf, const int* __restrict__ ei_graph,
    const int* __restrict__ attr, int* __restrict__ curc, int* __restrict__ curg,
    int* __restrict__ psrc, float2* __restrict__ pdcc,
    int* __restrict__ pgsrc, int* __restrict__ pattr)
{
    int idx = blockIdx.x * 256 + threadIdx.x;
    if (idx < EC) {
        int s = ei_conf[idx], t = ei_conf[EC + idx];
        float dx = pos[s * 3 + 0] - pos[t * 3 + 0];
        float dy = pos[s * 3 + 1] - pos[t * 3 + 1];
        float dz = pos[s * 3 + 2] - pos[t * 3 + 2];
        float dd = sqrtf(dx * dx + dy * dy + dz * dz);
        int p = atomicAdd(&curc[t], 1);
        psrc[p] = s;
        pdcc[p] = make_float2(dd, 0.5f * (cosf(dd * 0.314159265358979f) + 1.0f));
    } else {
        int j = idx - EC;
        if (j < EG) {
            int s = ei_graph[j], t = ei_graph[EG + j];
            int p = atomicAdd(&curg[t], 1);
            pgsrc[p] = s;
            pattr[p] = attr[j * 3] | (attr[j * 3 + 1] << 4) | (attr[j * 3 + 2] << 8);
        }
    }
}

// ---------------- gather-based aggregations (no atomics) ----------------

// 8 channels/thread, 16 lanes/node, 16 nodes/block. Nearest-neighbor table.
__global__ __launch_bounds__(256) void k_cf_agg(const unsigned short* __restrict__ tab,
    const int* __restrict__ rowptr, const int* __restrict__ psrc,
    const float2* __restrict__ pdcc,
    const unsigned short* __restrict__ cfh, unsigned short* __restrict__ hagg)
{
    int slot = threadIdx.x >> 4;
    int c8 = (threadIdx.x & 15) << 3;
    int n = blockIdx.x * 16 + slot;
    int lo = rowptr[n], hi = rowptr[n + 1];
    float a[8] = {0.f, 0.f, 0.f, 0.f, 0.f, 0.f, 0.f, 0.f};
    for (int e = lo; e < hi; ++e) {
        int s = psrc[e];
        float2 dc = pdcc[e];
        float u = dc.x * INVSTEP + 0.5f;
        int it = (int)u;
        if (it > NTAB - 1) it = NTAB - 1;
        uint4 T = *(const uint4*)&tab[(size_t)it * F + c8];
        uint4 HV = *(const uint4*)&cfh[(size_t)s * F + c8];
        float cc = dc.y;
        a[0] = fmaf(bflo(T.x) * cc, bflo(HV.x), a[0]);
        a[1] = fmaf(bfhi(T.x) * cc, bfhi(HV.x), a[1]);
        a[2] = fmaf(bflo(T.y) * cc, bflo(HV.y), a[2]);
        a[3] = fmaf(bfhi(T.y) * cc, bfhi(HV.y), a[3]);
        a[4] = fmaf(bflo(T.z) * cc, bflo(HV.z), a[4]);
        a[5] = fmaf(bfhi(T.z) * cc, bfhi(HV.z), a[5]);
        a[6] = fmaf(bflo(T.w) * cc, bflo(HV.w), a[6]);
        a[7] = fmaf(bfhi(T.w) * cc, bfhi(HV.w), a[7]);
    }
    uint4 o;
    o.x = ((unsigned)f2bf(a[1]) << 16) | f2bf(a[0]);
    o.y = ((unsigned)f2bf(a[3]) << 16) | f2bf(a[2]);
    o.z = ((unsigned)f2bf(a[5]) << 16) | f2bf(a[4]);
    o.w = ((unsigned)f2bf(a[7]) << 16) | f2bf(a[6]);
    *(uint4*)&hagg[(size_t)n * F + c8] = o;
}

// AGG[g] = bf16((1+eps)*xa[g] + sum_e relu(xa[pgsrc[e]] + bond_sum)); block 0 zeroes stats
__global__ __launch_bounds__(256) void k_gin_agg(const unsigned short* __restrict__ xa,
    const float* __restrict__ bond, const int* __restrict__ growptr,
    const int* __restrict__ pgsrc, const int* __restrict__ pattr,
    const float* __restrict__ eps_p, unsigned short* __restrict__ agg,
    float* __restrict__ stats)
{
    int g = blockIdx.x, h = threadIdx.x;
    if (g == 0) {
#pragma unroll
        for (int q = 0; q < 4; ++q) stats[q * 256 + h] = 0.f;
    }
    int lo = growptr[g], hi = growptr[g + 1];
    float acc = 0.f;
    for (int e = lo; e < hi; ++e) {
        int s = pgsrc[e], a = pattr[e];
        float v = bf2f(xa[(size_t)s * H + h])
                + bond[(a & 15) * H + h]
                + bond[(8 + ((a >> 4) & 15)) * H + h]
                + bond[(16 + (a >> 8)) * H + h];
        acc += fmaxf(v, 0.f);
    }
    agg[(size_t)g * H + h] =
        f2bf((1.0f + eps_p[0]) * bf2f(xa[(size_t)g * H + h]) + acc);
}

// ---------------- MFMA GEMM ----------------
// tile 128x128, BK=64, 4 waves.
// ASRC: 0 = f32 A, 2 = bf16 A, 4 = f32 A + scale/shift + relu (fused BN),
//       6 = bf16 A + VN[conf(row)] add (f32)
// EPI:  1 = relu->Cf, 6 = ->bf16 Cb, 7 = ->Cf + column stats atomics
template<int ASRC, int EPI>
__global__ __launch_bounds__(256) void mgemm(
    const float* __restrict__ Af, const unsigned short* __restrict__ Ab,
    const unsigned short* __restrict__ Bt,
    const float* __restrict__ bias,
    float* __restrict__ Cf, unsigned short* __restrict__ Cb,
    int K, int Kp, int ldc,
    const float* __restrict__ sca, const float* __restrict__ sha,
    float* __restrict__ stats_out, const float* __restrict__ vnp)
{
    __shared__ unsigned short As[128][72];
    __shared__ unsigned short Bs[128][72];
    const int tid = threadIdx.x;
    const int bm = blockIdx.y * 128;
    const int bn = blockIdx.x * 128;
    const int lane = tid & 63;
    const int wid = tid >> 6;
    const int wm = wid >> 1, wn = wid & 1;
    const int rsel = lane & 15, ksel = (lane >> 4) * 8;

    f32x4 acc[4][4];
#pragma unroll
    for (int a = 0; a < 4; ++a)
#pragma unroll
        for (int b = 0; b < 4; ++b) acc[a][b] = (f32x4){0.f, 0.f, 0.f, 0.f};

    for (int k0 = 0; k0 < Kp; k0 += 64) {
#pragma unroll
        for (int i = 0; i < 4; ++i) {
            int c = tid + i * 256;
            int row = c >> 3, kc = (c & 7) * 8;
            *(uint4*)&Bs[row][kc] =
                *(const uint4*)&Bt[(size_t)(bn + row) * Kp + k0 + kc];
        }
        if constexpr (ASRC == 0 || ASRC == 4) {
#pragma unroll
            for (int i = 0; i < 8; ++i) {
                int c = tid + i * 256;
                int row = c >> 4, kc = (c & 15) * 4;
                float4 v = *(const float4*)&Af[(size_t)(bm + row) * K + k0 + kc];
                if constexpr (ASRC == 4) {
                    float4 s4 = *(const float4*)&sca[k0 + kc];
                    float4 h4 = *(const float4*)&sha[k0 + kc];
                    v.x = fmaxf(fmaf(v.x, s4.x, h4.x), 0.f);
                    v.y = fmaxf(fmaf(v.y, s4.y, h4.y), 0.f);
                    v.z = fmaxf(fmaf(v.z, s4.z, h4.z), 0.f);
                    v.w = fmaxf(fmaf(v.w, s4.w, h4.w), 0.f);
                }
                ushort4 b;
                b.x = f2bf(v.x); b.y = f2bf(v.y); b.z = f2bf(v.z); b.w = f2bf(v.w);
                *(ushort4*)&As[row][kc] = b;
            }
        } else if constexpr (ASRC == 6) {
#pragma unroll
            for (int i = 0; i < 4; ++i) {
                int c = tid + i * 256;
                int row = c >> 3, kc = (c & 7) * 8;
                int gm = bm + row;
                int cf = conf_of(gm);
                uint4 xv = *(const uint4*)&Ab[(size_t)gm * K + k0 + kc];
                const float* vr = &vnp[(size_t)cf * 256 + k0 + kc];
                float4 v0 = *(const float4*)vr;
                float4 v1 = *(const float4*)(vr + 4);
                uint4 o;
                o.x = ((unsigned)f2bf(bfhi(xv.x) + v0.y) << 16) | f2bf(bflo(xv.x) + v0.x);
                o.y = ((unsigned)f2bf(bfhi(xv.y) + v0.w) << 16) | f2bf(bflo(xv.y) + v0.z);
                o.z = ((unsigned)f2bf(bfhi(xv.z) + v1.y) << 16) | f2bf(bflo(xv.z) + v1.x);
                o.w = ((unsigned)f2bf(bfhi(xv.w) + v1.w) << 16) | f2bf(bflo(xv.w) + v1.z);
                *(uint4*)&As[row][kc] = o;
            }
        } else {
#pragma unroll
            for (int i = 0; i < 4; ++i) {
                int c = tid + i * 256;
                int row = c >> 3, kc = (c & 7) * 8;
                *(uint4*)&As[row][kc] =
                    *(const uint4*)&Ab[(size_t)(bm + row) * K + k0 + kc];
            }
        }
        __syncthreads();
#pragma unroll
        for (int kk = 0; kk < 64; kk += 32) {
            s16x8 af[4], bf[4];
#pragma unroll
            for (int mi = 0; mi < 4; ++mi)
                af[mi] = *(const s16x8*)&As[wm * 64 + mi * 16 + rsel][kk + ksel];
#pragma unroll
            for (int ni = 0; ni < 4; ++ni)
                bf[ni] = *(const s16x8*)&Bs[wn * 64 + ni * 16 + rsel][kk + ksel];
#pragma unroll
            for (int mi = 0; mi < 4; ++mi)
#pragma unroll
                for (int ni = 0; ni < 4; ++ni)
                    acc[mi][ni] = __builtin_amdgcn_mfma_f32_16x16x32_bf16(
                        af[mi], bf[ni], acc[mi][ni], 0, 0, 0);
        }
        __syncthreads();
    }

    float colS[4] = {0.f, 0.f, 0.f, 0.f};
    float colQ[4] = {0.f, 0.f, 0.f, 0.f};
#pragma unroll
    for (int mi = 0; mi < 4; ++mi) {
#pragma unroll
        for (int r = 0; r < 4; ++r) {
            int m = bm + wm * 64 + mi * 16 + ((lane >> 4) << 2) + r;
#pragma unroll
            for (int ni = 0; ni < 4; ++ni) {
                int n = bn + wn * 64 + ni * 16 + (lane & 15);
                float v = acc[mi][ni][r];
                if (bias) v += bias[n];
                if constexpr (EPI == 1) {
                    Cf[(size_t)m * ldc + n] = fmaxf(v, 0.f);
                } else if constexpr (EPI == 6) {
                    Cb[(size_t)m * ldc + n] = f2bf(v);
                } else {  // EPI == 7
                    Cf[(size_t)m * ldc + n] = v;
                    colS[ni] += v;
                    colQ[ni] = fmaf(v, v, colQ[ni]);
                }
            }
        }
    }
    if constexpr (EPI == 7) {
        float* cs = (float*)&As[0][0];
        cs[tid] = 0.f;
        __syncthreads();
#pragma unroll
        for (int ni = 0; ni < 4; ++ni) {
            int nl = wn * 64 + ni * 16 + (lane & 15);
            atomicAdd(&cs[nl], colS[ni]);
            atomicAdd(&cs[128 + nl], colQ[ni]);
        }
        __syncthreads();
        if (tid < 128) {
            atomicAdd(&stats_out[bn + tid], cs[tid]);
            atomicAdd(&stats_out[256 + bn + tid], cs[128 + tid]);
        }
    }
}

// ---------------- fused table build: TAB[l][i] = mlp_l(gauss(i*step)) ----------------
__global__ __launch_bounds__(256) void k_tab(
    const unsigned short* __restrict__ w1t,  // [L][128][64]
    const float* __restrict__ b1,            // [L][128]
    const unsigned short* __restrict__ w2t,  // [L][128][128]
    const float* __restrict__ b2,            // [L][128]
    unsigned short* __restrict__ tab)        // [L][NTAB][128]
{
    __shared__ unsigned short As[128][72];
    __shared__ unsigned short Bs[128][72];
    __shared__ unsigned short T1s[128][152];
    const int l = blockIdx.y;
    w1t += (size_t)l * 128 * 64;  b1 += l * 128;
    w2t += (size_t)l * 128 * 128; b2 += l * 128;
    tab += (size_t)l * NTAB * F;
    const int tid = threadIdx.x;
    const int bm = blockIdx.x * 128;
    const int lane = tid & 63, wid = tid >> 6;
    const int wm = wid >> 1, wn = wid & 1;
    const int rsel = lane & 15, ksel = (lane >> 4) * 8;

    f32x4 acc[4][4];
#pragma unroll
    for (int a = 0; a < 4; ++a)
#pragma unroll
        for (int b = 0; b < 4; ++b) acc[a][b] = (f32x4){0.f, 0.f, 0.f, 0.f};

    // stage 1: A = gauss rows (K=50 pad 64), B = w1t
#pragma unroll
    for (int i = 0; i < 8; ++i) {
        int c = tid + i * 256;
        int row = c >> 4, kc = (c & 15) * 4;
        float dv = (float)(bm + row) * TABSTEP;
        ushort4 b;
        unsigned short* bp = (unsigned short*)&b;
#pragma unroll
        for (int j = 0; j < 4; ++j) {
            int k = kc + j;
            float f = 0.f;
            if (k < NGAUSS) {
                float t = dv - (float)k * (10.0f / 49.0f);
                f = __expf(-12.005f * t * t);
            }
            bp[j] = f2bf(f);
        }
        *(ushort4*)&As[row][kc] = b;
    }
#pragma unroll
    for (int i = 0; i < 4; ++i) {
        int c = tid + i * 256;
        int row = c >> 3, kc = (c & 7) * 8;
        *(uint4*)&Bs[row][kc] = *(const uint4*)&w1t[(size_t)row * 64 + kc];
    }
    __syncthreads();
#pragma unroll
    for (int kk = 0; kk < 64; kk += 32) {
        s16x8 af[4], bf[4];
#pragma unroll
        for (int mi = 0; mi < 4; ++mi)
            af[mi] = *(const s16x8*)&As[wm * 64 + mi * 16 + rsel][kk + ksel];
#pragma unroll
        for (int ni = 0; ni < 4; ++ni)
            bf[ni] = *(const s16x8*)&Bs[wn * 64 + ni * 16 + rsel][kk + ksel];
#pragma unroll
        for (int mi = 0; mi < 4; ++mi)
#pragma unroll
            for (int ni = 0; ni < 4; ++ni)
                acc[mi][ni] = __builtin_amdgcn_mfma_f32_16x16x32_bf16(
                    af[mi], bf[ni], acc[mi][ni], 0, 0, 0);
    }
    __syncthreads();
#pragma unroll
    for (int mi = 0; mi < 4; ++mi)
#pragma unroll
        for (int r = 0; r < 4; ++r) {
            int mrow = wm * 64 + mi * 16 + ((lane >> 4) << 2) + r;
#pragma unroll
            for (int ni = 0; ni < 4; ++ni) {
                int n = wn * 64 + ni * 16 + (lane & 15);
                T1s[mrow][n] = f2bf(fmaxf(acc[mi][ni][r] + b1[n], 0.f));
            }
        }
#pragma unroll
    for (int a = 0; a < 4; ++a)
#pragma unroll
        for (int b = 0; b < 4; ++b) acc[a][b] = (f32x4){0.f, 0.f, 0.f, 0.f};
    // stage 2: A = T1s (K=128), B = w2t
    for (int k0 = 0; k0 < 128; k0 += 64) {
#pragma unroll
        for (int i = 0; i < 4; ++i) {
            int c = tid + i * 256;
            int row = c >> 3, kc = (c & 7) * 8;
            *(uint4*)&Bs[row][kc] = *(const uint4*)&w2t[(size_t)row * 128 + k0 + kc];
        }
        __syncthreads();
#pragma unroll
        for (int kk = 0; kk < 64; kk += 32) {
            s16x8 af[4], bf[4];
#pragma unroll
            for (int mi = 0; mi < 4; ++mi)
                af[mi] = *(const s16x8*)&T1s[wm * 64 + mi * 16 + rsel][k0 + kk + ksel];
#pragma unroll
            for (int ni = 0; ni < 4; ++ni)
                bf[ni] = *(const s16x8*)&Bs[wn * 64 + ni * 16 + rsel][kk + ksel];
#pragma unroll
            for (int mi = 0; mi < 4; ++mi)
#pragma unroll
                for (int ni = 0; ni < 4; ++ni)
                    acc[mi][ni] = __builtin_amdgcn_mfma_f32_16x16x32_bf16(
                        af[mi], bf[ni], acc[mi][ni], 0, 0, 0);
        }
        __syncthreads();
    }
#pragma unroll
    for (int mi = 0; mi < 4; ++mi)
#pragma unroll
        for (int r = 0; r < 4; ++r) {
            int m = bm + wm * 64 + mi * 16 + ((lane >> 4) << 2) + r;
#pragma unroll
            for (int ni = 0; ni < 4; ++ni) {
                int n = wn * 64 + ni * 16 + (lane & 15);
                tab[(size_t)m * F + n] = f2bf(acc[mi][ni][r] + b2[n]);
            }
        }
}

// ---------------- fused vn MLP: VNout = relu(relu((SUMX+17*VNin)@w1+b1)@w2+b2) ----------------
__global__ __launch_bounds__(512) void k_vnmlp(
    const float* __restrict__ SUMX, const float* __restrict__ VNin,
    const unsigned short* __restrict__ w1, const float* __restrict__ b1,
    const unsigned short* __restrict__ w2, const float* __restrict__ b2,
    float* __restrict__ VNout)
{
    __shared__ unsigned short As[128][72];
    __shared__ unsigned short Bs[256][72];
    __shared__ unsigned short Ts[128][264];
    const int tid = threadIdx.x;
    const int bm = blockIdx.x * 128;
    const int lane = tid & 63, wid = tid >> 6;
    const int wm = wid >> 2, wn = wid & 3;
    const int rsel = lane & 15, ksel = (lane >> 4) * 8;

    f32x4 acc[4][4];
#pragma unroll
    for (int a = 0; a < 4; ++a)
#pragma unroll
        for (int b = 0; b < 4; ++b) acc[a][b] = (f32x4){0.f, 0.f, 0.f, 0.f};
    for (int k0 = 0; k0 < 256; k0 += 64) {
#pragma unroll
        for (int i = 0; i < 4; ++i) {
            int c = tid + i * 512;
            int row = c >> 4, kc = (c & 15) * 4;
            size_t off = (size_t)(bm + row) * 256 + k0 + kc;
            float4 sx = *(const float4*)&SUMX[off];
            float4 vv = *(const float4*)&VNin[off];
            ushort4 b;
            b.x = f2bf(fmaf(17.f, vv.x, sx.x));
            b.y = f2bf(fmaf(17.f, vv.y, sx.y));
            b.z = f2bf(fmaf(17.f, vv.z, sx.z));
            b.w = f2bf(fmaf(17.f, vv.w, sx.w));
            *(ushort4*)&As[row][kc] = b;
        }
#pragma unroll
        for (int i = 0; i < 4; ++i) {
            int c = tid + i * 512;
            int row = c >> 3, kc = (c & 7) * 8;
            *(uint4*)&Bs[row][kc] = *(const uint4*)&w1[(size_t)row * 256 + k0 + kc];
        }
        __syncthreads();
#pragma unroll
        for (int kk = 0; kk < 64; kk += 32) {
            s16x8 af[4], bf[4];
#pragma unroll
            for (int mi = 0; mi < 4; ++mi)
                af[mi] = *(const s16x8*)&As[wm * 64 + mi * 16 + rsel][kk + ksel];
#pragma unroll
            for (int ni = 0; ni < 4; ++ni)
                bf[ni] = *(const s16x8*)&Bs[wn * 64 + ni * 16 + rsel][kk + ksel];
#pragma unroll
            for (int mi = 0; mi < 4; ++mi)
#pragma unroll
                for (int ni = 0; ni < 4; ++ni)
                    acc[mi][ni] = __builtin_amdgcn_mfma_f32_16x16x32_bf16(
                        af[mi], bf[ni], acc[mi][ni], 0, 0, 0);
        }
        __syncthreads();
    }
#pragma unroll
    for (int mi = 0; mi < 4; ++mi)
#pragma unroll
        for (int r = 0; r < 4; ++r) {
            int mrow = wm * 64 + mi * 16 + ((lane >> 4) << 2) + r;
#pragma unroll
            for (int ni = 0; ni < 4; ++ni) {
                int n = wn * 64 + ni * 16 + (lane & 15);
                Ts[mrow][n] = f2bf(fmaxf(acc[mi][ni][r] + b1[n], 0.f));
            }
        }
#pragma unroll
    for (int a = 0; a < 4; ++a)
#pragma unroll
        for (int b = 0; b < 4; ++b) acc[a][b] = (f32x4){0.f, 0.f, 0.f, 0.f};
    for (int k0 = 0; k0 < 256; k0 += 64) {
#pragma unroll
        for (int i = 0; i < 4; ++i) {
            int c = tid + i * 512;
            int row = c >> 3, kc = (c & 7) * 8;
            *(uint4*)&Bs[row][kc] = *(const uint4*)&w2[(size_t)row * 256 + k0 + kc];
        }
        __syncthreads();
#pragma unroll
        for (int kk = 0; kk < 64; kk += 32) {
            s16x8 af[4], bf[4];
#pragma unroll
            for (int mi = 0; mi < 4; ++mi)
                af[mi] = *(const s16x8*)&Ts[wm * 64 + mi * 16 + rsel][k0 + kk + ksel];
#pragma unroll
            for (int ni = 0; ni < 4; ++ni)
                bf[ni] = *(const s16x8*)&Bs[wn * 64 + ni * 16 + rsel][kk + ksel];
#pragma unroll
            for (int mi = 0; mi < 4; ++mi)
#pragma unroll
                for (int ni = 0; ni < 4; ++ni)
                    acc[mi][ni] = __builtin_amdgcn_mfma_f32_16x16x32_bf16(
                        af[mi], bf[ni], acc[mi][ni], 0, 0, 0);
        }
        __syncthreads();
    }
#pragma unroll
    for (int mi = 0; mi < 4; ++mi)
#pragma unroll
        for (int r = 0; r < 4; ++r) {
            int m = bm + wm * 64 + mi * 16 + ((lane >> 4) << 2) + r;
#pragma unroll
            for (int ni = 0; ni < 4; ++ni) {
                int n = wn * 64 + ni * 16 + (lane & 15);
                VNout[(size_t)m * 256 + n] = fmaxf(acc[mi][ni][r] + b2[n], 0.f);
            }
        }
}

// ---- fused combine: X = relu(X + VN + relu(HAGG@lin2+b2)@linw + b + bn(Z2));
//      optionally emits per-conformer column sums SUMX (for next layer's vnmlp).
template <bool DOSUM>
__global__ __launch_bounds__(512) void k_combine(
    const unsigned short* __restrict__ HAGG,
    const unsigned short* __restrict__ lin2t, const float* __restrict__ lin2b,
    const unsigned short* __restrict__ linwt, const float* __restrict__ linb,
    const float* __restrict__ Z2,
    const float* __restrict__ scb, const float* __restrict__ shb,
    const float* __restrict__ vn, unsigned short* __restrict__ X,
    float* __restrict__ SUMX)
{
    __shared__ unsigned short As[128][72];
    __shared__ unsigned short Bs[256][72];
    __shared__ unsigned short H2s[128][264];
    const int tid = threadIdx.x;
    const int bm = blockIdx.x * 128;
    const int lane = tid & 63;
    const int wid = tid >> 6;
    const int wm = wid >> 2, wn = wid & 3;
    const int rsel = lane & 15, ksel = (lane >> 4) * 8;

    f32x4 acc[4][4];
#pragma unroll
    for (int a = 0; a < 4; ++a)
#pragma unroll
        for (int b = 0; b < 4; ++b) acc[a][b] = (f32x4){0.f, 0.f, 0.f, 0.f};

    for (int k0 = 0; k0 < 128; k0 += 64) {
#pragma unroll
        for (int i = 0; i < 2; ++i) {
            int c = tid + i * 512;
            int row = c >> 3, kc = (c & 7) * 8;
            *(uint4*)&As[row][kc] =
                *(const uint4*)&HAGG[(size_t)(bm + row) * 128 + k0 + kc];
        }
#pragma unroll
        for (int i = 0; i < 4; ++i) {
            int c = tid + i * 512;
            int row = c >> 3, kc = (c & 7) * 8;
            *(uint4*)&Bs[row][kc] = *(const uint4*)&lin2t[(size_t)row * 128 + k0 + kc];
        }
        __syncthreads();
#pragma unroll
        for (int kk = 0; kk < 64; kk += 32) {
            s16x8 af[4], bf[4];
#pragma unroll
            for (int mi = 0; mi < 4; ++mi)
                af[mi] = *(const s16x8*)&As[wm * 64 + mi * 16 + rsel][kk + ksel];
#pragma unroll
            for (int ni = 0; ni < 4; ++ni)
                bf[ni] = *(const s16x8*)&Bs[wn * 64 + ni * 16 + rsel][kk + ksel];
#pragma unroll
            for (int mi = 0; mi < 4; ++mi)
#pragma unroll
                for (int ni = 0; ni < 4; ++ni)
                    acc[mi][ni] = __builtin_amdgcn_mfma_f32_16x16x32_bf16(
                        af[mi], bf[ni], acc[mi][ni], 0, 0, 0);
        }
        __syncthreads();
    }
#pragma unroll
    for (int mi = 0; mi < 4; ++mi)
#pragma unroll
        for (int r = 0; r < 4; ++r) {
            int mrow = wm * 64 + mi * 16 + ((lane >> 4) << 2) + r;
#pragma unroll
            for (int ni = 0; ni < 4; ++ni) {
                int n = wn * 64 + ni * 16 + (lane & 15);
                H2s[mrow][n] = f2bf(fmaxf(acc[mi][ni][r] + lin2b[n], 0.f));
            }
        }

#pragma unroll
    for (int a = 0; a < 4; ++a)
#pragma unroll
        for (int b = 0; b < 4; ++b) acc[a][b] = (f32x4){0.f, 0.f, 0.f, 0.f};
    for (int k0 = 0; k0 < 256; k0 += 64) {
#pragma unroll
        for (int i = 0; i < 4; ++i) {
            int c = tid + i * 512;
            int row = c >> 3, kc = (c & 7) * 8;
            *(uint4*)&Bs[row][kc] = *(const uint4*)&linwt[(size_t)row * 256 + k0 + kc];
        }
        __syncthreads();
#pragma unroll
        for (int kk = 0; kk < 64; kk += 32) {
            s16x8 af[4], bf[4];
#pragma unroll
            for (int mi = 0; mi < 4; ++mi)
                af[mi] = *(const s16x8*)&H2s[wm * 64 + mi * 16 + rsel][k0 + kk + ksel];
#pragma unroll
            for (int ni = 0; ni < 4; ++ni)
                bf[ni] = *(const s16x8*)&Bs[wn * 64 + ni * 16 + rsel][kk + ksel];
#pragma unroll
            for (int mi = 0; mi < 4; ++mi)
#pragma unroll
                for (int ni = 0; ni < 4; ++ni)
                    acc[mi][ni] = __builtin_amdgcn_mfma_f32_16x16x32_bf16(
                        af[mi], bf[ni], acc[mi][ni], 0, 0, 0);
        }
        __syncthreads();
    }
    // epilogue: residual (+VN, +bn(Z2)), relu, bf16 store; per-conformer SUMX
#pragma unroll
    for (int mi = 0; mi < 4; ++mi) {
        int gm0 = bm + wm * 64 + mi * 16;       // 16-row group = one conformer
        int cf = conf_of(gm0);
        float srow[4] = {0.f, 0.f, 0.f, 0.f};
#pragma unroll
        for (int r = 0; r < 4; ++r) {
            int m = gm0 + ((lane >> 4) << 2) + r;
            const float* z2row = &Z2[(size_t)(m & (NG - 1)) * 256];
#pragma unroll
            for (int ni = 0; ni < 4; ++ni) {
                int n = wn * 64 + ni * 16 + (lane & 15);
                size_t ix = (size_t)m * 256 + n;
                float z2v = fmaf(z2row[n], scb[n], shb[n]);
                float vnv = vn[(size_t)cf * 256 + n];
                float o = bf2f(X[ix]) + vnv + acc[mi][ni][r] + linb[n] + z2v;
                o = fmaxf(o, 0.f);
                X[ix] = f2bf(o);
                if (DOSUM) srow[ni] += o;
            }
        }
        if (DOSUM) {
#pragma unroll
            for (int ni = 0; ni < 4; ++ni) {
                float s = srow[ni];
                s += __shfl_xor(s, 16);
                s += __shfl_xor(s, 32);
                if ((lane >> 4) == 0) {
                    int n = wn * 64 + ni * 16 + (lane & 15);
                    SUMX[(size_t)cf * 256 + n] = s;
                }
            }
        }
    }
}

// ---------------- launch ----------------
extern "C" void kernel_launch(void* const* d_in, const int* in_sizes, int n_in,
                              void* d_out, int out_size, void* d_ws, size_t ws_size,
                              hipStream_t stream)
{
    (void)in_sizes; (void)n_in; (void)out_size; (void)ws_size;
    const float* pos       = (const float*)d_in[0];
    const float* atom_emb  = (const float*)d_in[1];
    const float* vn_emb    = (const float*)d_in[2];
    const float* cf_lin1   = (const float*)d_in[3];
    const float* cf_mlp_w1 = (const float*)d_in[4];
    const float* cf_mlp_b1 = (const float*)d_in[5];
    const float* cf_mlp_w2 = (const float*)d_in[6];
    const float* cf_mlp_b2 = (const float*)d_in[7];
    const float* cf_lin2   = (const float*)d_in[8];
    const float* cf_lin2_b = (const float*)d_in[9];
    const float* lin_w     = (const float*)d_in[10];
    const float* lin_b     = (const float*)d_in[11];
    const float* bond_emb  = (const float*)d_in[12];
    const float* gin_eps   = (const float*)d_in[13];
    const float* gin_w1    = (const float*)d_in[14];
    const float* gin_b1    = (const float*)d_in[15];
    const float* gin_g1    = (const float*)d_in[16];
    const float* gin_be1   = (const float*)d_in[17];
    const float* gin_w2    = (const float*)d_in[18];
    const float* gin_b2    = (const float*)d_in[19];
    const float* bn_g      = (const float*)d_in[20];
    const float* bn_b      = (const float*)d_in[21];
    const float* vn_w1     = (const float*)d_in[22];
    const float* vn_b1     = (const float*)d_in[23];
    const float* vn_w2     = (const float*)d_in[24];
    const float* vn_b2     = (const float*)d_in[25];
    const float* out_w1    = (const float*)d_in[26];
    const float* out_b1    = (const float*)d_in[27];
    const float* out_w2    = (const float*)d_in[28];
    const float* out_b2    = (const float*)d_in[29];
    const int* x_atom      = (const int*)d_in[30];
    const int* ei_conf     = (const int*)d_in[34];
    const int* ei_graph    = (const int*)d_in[35];
    const int* attr_graph  = (const int*)d_in[36];
    float* out = (float*)d_out;
    float* ws  = (float*)d_ws;

    size_t o = 0;
    float* Z1   = ws + o; o += (size_t)NG * H;
    float* Z2   = ws + o; o += (size_t)NG * H;
    float* VN0  = ws + o; o += (size_t)NCONF * H;
    float* VN1  = ws + o; o += (size_t)NCONF * H;
    float* SUMX = ws + o; o += (size_t)NCONF * H;
    float* XM   = ws + o; o += (size_t)NMOL * H;
    float* Y1   = ws + o; o += (size_t)NMOL * H;
    float* STATS= ws + o; o += 1024;
    float* SCA  = ws + o; o += 256;
    float* SHA  = ws + o; o += 256;
    float* SCB  = ws + o; o += 256;
    float* SHB  = ws + o; o += 256;
    float* PDCC = ws + o; o += (size_t)2 * EC;
    // bf16 regions
    unsigned short* XB   = (unsigned short*)(ws + o); o += (size_t)NC * H / 2;
    unsigned short* XA   = (unsigned short*)(ws + o); o += (size_t)NG * H / 2;
    unsigned short* AGGB = (unsigned short*)(ws + o); o += (size_t)NG * H / 2;
    unsigned short* CFH  = (unsigned short*)(ws + o); o += (size_t)NC * F / 2;
    unsigned short* HAGG = (unsigned short*)(ws + o); o += (size_t)NC * F / 2;
    unsigned short* TAB  = (unsigned short*)(ws + o); o += (size_t)NLAYERS * NTAB * F / 2;
    // int region
    int* PSRC   = (int*)(ws + o); o += EC;
    int* PGSRC  = (int*)(ws + o); o += EG;
    int* PATTR  = (int*)(ws + o); o += EG;
    int* CNT    = (int*)(ws + o); o += NC + NG;      // conf bins | graph bins
    int* ROWC   = (int*)(ws + o); o += NC + 64;
    int* CURC   = (int*)(ws + o); o += NC;
    int* ROWG   = (int*)(ws + o); o += NG + 64;
    int* CURG   = (int*)(ws + o); o += NG;
    int* BSUMC  = (int*)(ws + o); o += 256;
    int* BSUMG  = (int*)(ws + o); o += 64;
    // transposed bf16 weights
    unsigned short* WT = (unsigned short*)(ws + o);
    size_t wo = 0;
    unsigned short* lin1t = WT + wo; wo += (size_t)NLAYERS * 128 * 256;
    unsigned short* w1t   = WT + wo; wo += (size_t)NLAYERS * 128 * 64;
    unsigned short* w2t   = WT + wo; wo += (size_t)NLAYERS * 128 * 128;
    unsigned short* lin2t = WT + wo; wo += (size_t)NLAYERS * 256 * 128;
    unsigned short* linwt = WT + wo; wo += (size_t)NLAYERS * 256 * 256;
    unsigned short* g1t   = WT + wo; wo += (size_t)NLAYERS * 256 * 256;
    unsigned short* g2t   = WT + wo; wo += (size_t)NLAYERS * 256 * 256;
    unsigned short* vn1t  = WT + wo; wo += 256 * 256;
    unsigned short* vn2t  = WT + wo; wo += 256 * 256;
    unsigned short* ow1t  = WT + wo; wo += 256 * 256;

    // ---- weight prep: one dispatch + table build ----
    k_wprep<<<6400, 256, 0, stream>>>(
        cf_lin1, cf_mlp_w1, cf_mlp_w2, cf_lin2, lin_w, gin_w1, gin_w2,
        vn_w1, vn_w2, out_w1,
        lin1t, w1t, w2t, lin2t, linwt, g1t, g2t, vn1t, vn2t, ow1t);
    k_tab<<<dim3(NTAB / 128, NLAYERS), 256, 0, stream>>>(
        w1t, cf_mlp_b1, w2t, cf_mlp_b2, TAB);

    // ---- dst-sort both edge lists (combined dispatches) ----
    hipMemsetAsync(CNT, 0, (NC + NG) * sizeof(int), stream);
    k_hist2<<<(EC + EG) / 256, 256, 0, stream>>>(ei_conf, ei_graph, CNT);
    k_scan1m<<<288, 256, 0, stream>>>(CNT, ROWC, ROWG, BSUMC, BSUMG);
    k_scan2m<<<2, 256, 0, stream>>>(BSUMC, BSUMG);
    k_scan3m<<<288, 256, 0, stream>>>(ROWC, ROWG, BSUMC, BSUMG, CURC, CURG);
    k_perm2<<<(EC + EG) / 256, 256, 0, stream>>>(
        pos, ei_conf, ei_graph, attr_graph, CURC, CURG,
        PSRC, (float2*)PDCC, PGSRC, PATTR);

    // ---- init: X (no vn), SUMX0, VN0 ----
    k_init_x<<<NCONF, 256, 0, stream>>>(atom_emb, x_atom, vn_emb, XB, SUMX, VN0);

    float* vc = VN0;   // VN_i (consumed this layer)
    float* vx = VN1;   // VN_{i+1} (produced this layer)
    for (int i = 0; i < NLAYERS; ++i) {
        if (i < NLAYERS - 1)
            k_vnmlp<<<NCONF / 128, 512, 0, stream>>>(
                SUMX, vc, vn1t, vn_b1, vn2t, vn_b2, vx);
        // ---- CFConv ----
        mgemm<6, 6><<<dim3(1, NC / 128), 256, 0, stream>>>(
            0, XB, lin1t + (size_t)i * 128 * 256, nullptr, 0, CFH,
            256, 256, 128, 0, 0, 0, vc);
        k_cf_agg<<<NC / 16, 256, 0, stream>>>(TAB + (size_t)i * NTAB * F,
            ROWC, PSRC, (const float2*)PDCC, CFH, HAGG);
        // ---- GIN ----
        k_xa2<<<NMOL, 256, 0, stream>>>(XB, vc, XA);
        k_gin_agg<<<NG, 256, 0, stream>>>(
            XA, bond_emb + (size_t)i * 3 * 8 * H, ROWG, PGSRC, PATTR,
            gin_eps + i, AGGB, STATS);
        mgemm<2, 7><<<dim3(2, NG / 128), 256, 0, stream>>>(
            0, AGGB, g1t + (size_t)i * 256 * 256, gin_b1 + i * H, Z1, 0,
            256, 256, 256, 0, 0, STATS, 0);
        k_bnprep<<<1, 256, 0, stream>>>(STATS, gin_g1 + i * H, gin_be1 + i * H,
                                        SCA, SHA);
        mgemm<4, 7><<<dim3(2, NG / 128), 256, 0, stream>>>(
            Z1, 0, g2t + (size_t)i * 256 * 256, gin_b2 + i * H, Z2, 0,
            256, 256, 256, SCA, SHA, STATS + 512, 0);
        k_bnprep<<<1, 256, 0, stream>>>(STATS + 512, bn_g + i * H, bn_b + i * H,
                                        SCB, SHB);
        // ---- fused combine (+VN residual, +Z2 BN, SUMX for next layer) ----
        if (i < NLAYERS - 1)
            k_combine<true><<<NC / 128, 512, 0, stream>>>(
                HAGG, lin2t + (size_t)i * 256 * 128, cf_lin2_b + i * H,
                linwt + (size_t)i * 256 * 256, lin_b + i * H, Z2, SCB, SHB,
                vc, XB, SUMX);
        else
            k_combine<false><<<NC / 128, 512, 0, stream>>>(
                HAGG, lin2t + (size_t)i * 256 * 128, cf_lin2_b + i * H,
                linwt + (size_t)i * 256 * 256, lin_b + i * H, Z2, SCB, SHB,
                vc, XB, SUMX);
        // swap VN buffers
        float* t = vc; vc = vx; vx = t;
    }

    k_molmax<<<NMOL, 256, 0, stream>>>(XB, XM);
    mgemm<0, 1><<<dim3(2, NMOL / 128), 256, 0, stream>>>(
        XM, 0, ow1t, out_b1, Y1, 0, 256, 256, 256, 0, 0, 0, 0);
    k_head<<<NMOL, 256, 0, stream>>>(Y1, out_w2, out_b2, out);
}

// Round 11
// 928.401 us; speedup vs baseline: 9.8141x; 1.0196x over previous
//
#include <hip/hip_runtime.h>
#include <math.h>

#define H 256
#define F 128
#define NLAYERS 4
#define NG 8192
#define NC 65536
#define EC 524288
#define EG 32768
#define NCONF 4096
#define NMOL 512
#define NGAUSS 50
#define NTAB 8192
#define TABSTEP 0.001953125f   // 16 / 8192
#define INVSTEP 512.0f

using s16x8 = __attribute__((ext_vector_type(8))) short;
using f32x4 = __attribute__((ext_vector_type(4))) float;

static __device__ __forceinline__ unsigned short f2bf(float f) {
    unsigned int u = __float_as_uint(f);
    u += 0x7fffu + ((u >> 16) & 1u);   // RNE (finite values)
    return (unsigned short)(u >> 16);
}
static __device__ __forceinline__ float bf2f(unsigned short b) {
    return __uint_as_float(((unsigned int)b) << 16);
}
static __device__ __forceinline__ float bflo(unsigned int u) {
    return __uint_as_float(u << 16);
}
static __device__ __forceinline__ float bfhi(unsigned int u) {
    return __uint_as_float(u & 0xffff0000u);
}
// conformer id of node row i: r = i>>13, j = i&8191, c = (j>>4)*8 + r
static __device__ __forceinline__ int conf_of(int i) {
    return (((i & (NG - 1)) >> 4) << 3) + (i >> 13);
}

// ---------------- init: X (no vn), SUMX0, VN0 ----------------
__global__ __launch_bounds__(256) void k_init_x(const float* __restrict__ atom_emb,
    const int* __restrict__ x_atom, const float* __restrict__ vn_emb,
    unsigned short* __restrict__ x, float* __restrict__ sumx,
    float* __restrict__ vn0)
{
    int c = blockIdx.x, h = threadIdx.x;
    int m = c >> 3, r = c & 7;
    float sum = 0.f;
    for (int t = 0; t < 16; ++t) {
        int g = m * 16 + t;
        float s = 0.f;
#pragma unroll
        for (int f = 0; f < 9; ++f) {
            int a = x_atom[g * 9 + f];
            s += atom_emb[(f * 64 + a) * H + h];
        }
        x[((size_t)r * NG + g) * H + h] = f2bf(s);
        sum += s;
    }
    sumx[(size_t)c * H + h] = sum;
    vn0[(size_t)c * H + h] = vn_emb[h];
}

// XA[g] = max_r (X[r*NG+g] + VN[conf]) ; block = molecule
__global__ __launch_bounds__(256) void k_xa2(const unsigned short* __restrict__ X,
    const float* __restrict__ vn, unsigned short* __restrict__ xa)
{
    int m = blockIdx.x, h = threadIdx.x;
    float xam[16];
#pragma unroll
    for (int t = 0; t < 16; ++t) xam[t] = -3.4e38f;
#pragma unroll 2
    for (int r = 0; r < 8; ++r) {
        float vv = vn[(size_t)(m * 8 + r) * H + h];
        size_t base = ((size_t)r * NG + m * 16) * H + h;
#pragma unroll
        for (int t = 0; t < 16; ++t)
            xam[t] = fmaxf(xam[t], bf2f(X[base + (size_t)t * H]) + vv);
    }
#pragma unroll
    for (int t = 0; t < 16; ++t)
        xa[(size_t)(m * 16 + t) * H + h] = f2bf(xam[t]);
}

__global__ __launch_bounds__(256) void k_molmax(const unsigned short* __restrict__ x,
                                                float* __restrict__ xm)
{
    int m = blockIdx.x, h = threadIdx.x;
    float best = -3.4e38f;
    for (int r = 0; r < 8; ++r) {
        size_t base = ((size_t)r * NG + m * 16) * H + h;
#pragma unroll 4
        for (int t = 0; t < 16; ++t) best = fmaxf(best, bf2f(x[base + (size_t)t * H]));
    }
    xm[(size_t)m * H + h] = best;
}

__global__ __launch_bounds__(256) void k_head(const float* __restrict__ y1,
    const float* __restrict__ w2, const float* __restrict__ b2,
    float* __restrict__ out)
{
    __shared__ float red[256];
    int m = blockIdx.x, h = threadIdx.x;
    red[h] = y1[(size_t)m * H + h] * w2[h];
    __syncthreads();
    for (int s = 128; s > 0; s >>= 1) {
        if (h < s) red[h] += red[h + s];
        __syncthreads();
    }
    if (h == 0) out[m] = red[0] + b2[0];
}

// ---------------- all weight transposes in ONE dispatch (6400 blocks) ----------------
__global__ __launch_bounds__(256) void k_wprep(
    const float* __restrict__ cf_lin1, const float* __restrict__ cf_mlp_w1,
    const float* __restrict__ cf_mlp_w2, const float* __restrict__ cf_lin2,
    const float* __restrict__ lin_w, const float* __restrict__ gin_w1,
    const float* __restrict__ gin_w2, const float* __restrict__ vn_w1,
    const float* __restrict__ vn_w2, const float* __restrict__ out_w1,
    unsigned short* __restrict__ lin1t, unsigned short* __restrict__ w1t,
    unsigned short* __restrict__ w2t, unsigned short* __restrict__ lin2t,
    unsigned short* __restrict__ linwt, unsigned short* __restrict__ g1t,
    unsigned short* __restrict__ g2t, unsigned short* __restrict__ vn1t,
    unsigned short* __restrict__ vn2t, unsigned short* __restrict__ ow1t)
{
    int b = blockIdx.x;
    const float* W; unsigned short* Wt; int K, N, Kp, l, n;
    if (b < 512)      { b -= 0;    l = b >> 7; n = b & 127; W = cf_lin1;   Wt = lin1t; K = 256; N = 128; Kp = 256; }
    else if (b < 1024){ b -= 512;  l = b >> 7; n = b & 127; W = cf_mlp_w1; Wt = w1t;   K = 50;  N = 128; Kp = 64;  }
    else if (b < 1536){ b -= 1024; l = b >> 7; n = b & 127; W = cf_mlp_w2; Wt = w2t;   K = 128; N = 128; Kp = 128; }
    else if (b < 2560){ b -= 1536; l = b >> 8; n = b & 255; W = cf_lin2;   Wt = lin2t; K = 128; N = 256; Kp = 128; }
    else if (b < 3584){ b -= 2560; l = b >> 8; n = b & 255; W = lin_w;     Wt = linwt; K = 256; N = 256; Kp = 256; }
    else if (b < 4608){ b -= 3584; l = b >> 8; n = b & 255; W = gin_w1;    Wt = g1t;   K = 256; N = 256; Kp = 256; }
    else if (b < 5632){ b -= 4608; l = b >> 8; n = b & 255; W = gin_w2;    Wt = g2t;   K = 256; N = 256; Kp = 256; }
    else if (b < 5888){ l = 0; n = b - 5632; W = vn_w1;  Wt = vn1t; K = 256; N = 256; Kp = 256; }
    else if (b < 6144){ l = 0; n = b - 5888; W = vn_w2;  Wt = vn2t; K = 256; N = 256; Kp = 256; }
    else              { l = 0; n = b - 6144; W = out_w1; Wt = ow1t; K = 256; N = 256; Kp = 256; }
    W  += (size_t)l * K * N;
    Wt += (size_t)l * N * Kp;
    for (int k = threadIdx.x; k < Kp; k += 256)
        Wt[(size_t)n * Kp + k] = (k < K) ? f2bf(W[(size_t)k * N + n]) : (unsigned short)0;
}

// ---------------- combined counting sort (both edge lists) ----------------

__global__ __launch_bounds__(256) void k_hist2(const int* __restrict__ ei_conf,
    const int* __restrict__ ei_graph, int* __restrict__ cnt)
{
    int idx = blockIdx.x * 256 + threadIdx.x;
    if (idx < EC) atomicAdd(&cnt[ei_conf[EC + idx]], 1);
    else {
        int j = idx - EC;
        if (j < EG) atomicAdd(&cnt[NC + ei_graph[EG + j]], 1);
    }
}

__global__ __launch_bounds__(256) void k_scan1m(const int* __restrict__ cnt,
    int* __restrict__ rowc, int* __restrict__ rowg,
    int* __restrict__ bsumc, int* __restrict__ bsumg)
{
    __shared__ int sh[256];
    int t = threadIdx.x, b = blockIdx.x;
    const int* src; int* part; int* bsum; int bb;
    if (b < 256) { src = cnt; part = rowc; bsum = bsumc; bb = b; }
    else         { src = cnt + NC; part = rowg; bsum = bsumg; bb = b - 256; }
    int idx = bb * 256 + t;
    int v = src[idx];
    sh[t] = v; __syncthreads();
    for (int s = 1; s < 256; s <<= 1) {
        int add = (t >= s) ? sh[t - s] : 0;
        __syncthreads();
        sh[t] += add;
        __syncthreads();
    }
    part[idx] = sh[t] - v;
    if (t == 255) bsum[bb] = sh[255];
}

__global__ __launch_bounds__(256) void k_scan2m(int* __restrict__ bsumc,
                                                int* __restrict__ bsumg)
{
    __shared__ int sh[256];
    int t = threadIdx.x;
    int* bs = (blockIdx.x == 0) ? bsumc : bsumg;
    int nb = (blockIdx.x == 0) ? 256 : 32;
    int v = (t < nb) ? bs[t] : 0;
    sh[t] = v; __syncthreads();
    for (int s = 1; s < 256; s <<= 1) {
        int add = (t >= s) ? sh[t - s] : 0;
        __syncthreads();
        sh[t] += add;
        __syncthreads();
    }
    if (t < nb) bs[t] = sh[t] - v;
}

__global__ __launch_bounds__(256) void k_scan3m(int* __restrict__ rowc,
    int* __restrict__ rowg, const int* __restrict__ bsumc,
    const int* __restrict__ bsumg, int* __restrict__ curc, int* __restrict__ curg)
{
    int t = threadIdx.x, b = blockIdx.x;
    if (b < 256) {
        int idx = b * 256 + t;
        int v = rowc[idx] + bsumc[b];
        rowc[idx] = v; curc[idx] = v;
        if (idx == 0) rowc[NC] = EC;
    } else {
        int bb = b - 256;
        int idx = bb * 256 + t;
        int v = rowg[idx] + bsumg[bb];
        rowg[idx] = v; curg[idx] = v;
        if (idx == 0) rowg[NG] = EG;
    }
}

__global__ __launch_bounds__(256) void k_perm2(const float* __restrict__ pos,
    const int* __restrict__ ei_conf, const int* __restrict__ ei_graph,
    const int* __restrict__ attr, int* __restrict__ curc, int* __restrict__ curg,
    int* __restrict__ psrc, float2* __restrict__ pdcc,
    int* __restrict__ pgsrc, int* __restrict__ pattr)
{
    int idx = blockIdx.x * 256 + threadIdx.x;
    if (idx < EC) {
        int s = ei_conf[idx], t = ei_conf[EC + idx];
        float dx = pos[s * 3 + 0] - pos[t * 3 + 0];
        float dy = pos[s * 3 + 1] - pos[t * 3 + 1];
        float dz = pos[s * 3 + 2] - pos[t * 3 + 2];
        float dd = sqrtf(dx * dx + dy * dy + dz * dz);
        int p = atomicAdd(&curc[t], 1);
        psrc[p] = s;
        pdcc[p] = make_float2(dd, 0.5f * (cosf(dd * 0.314159265358979f) + 1.0f));
    } else {
        int j = idx - EC;
        if (j < EG) {
            int s = ei_graph[j], t = ei_graph[EG + j];
            int p = atomicAdd(&curg[t], 1);
            pgsrc[p] = s;
            pattr[p] = attr[j * 3] | (attr[j * 3 + 1] << 4) | (attr[j * 3 + 2] << 8);
        }
    }
}

// ---------------- gather-based aggregations (no atomics) ----------------

// 8 channels/thread, 16 lanes/node, 16 nodes/block; NN table; 2-edge unroll.
__global__ __launch_bounds__(256) void k_cf_agg(const unsigned short* __restrict__ tab,
    const int* __restrict__ rowptr, const int* __restrict__ psrc,
    const float2* __restrict__ pdcc,
    const unsigned short* __restrict__ cfh, unsigned short* __restrict__ hagg)
{
    int slot = threadIdx.x >> 4;
    int c8 = (threadIdx.x & 15) << 3;
    int n = blockIdx.x * 16 + slot;
    int lo = rowptr[n], hi = rowptr[n + 1];
    float a[8] = {0.f, 0.f, 0.f, 0.f, 0.f, 0.f, 0.f, 0.f};
    int e = lo;
    for (; e + 2 <= hi; e += 2) {
        int s0 = psrc[e], s1 = psrc[e + 1];
        float2 d0 = pdcc[e], d1 = pdcc[e + 1];
        int it0 = (int)(d0.x * INVSTEP + 0.5f);
        int it1 = (int)(d1.x * INVSTEP + 0.5f);
        if (it0 > NTAB - 1) it0 = NTAB - 1;
        if (it1 > NTAB - 1) it1 = NTAB - 1;
        uint4 Ta = *(const uint4*)&tab[(size_t)it0 * F + c8];
        uint4 Ha = *(const uint4*)&cfh[(size_t)s0 * F + c8];
        uint4 Tb = *(const uint4*)&tab[(size_t)it1 * F + c8];
        uint4 Hb = *(const uint4*)&cfh[(size_t)s1 * F + c8];
        float c0 = d0.y, c1 = d1.y;
        a[0] = fmaf(bflo(Ta.x) * c0, bflo(Ha.x), a[0]);
        a[1] = fmaf(bfhi(Ta.x) * c0, bfhi(Ha.x), a[1]);
        a[2] = fmaf(bflo(Ta.y) * c0, bflo(Ha.y), a[2]);
        a[3] = fmaf(bfhi(Ta.y) * c0, bfhi(Ha.y), a[3]);
        a[4] = fmaf(bflo(Ta.z) * c0, bflo(Ha.z), a[4]);
        a[5] = fmaf(bfhi(Ta.z) * c0, bfhi(Ha.z), a[5]);
        a[6] = fmaf(bflo(Ta.w) * c0, bflo(Ha.w), a[6]);
        a[7] = fmaf(bfhi(Ta.w) * c0, bfhi(Ha.w), a[7]);
        a[0] = fmaf(bflo(Tb.x) * c1, bflo(Hb.x), a[0]);
        a[1] = fmaf(bfhi(Tb.x) * c1, bfhi(Hb.x), a[1]);
        a[2] = fmaf(bflo(Tb.y) * c1, bflo(Hb.y), a[2]);
        a[3] = fmaf(bfhi(Tb.y) * c1, bfhi(Hb.y), a[3]);
        a[4] = fmaf(bflo(Tb.z) * c1, bflo(Hb.z), a[4]);
        a[5] = fmaf(bfhi(Tb.z) * c1, bfhi(Hb.z), a[5]);
        a[6] = fmaf(bflo(Tb.w) * c1, bflo(Hb.w), a[6]);
        a[7] = fmaf(bfhi(Tb.w) * c1, bfhi(Hb.w), a[7]);
    }
    if (e < hi) {
        int s0 = psrc[e];
        float2 d0 = pdcc[e];
        int it0 = (int)(d0.x * INVSTEP + 0.5f);
        if (it0 > NTAB - 1) it0 = NTAB - 1;
        uint4 Ta = *(const uint4*)&tab[(size_t)it0 * F + c8];
        uint4 Ha = *(const uint4*)&cfh[(size_t)s0 * F + c8];
        float c0 = d0.y;
        a[0] = fmaf(bflo(Ta.x) * c0, bflo(Ha.x), a[0]);
        a[1] = fmaf(bfhi(Ta.x) * c0, bfhi(Ha.x), a[1]);
        a[2] = fmaf(bflo(Ta.y) * c0, bflo(Ha.y), a[2]);
        a[3] = fmaf(bfhi(Ta.y) * c0, bfhi(Ha.y), a[3]);
        a[4] = fmaf(bflo(Ta.z) * c0, bflo(Ha.z), a[4]);
        a[5] = fmaf(bfhi(Ta.z) * c0, bfhi(Ha.z), a[5]);
        a[6] = fmaf(bflo(Ta.w) * c0, bflo(Ha.w), a[6]);
        a[7] = fmaf(bfhi(Ta.w) * c0, bfhi(Ha.w), a[7]);
    }
    uint4 o;
    o.x = ((unsigned)f2bf(a[1]) << 16) | f2bf(a[0]);
    o.y = ((unsigned)f2bf(a[3]) << 16) | f2bf(a[2]);
    o.z = ((unsigned)f2bf(a[5]) << 16) | f2bf(a[4]);
    o.w = ((unsigned)f2bf(a[7]) << 16) | f2bf(a[6]);
    *(uint4*)&hagg[(size_t)n * F + c8] = o;
}

// AGG[g] = bf16((1+eps)*xa[g] + sum_e relu(xa[pgsrc[e]] + bond_sum)); block 0 zeroes stats
__global__ __launch_bounds__(256) void k_gin_agg(const unsigned short* __restrict__ xa,
    const float* __restrict__ bond, const int* __restrict__ growptr,
    const int* __restrict__ pgsrc, const int* __restrict__ pattr,
    const float* __restrict__ eps_p, unsigned short* __restrict__ agg,
    float* __restrict__ stats)
{
    int g = blockIdx.x, h = threadIdx.x;
    if (g == 0) {
#pragma unroll
        for (int q = 0; q < 4; ++q) stats[q * 256 + h] = 0.f;
    }
    int lo = growptr[g], hi = growptr[g + 1];
    float acc = 0.f;
    for (int e = lo; e < hi; ++e) {
        int s = pgsrc[e], a = pattr[e];
        float v = bf2f(xa[(size_t)s * H + h])
                + bond[(a & 15) * H + h]
                + bond[(8 + ((a >> 4) & 15)) * H + h]
                + bond[(16 + (a >> 8)) * H + h];
        acc += fmaxf(v, 0.f);
    }
    agg[(size_t)g * H + h] =
        f2bf((1.0f + eps_p[0]) * bf2f(xa[(size_t)g * H + h]) + acc);
}

// ---------------- MFMA GEMM ----------------
// tile 128x128, BK=64, 4 waves.
// ASRC: 0 = f32 A, 2 = bf16 A, 5 = bf16 A + in-kernel BN(scale/shift from stats_in)+relu,
//       6 = bf16 A + VN[conf(row)] add (f32)
// EPI:  1 = relu->Cf, 6 = ->bf16 Cb, 7 = ->Cf + column stats, 8 = ->bf16 Cb + column stats
template<int ASRC, int EPI>
__global__ __launch_bounds__(256) void mgemm(
    const float* __restrict__ Af, const unsigned short* __restrict__ Ab,
    const unsigned short* __restrict__ Bt,
    const float* __restrict__ bias,
    float* __restrict__ Cf, unsigned short* __restrict__ Cb,
    int K, int Kp, int ldc,
    const float* __restrict__ gam, const float* __restrict__ bet,
    const float* __restrict__ stats_in, float* __restrict__ stats_out,
    const float* __restrict__ vnp)
{
    __shared__ unsigned short As[128][72];
    __shared__ unsigned short Bs[128][72];
    __shared__ float scs[256], shs[256];
    const int tid = threadIdx.x;
    const int bm = blockIdx.y * 128;
    const int bn = blockIdx.x * 128;
    const int lane = tid & 63;
    const int wid = tid >> 6;
    const int wm = wid >> 1, wn = wid & 1;
    const int rsel = lane & 15, ksel = (lane >> 4) * 8;

    if constexpr (ASRC == 5) {
        // BN prep in-kernel: scale/shift over K (=256) from stats_in + gamma/beta
        float mean = stats_in[tid] * (1.0f / NG);
        float var = stats_in[256 + tid] * (1.0f / NG) - mean * mean;
        float sc = gam[tid] * rsqrtf(var + 1e-5f);
        scs[tid] = sc;
        shs[tid] = bet[tid] - mean * sc;
        __syncthreads();
    }

    f32x4 acc[4][4];
#pragma unroll
    for (int a = 0; a < 4; ++a)
#pragma unroll
        for (int b = 0; b < 4; ++b) acc[a][b] = (f32x4){0.f, 0.f, 0.f, 0.f};

    for (int k0 = 0; k0 < Kp; k0 += 64) {
#pragma unroll
        for (int i = 0; i < 4; ++i) {
            int c = tid + i * 256;
            int row = c >> 3, kc = (c & 7) * 8;
            *(uint4*)&Bs[row][kc] =
                *(const uint4*)&Bt[(size_t)(bn + row) * Kp + k0 + kc];
        }
        if constexpr (ASRC == 0) {
#pragma unroll
            for (int i = 0; i < 8; ++i) {
                int c = tid + i * 256;
                int row = c >> 4, kc = (c & 15) * 4;
                float4 v = *(const float4*)&Af[(size_t)(bm + row) * K + k0 + kc];
                ushort4 b;
                b.x = f2bf(v.x); b.y = f2bf(v.y); b.z = f2bf(v.z); b.w = f2bf(v.w);
                *(ushort4*)&As[row][kc] = b;
            }
        } else if constexpr (ASRC == 5) {
#pragma unroll
            for (int i = 0; i < 4; ++i) {
                int c = tid + i * 256;
                int row = c >> 3, kc = (c & 7) * 8;
                uint4 xv = *(const uint4*)&Ab[(size_t)(bm + row) * K + k0 + kc];
                const float* sp = &scs[k0 + kc];
                const float* hp = &shs[k0 + kc];
                float4 s0 = *(const float4*)sp, s1 = *(const float4*)(sp + 4);
                float4 h0 = *(const float4*)hp, h1 = *(const float4*)(hp + 4);
                uint4 o;
                o.x = ((unsigned)f2bf(fmaxf(fmaf(bfhi(xv.x), s0.y, h0.y), 0.f)) << 16)
                    | f2bf(fmaxf(fmaf(bflo(xv.x), s0.x, h0.x), 0.f));
                o.y = ((unsigned)f2bf(fmaxf(fmaf(bfhi(xv.y), s0.w, h0.w), 0.f)) << 16)
                    | f2bf(fmaxf(fmaf(bflo(xv.y), s0.z, h0.z), 0.f));
                o.z = ((unsigned)f2bf(fmaxf(fmaf(bfhi(xv.z), s1.y, h1.y), 0.f)) << 16)
                    | f2bf(fmaxf(fmaf(bflo(xv.z), s1.x, h1.x), 0.f));
                o.w = ((unsigned)f2bf(fmaxf(fmaf(bfhi(xv.w), s1.w, h1.w), 0.f)) << 16)
                    | f2bf(fmaxf(fmaf(bflo(xv.w), s1.z, h1.z), 0.f));
                *(uint4*)&As[row][kc] = o;
            }
        } else if constexpr (ASRC == 6) {
#pragma unroll
            for (int i = 0; i < 4; ++i) {
                int c = tid + i * 256;
                int row = c >> 3, kc = (c & 7) * 8;
                int gm = bm + row;
                int cf = conf_of(gm);
                uint4 xv = *(const uint4*)&Ab[(size_t)gm * K + k0 + kc];
                const float* vr = &vnp[(size_t)cf * 256 + k0 + kc];
                float4 v0 = *(const float4*)vr;
                float4 v1 = *(const float4*)(vr + 4);
                uint4 o;
                o.x = ((unsigned)f2bf(bfhi(xv.x) + v0.y) << 16) | f2bf(bflo(xv.x) + v0.x);
                o.y = ((unsigned)f2bf(bfhi(xv.y) + v0.w) << 16) | f2bf(bflo(xv.y) + v0.z);
                o.z = ((unsigned)f2bf(bfhi(xv.z) + v1.y) << 16) | f2bf(bflo(xv.z) + v1.x);
                o.w = ((unsigned)f2bf(bfhi(xv.w) + v1.w) << 16) | f2bf(bflo(xv.w) + v1.z);
                *(uint4*)&As[row][kc] = o;
            }
        } else {
#pragma unroll
            for (int i = 0; i < 4; ++i) {
                int c = tid + i * 256;
                int row = c >> 3, kc = (c & 7) * 8;
                *(uint4*)&As[row][kc] =
                    *(const uint4*)&Ab[(size_t)(bm + row) * K + k0 + kc];
            }
        }
        __syncthreads();
#pragma unroll
        for (int kk = 0; kk < 64; kk += 32) {
            s16x8 af[4], bf[4];
#pragma unroll
            for (int mi = 0; mi < 4; ++mi)
                af[mi] = *(const s16x8*)&As[wm * 64 + mi * 16 + rsel][kk + ksel];
#pragma unroll
            for (int ni = 0; ni < 4; ++ni)
                bf[ni] = *(const s16x8*)&Bs[wn * 64 + ni * 16 + rsel][kk + ksel];
#pragma unroll
            for (int mi = 0; mi < 4; ++mi)
#pragma unroll
                for (int ni = 0; ni < 4; ++ni)
                    acc[mi][ni] = __builtin_amdgcn_mfma_f32_16x16x32_bf16(
                        af[mi], bf[ni], acc[mi][ni], 0, 0, 0);
        }
        __syncthreads();
    }

    float colS[4] = {0.f, 0.f, 0.f, 0.f};
    float colQ[4] = {0.f, 0.f, 0.f, 0.f};
#pragma unroll
    for (int mi = 0; mi < 4; ++mi) {
#pragma unroll
        for (int r = 0; r < 4; ++r) {
            int m = bm + wm * 64 + mi * 16 + ((lane >> 4) << 2) + r;
#pragma unroll
            for (int ni = 0; ni < 4; ++ni) {
                int n = bn + wn * 64 + ni * 16 + (lane & 15);
                float v = acc[mi][ni][r];
                if (bias) v += bias[n];
                if constexpr (EPI == 1) {
                    Cf[(size_t)m * ldc + n] = fmaxf(v, 0.f);
                } else if constexpr (EPI == 6) {
                    Cb[(size_t)m * ldc + n] = f2bf(v);
                } else if constexpr (EPI == 7) {
                    Cf[(size_t)m * ldc + n] = v;
                    colS[ni] += v;
                    colQ[ni] = fmaf(v, v, colQ[ni]);
                } else {  // EPI == 8
                    Cb[(size_t)m * ldc + n] = f2bf(v);
                    colS[ni] += v;
                    colQ[ni] = fmaf(v, v, colQ[ni]);
                }
            }
        }
    }
    if constexpr (EPI == 7 || EPI == 8) {
        float* cs = (float*)&As[0][0];
        cs[tid] = 0.f;
        __syncthreads();
#pragma unroll
        for (int ni = 0; ni < 4; ++ni) {
            int nl = wn * 64 + ni * 16 + (lane & 15);
            atomicAdd(&cs[nl], colS[ni]);
            atomicAdd(&cs[128 + nl], colQ[ni]);
        }
        __syncthreads();
        if (tid < 128) {
            atomicAdd(&stats_out[bn + tid], cs[tid]);
            atomicAdd(&stats_out[256 + bn + tid], cs[128 + tid]);
        }
    }
}

// ---------------- fused table build: TAB[l][i] = mlp_l(gauss(i*step)) ----------------
__global__ __launch_bounds__(256) void k_tab(
    const unsigned short* __restrict__ w1t, const float* __restrict__ b1,
    const unsigned short* __restrict__ w2t, const float* __restrict__ b2,
    unsigned short* __restrict__ tab)
{
    __shared__ unsigned short As[128][72];
    __shared__ unsigned short Bs[128][72];
    __shared__ unsigned short T1s[128][152];
    const int l = blockIdx.y;
    w1t += (size_t)l * 128 * 64;  b1 += l * 128;
    w2t += (size_t)l * 128 * 128; b2 += l * 128;
    tab += (size_t)l * NTAB * F;
    const int tid = threadIdx.x;
    const int bm = blockIdx.x * 128;
    const int lane = tid & 63, wid = tid >> 6;
    const int wm = wid >> 1, wn = wid & 1;
    const int rsel = lane & 15, ksel = (lane >> 4) * 8;

    f32x4 acc[4][4];
#pragma unroll
    for (int a = 0; a < 4; ++a)
#pragma unroll
        for (int b = 0; b < 4; ++b) acc[a][b] = (f32x4){0.f, 0.f, 0.f, 0.f};

#pragma unroll
    for (int i = 0; i < 8; ++i) {
        int c = tid + i * 256;
        int row = c >> 4, kc = (c & 15) * 4;
        float dv = (float)(bm + row) * TABSTEP;
        ushort4 b;
        unsigned short* bp = (unsigned short*)&b;
#pragma unroll
        for (int j = 0; j < 4; ++j) {
            int k = kc + j;
            float f = 0.f;
            if (k < NGAUSS) {
                float t = dv - (float)k * (10.0f / 49.0f);
                f = __expf(-12.005f * t * t);
            }
            bp[j] = f2bf(f);
        }
        *(ushort4*)&As[row][kc] = b;
    }
#pragma unroll
    for (int i = 0; i < 4; ++i) {
        int c = tid + i * 256;
        int row = c >> 3, kc = (c & 7) * 8;
        *(uint4*)&Bs[row][kc] = *(const uint4*)&w1t[(size_t)row * 64 + kc];
    }
    __syncthreads();
#pragma unroll
    for (int kk = 0; kk < 64; kk += 32) {
        s16x8 af[4], bf[4];
#pragma unroll
        for (int mi = 0; mi < 4; ++mi)
            af[mi] = *(const s16x8*)&As[wm * 64 + mi * 16 + rsel][kk + ksel];
#pragma unroll
        for (int ni = 0; ni < 4; ++ni)
            bf[ni] = *(const s16x8*)&Bs[wn * 64 + ni * 16 + rsel][kk + ksel];
#pragma unroll
        for (int mi = 0; mi < 4; ++mi)
#pragma unroll
            for (int ni = 0; ni < 4; ++ni)
                acc[mi][ni] = __builtin_amdgcn_mfma_f32_16x16x32_bf16(
                    af[mi], bf[ni], acc[mi][ni], 0, 0, 0);
    }
    __syncthreads();
#pragma unroll
    for (int mi = 0; mi < 4; ++mi)
#pragma unroll
        for (int r = 0; r < 4; ++r) {
            int mrow = wm * 64 + mi * 16 + ((lane >> 4) << 2) + r;
#pragma unroll
            for (int ni = 0; ni < 4; ++ni) {
                int n = wn * 64 + ni * 16 + (lane & 15);
                T1s[mrow][n] = f2bf(fmaxf(acc[mi][ni][r] + b1[n], 0.f));
            }
        }
#pragma unroll
    for (int a = 0; a < 4; ++a)
#pragma unroll
        for (int b = 0; b < 4; ++b) acc[a][b] = (f32x4){0.f, 0.f, 0.f, 0.f};
    for (int k0 = 0; k0 < 128; k0 += 64) {
#pragma unroll
        for (int i = 0; i < 4; ++i) {
            int c = tid + i * 256;
            int row = c >> 3, kc = (c & 7) * 8;
            *(uint4*)&Bs[row][kc] = *(const uint4*)&w2t[(size_t)row * 128 + k0 + kc];
        }
        __syncthreads();
#pragma unroll
        for (int kk = 0; kk < 64; kk += 32) {
            s16x8 af[4], bf[4];
#pragma unroll
            for (int mi = 0; mi < 4; ++mi)
                af[mi] = *(const s16x8*)&T1s[wm * 64 + mi * 16 + rsel][k0 + kk + ksel];
#pragma unroll
            for (int ni = 0; ni < 4; ++ni)
                bf[ni] = *(const s16x8*)&Bs[wn * 64 + ni * 16 + rsel][kk + ksel];
#pragma unroll
            for (int mi = 0; mi < 4; ++mi)
#pragma unroll
                for (int ni = 0; ni < 4; ++ni)
                    acc[mi][ni] = __builtin_amdgcn_mfma_f32_16x16x32_bf16(
                        af[mi], bf[ni], acc[mi][ni], 0, 0, 0);
        }
        __syncthreads();
    }
#pragma unroll
    for (int mi = 0; mi < 4; ++mi)
#pragma unroll
        for (int r = 0; r < 4; ++r) {
            int m = bm + wm * 64 + mi * 16 + ((lane >> 4) << 2) + r;
#pragma unroll
            for (int ni = 0; ni < 4; ++ni) {
                int n = wn * 64 + ni * 16 + (lane & 15);
                tab[(size_t)m * F + n] = f2bf(acc[mi][ni][r] + b2[n]);
            }
        }
}

// ---------------- fused vn MLP: VNout = relu(relu((SUMX+17*VNin)@w1+b1)@w2+b2) ----------------
__global__ __launch_bounds__(512) void k_vnmlp(
    const float* __restrict__ SUMX, const float* __restrict__ VNin,
    const unsigned short* __restrict__ w1, const float* __restrict__ b1,
    const unsigned short* __restrict__ w2, const float* __restrict__ b2,
    float* __restrict__ VNout)
{
    __shared__ unsigned short As[128][72];
    __shared__ unsigned short Bs[256][72];
    __shared__ unsigned short Ts[128][264];
    const int tid = threadIdx.x;
    const int bm = blockIdx.x * 128;
    const int lane = tid & 63, wid = tid >> 6;
    const int wm = wid >> 2, wn = wid & 3;
    const int rsel = lane & 15, ksel = (lane >> 4) * 8;

    f32x4 acc[4][4];
#pragma unroll
    for (int a = 0; a < 4; ++a)
#pragma unroll
        for (int b = 0; b < 4; ++b) acc[a][b] = (f32x4){0.f, 0.f, 0.f, 0.f};
    for (int k0 = 0; k0 < 256; k0 += 64) {
#pragma unroll
        for (int i = 0; i < 4; ++i) {
            int c = tid + i * 512;
            int row = c >> 4, kc = (c & 15) * 4;
            size_t off = (size_t)(bm + row) * 256 + k0 + kc;
            float4 sx = *(const float4*)&SUMX[off];
            float4 vv = *(const float4*)&VNin[off];
            ushort4 b;
            b.x = f2bf(fmaf(17.f, vv.x, sx.x));
            b.y = f2bf(fmaf(17.f, vv.y, sx.y));
            b.z = f2bf(fmaf(17.f, vv.z, sx.z));
            b.w = f2bf(fmaf(17.f, vv.w, sx.w));
            *(ushort4*)&As[row][kc] = b;
        }
#pragma unroll
        for (int i = 0; i < 4; ++i) {
            int c = tid + i * 512;
            int row = c >> 3, kc = (c & 7) * 8;
            *(uint4*)&Bs[row][kc] = *(const uint4*)&w1[(size_t)row * 256 + k0 + kc];
        }
        __syncthreads();
#pragma unroll
        for (int kk = 0; kk < 64; kk += 32) {
            s16x8 af[4], bf[4];
#pragma unroll
            for (int mi = 0; mi < 4; ++mi)
                af[mi] = *(const s16x8*)&As[wm * 64 + mi * 16 + rsel][kk + ksel];
#pragma unroll
            for (int ni = 0; ni < 4; ++ni)
                bf[ni] = *(const s16x8*)&Bs[wn * 64 + ni * 16 + rsel][kk + ksel];
#pragma unroll
            for (int mi = 0; mi < 4; ++mi)
#pragma unroll
                for (int ni = 0; ni < 4; ++ni)
                    acc[mi][ni] = __builtin_amdgcn_mfma_f32_16x16x32_bf16(
                        af[mi], bf[ni], acc[mi][ni], 0, 0, 0);
        }
        __syncthreads();
    }
#pragma unroll
    for (int mi = 0; mi < 4; ++mi)
#pragma unroll
        for (int r = 0; r < 4; ++r) {
            int mrow = wm * 64 + mi * 16 + ((lane >> 4) << 2) + r;
#pragma unroll
            for (int ni = 0; ni < 4; ++ni) {
                int n = wn * 64 + ni * 16 + (lane & 15);
                Ts[mrow][n] = f2bf(fmaxf(acc[mi][ni][r] + b1[n], 0.f));
            }
        }
#pragma unroll
    for (int a = 0; a < 4; ++a)
#pragma unroll
        for (int b = 0; b < 4; ++b) acc[a][b] = (f32x4){0.f, 0.f, 0.f, 0.f};
    for (int k0 = 0; k0 < 256; k0 += 64) {
#pragma unroll
        for (int i = 0; i < 4; ++i) {
            int c = tid + i * 512;
            int row = c >> 3, kc = (c & 7) * 8;
            *(uint4*)&Bs[row][kc] = *(const uint4*)&w2[(size_t)row * 256 + k0 + kc];
        }
        __syncthreads();
#pragma unroll
        for (int kk = 0; kk < 64; kk += 32) {
            s16x8 af[4], bf[4];
#pragma unroll
            for (int mi = 0; mi < 4; ++mi)
                af[mi] = *(const s16x8*)&Ts[wm * 64 + mi * 16 + rsel][k0 + kk + ksel];
#pragma unroll
            for (int ni = 0; ni < 4; ++ni)
                bf[ni] = *(const s16x8*)&Bs[wn * 64 + ni * 16 + rsel][kk + ksel];
#pragma unroll
            for (int mi = 0; mi < 4; ++mi)
#pragma unroll
                for (int ni = 0; ni < 4; ++ni)
                    acc[mi][ni] = __builtin_amdgcn_mfma_f32_16x16x32_bf16(
                        af[mi], bf[ni], acc[mi][ni], 0, 0, 0);
        }
        __syncthreads();
    }
#pragma unroll
    for (int mi = 0; mi < 4; ++mi)
#pragma unroll
        for (int r = 0; r < 4; ++r) {
            int m = bm + wm * 64 + mi * 16 + ((lane >> 4) << 2) + r;
#pragma unroll
            for (int ni = 0; ni < 4; ++ni) {
                int n = wn * 64 + ni * 16 + (lane & 15);
                VNout[(size_t)m * 256 + n] = fmaxf(acc[mi][ni][r] + b2[n], 0.f);
            }
        }
}

// ---- fused combine v2 (64-row tile, 2 blocks/CU, As aliased into H2s):
//   X = relu(X + VN + relu(HAGG@lin2+b2)@linw + b + bn(Z2)); optional SUMX.
template <bool DOSUM>
__global__ __launch_bounds__(512) void k_combine(
    const unsigned short* __restrict__ HAGG,
    const unsigned short* __restrict__ lin2t, const float* __restrict__ lin2b,
    const unsigned short* __restrict__ linwt, const float* __restrict__ linb,
    const float* __restrict__ Z2,
    const float* __restrict__ stats2, const float* __restrict__ gam2,
    const float* __restrict__ bet2,
    const float* __restrict__ vn, unsigned short* __restrict__ X,
    float* __restrict__ SUMX)
{
    __shared__ unsigned short H2s[64][264];     // 33.8 KB (As[64][72] aliased at base)
    __shared__ unsigned short Bs[256][72];      // 36.9 KB
    __shared__ float scb[256], shb[256];        // 2 KB
    unsigned short (*As)[72] = (unsigned short (*)[72])&H2s[0][0];
    const int tid = threadIdx.x;
    const int bm = blockIdx.x * 64;
    const int lane = tid & 63;
    const int w = tid >> 6;                     // 8 waves, 1m x 8n (32 cols each)
    const int rsel = lane & 15, ksel = (lane >> 4) * 8;

    if (tid < 256) {                            // Z2 BN prep
        float mean = stats2[tid] * (1.0f / NG);
        float var = stats2[256 + tid] * (1.0f / NG) - mean * mean;
        float sc = gam2[tid] * rsqrtf(var + 1e-5f);
        scb[tid] = sc;
        shb[tid] = bet2[tid] - mean * sc;
    }

    f32x4 acc[4][2];
#pragma unroll
    for (int a = 0; a < 4; ++a)
#pragma unroll
        for (int b = 0; b < 2; ++b) acc[a][b] = (f32x4){0.f, 0.f, 0.f, 0.f};

    // ---- stage 1: H2 = relu(HAGG[64x128] @ lin2 + b2) ----
    for (int k0 = 0; k0 < 128; k0 += 64) {
        {   // A: 64 rows x 8 chunks = 512 = one per thread
            int row = tid >> 3, kc = (tid & 7) * 8;
            *(uint4*)&As[row][kc] =
                *(const uint4*)&HAGG[(size_t)(bm + row) * 128 + k0 + kc];
        }
#pragma unroll
        for (int i = 0; i < 4; ++i) {
            int c = tid + i * 512;
            int row = c >> 3, kc = (c & 7) * 8;
            *(uint4*)&Bs[row][kc] = *(const uint4*)&lin2t[(size_t)row * 128 + k0 + kc];
        }
        __syncthreads();
#pragma unroll
        for (int kk = 0; kk < 64; kk += 32) {
            s16x8 af[4], bf[2];
#pragma unroll
            for (int mi = 0; mi < 4; ++mi)
                af[mi] = *(const s16x8*)&As[mi * 16 + rsel][kk + ksel];
#pragma unroll
            for (int ni = 0; ni < 2; ++ni)
                bf[ni] = *(const s16x8*)&Bs[w * 32 + ni * 16 + rsel][kk + ksel];
#pragma unroll
            for (int mi = 0; mi < 4; ++mi)
#pragma unroll
                for (int ni = 0; ni < 2; ++ni)
                    acc[mi][ni] = __builtin_amdgcn_mfma_f32_16x16x32_bf16(
                        af[mi], bf[ni], acc[mi][ni], 0, 0, 0);
        }
        __syncthreads();
    }
    // epilogue 1 -> H2s (safe: As reads all done, guarded by trailing syncthreads)
#pragma unroll
    for (int mi = 0; mi < 4; ++mi)
#pragma unroll
        for (int r = 0; r < 4; ++r) {
            int mrow = mi * 16 + ((lane >> 4) << 2) + r;
#pragma unroll
            for (int ni = 0; ni < 2; ++ni) {
                int n = w * 32 + ni * 16 + (lane & 15);
                H2s[mrow][n] = f2bf(fmaxf(acc[mi][ni][r] + lin2b[n], 0.f));
            }
        }

    // ---- stage 2: acc = H2 @ linw ----
#pragma unroll
    for (int a = 0; a < 4; ++a)
#pragma unroll
        for (int b = 0; b < 2; ++b) acc[a][b] = (f32x4){0.f, 0.f, 0.f, 0.f};
    for (int k0 = 0; k0 < 256; k0 += 64) {
#pragma unroll
        for (int i = 0; i < 4; ++i) {
            int c = tid + i * 512;
            int row = c >> 3, kc = (c & 7) * 8;
            *(uint4*)&Bs[row][kc] = *(const uint4*)&linwt[(size_t)row * 256 + k0 + kc];
        }
        __syncthreads();   // first iter also covers H2s epilogue writes + scb/shb
#pragma unroll
        for (int kk = 0; kk < 64; kk += 32) {
            s16x8 af[4], bf[2];
#pragma unroll
            for (int mi = 0; mi < 4; ++mi)
                af[mi] = *(const s16x8*)&H2s[mi * 16 + rsel][k0 + kk + ksel];
#pragma unroll
            for (int ni = 0; ni < 2; ++ni)
                bf[ni] = *(const s16x8*)&Bs[w * 32 + ni * 16 + rsel][kk + ksel];
#pragma unroll
            for (int mi = 0; mi < 4; ++mi)
#pragma unroll
                for (int ni = 0; ni < 2; ++ni)
                    acc[mi][ni] = __builtin_amdgcn_mfma_f32_16x16x32_bf16(
                        af[mi], bf[ni], acc[mi][ni], 0, 0, 0);
        }
        __syncthreads();
    }
    // epilogue 2: residual (+VN, +bn(Z2)), relu, bf16 store; per-conformer SUMX
#pragma unroll
    for (int mi = 0; mi < 4; ++mi) {
        int gm0 = bm + mi * 16;                  // 16-row group = one conformer
        int cf = conf_of(gm0);
        float srow[2] = {0.f, 0.f};
#pragma unroll
        for (int r = 0; r < 4; ++r) {
            int m = gm0 + ((lane >> 4) << 2) + r;
            const float* z2row = &Z2[(size_t)(m & (NG - 1)) * 256];
#pragma unroll
            for (int ni = 0; ni < 2; ++ni) {
                int n = w * 32 + ni * 16 + (lane & 15);
                size_t ix = (size_t)m * 256 + n;
                float z2v = fmaf(z2row[n], scb[n], shb[n]);
                float vnv = vn[(size_t)cf * 256 + n];
                float o = bf2f(X[ix]) + vnv + acc[mi][ni][r] + linb[n] + z2v;
                o = fmaxf(o, 0.f);
                X[ix] = f2bf(o);
                if (DOSUM) srow[ni] += o;
            }
        }
        if (DOSUM) {
#pragma unroll
            for (int ni = 0; ni < 2; ++ni) {
                float s = srow[ni];
                s += __shfl_xor(s, 16);
                s += __shfl_xor(s, 32);
                if ((lane >> 4) == 0) {
                    int n = w * 32 + ni * 16 + (lane & 15);
                    SUMX[(size_t)cf * 256 + n] = s;
                }
            }
        }
    }
}

// ---------------- launch ----------------
extern "C" void kernel_launch(void* const* d_in, const int* in_sizes, int n_in,
                              void* d_out, int out_size, void* d_ws, size_t ws_size,
                              hipStream_t stream)
{
    (void)in_sizes; (void)n_in; (void)out_size; (void)ws_size;
    const float* pos       = (const float*)d_in[0];
    const float* atom_emb  = (const float*)d_in[1];
    const float* vn_emb    = (const float*)d_in[2];
    const float* cf_lin1   = (const float*)d_in[3];
    const float* cf_mlp_w1 = (const float*)d_in[4];
    const float* cf_mlp_b1 = (const float*)d_in[5];
    const float* cf_mlp_w2 = (const float*)d_in[6];
    const float* cf_mlp_b2 = (const float*)d_in[7];
    const float* cf_lin2   = (const float*)d_in[8];
    const float* cf_lin2_b = (const float*)d_in[9];
    const float* lin_w     = (const float*)d_in[10];
    const float* lin_b     = (const float*)d_in[11];
    const float* bond_emb  = (const float*)d_in[12];
    const float* gin_eps   = (const float*)d_in[13];
    const float* gin_w1    = (const float*)d_in[14];
    const float* gin_b1    = (const float*)d_in[15];
    const float* gin_g1    = (const float*)d_in[16];
    const float* gin_be1   = (const float*)d_in[17];
    const float* gin_w2    = (const float*)d_in[18];
    const float* gin_b2    = (const float*)d_in[19];
    const float* bn_g      = (const float*)d_in[20];
    const float* bn_b      = (const float*)d_in[21];
    const float* vn_w1     = (const float*)d_in[22];
    const float* vn_b1     = (const float*)d_in[23];
    const float* vn_w2     = (const float*)d_in[24];
    const float* vn_b2     = (const float*)d_in[25];
    const float* out_w1    = (const float*)d_in[26];
    const float* out_b1    = (const float*)d_in[27];
    const float* out_w2    = (const float*)d_in[28];
    const float* out_b2    = (const float*)d_in[29];
    const int* x_atom      = (const int*)d_in[30];
    const int* ei_conf     = (const int*)d_in[34];
    const int* ei_graph    = (const int*)d_in[35];
    const int* attr_graph  = (const int*)d_in[36];
    float* out = (float*)d_out;
    float* ws  = (float*)d_ws;

    size_t o = 0;
    float* Z2   = ws + o; o += (size_t)NG * H;
    float* VN0  = ws + o; o += (size_t)NCONF * H;
    float* VN1  = ws + o; o += (size_t)NCONF * H;
    float* SUMX = ws + o; o += (size_t)NCONF * H;
    float* XM   = ws + o; o += (size_t)NMOL * H;
    float* Y1   = ws + o; o += (size_t)NMOL * H;
    float* STATS= ws + o; o += 1024;
    float* PDCC = ws + o; o += (size_t)2 * EC;
    // bf16 regions
    unsigned short* XB   = (unsigned short*)(ws + o); o += (size_t)NC * H / 2;
    unsigned short* XA   = (unsigned short*)(ws + o); o += (size_t)NG * H / 2;
    unsigned short* AGGB = (unsigned short*)(ws + o); o += (size_t)NG * H / 2;
    unsigned short* Z1B  = (unsigned short*)(ws + o); o += (size_t)NG * H / 2;
    unsigned short* CFH  = (unsigned short*)(ws + o); o += (size_t)NC * F / 2;
    unsigned short* HAGG = (unsigned short*)(ws + o); o += (size_t)NC * F / 2;
    unsigned short* TAB  = (unsigned short*)(ws + o); o += (size_t)NLAYERS * NTAB * F / 2;
    // int region
    int* PSRC   = (int*)(ws + o); o += EC;
    int* PGSRC  = (int*)(ws + o); o += EG;
    int* PATTR  = (int*)(ws + o); o += EG;
    int* CNT    = (int*)(ws + o); o += NC + NG;
    int* ROWC   = (int*)(ws + o); o += NC + 64;
    int* CURC   = (int*)(ws + o); o += NC;
    int* ROWG   = (int*)(ws + o); o += NG + 64;
    int* CURG   = (int*)(ws + o); o += NG;
    int* BSUMC  = (int*)(ws + o); o += 256;
    int* BSUMG  = (int*)(ws + o); o += 64;
    // transposed bf16 weights
    unsigned short* WT = (unsigned short*)(ws + o);
    size_t wo = 0;
    unsigned short* lin1t = WT + wo; wo += (size_t)NLAYERS * 128 * 256;
    unsigned short* w1t   = WT + wo; wo += (size_t)NLAYERS * 128 * 64;
    unsigned short* w2t   = WT + wo; wo += (size_t)NLAYERS * 128 * 128;
    unsigned short* lin2t = WT + wo; wo += (size_t)NLAYERS * 256 * 128;
    unsigned short* linwt = WT + wo; wo += (size_t)NLAYERS * 256 * 256;
    unsigned short* g1t   = WT + wo; wo += (size_t)NLAYERS * 256 * 256;
    unsigned short* g2t   = WT + wo; wo += (size_t)NLAYERS * 256 * 256;
    unsigned short* vn1t  = WT + wo; wo += 256 * 256;
    unsigned short* vn2t  = WT + wo; wo += 256 * 256;
    unsigned short* ow1t  = WT + wo; wo += 256 * 256;

    // ---- weight prep: one dispatch + table build ----
    k_wprep<<<6400, 256, 0, stream>>>(
        cf_lin1, cf_mlp_w1, cf_mlp_w2, cf_lin2, lin_w, gin_w1, gin_w2,
        vn_w1, vn_w2, out_w1,
        lin1t, w1t, w2t, lin2t, linwt, g1t, g2t, vn1t, vn2t, ow1t);
    k_tab<<<dim3(NTAB / 128, NLAYERS), 256, 0, stream>>>(
        w1t, cf_mlp_b1, w2t, cf_mlp_b2, TAB);

    // ---- dst-sort both edge lists ----
    hipMemsetAsync(CNT, 0, (NC + NG) * sizeof(int), stream);
    k_hist2<<<(EC + EG) / 256, 256, 0, stream>>>(ei_conf, ei_graph, CNT);
    k_scan1m<<<288, 256, 0, stream>>>(CNT, ROWC, ROWG, BSUMC, BSUMG);
    k_scan2m<<<2, 256, 0, stream>>>(BSUMC, BSUMG);
    k_scan3m<<<288, 256, 0, stream>>>(ROWC, ROWG, BSUMC, BSUMG, CURC, CURG);
    k_perm2<<<(EC + EG) / 256, 256, 0, stream>>>(
        pos, ei_conf, ei_graph, attr_graph, CURC, CURG,
        PSRC, (float2*)PDCC, PGSRC, PATTR);

    k_init_x<<<NCONF, 256, 0, stream>>>(atom_emb, x_atom, vn_emb, XB, SUMX, VN0);

    float* vc = VN0;
    float* vx = VN1;
    for (int i = 0; i < NLAYERS; ++i) {
        if (i < NLAYERS - 1)
            k_vnmlp<<<NCONF / 128, 512, 0, stream>>>(
                SUMX, vc, vn1t, vn_b1, vn2t, vn_b2, vx);
        // ---- CFConv ----
        mgemm<6, 6><<<dim3(1, NC / 128), 256, 0, stream>>>(
            0, XB, lin1t + (size_t)i * 128 * 256, nullptr, 0, CFH,
            256, 256, 128, 0, 0, 0, 0, vc);
        k_cf_agg<<<NC / 16, 256, 0, stream>>>(TAB + (size_t)i * NTAB * F,
            ROWC, PSRC, (const float2*)PDCC, CFH, HAGG);
        // ---- GIN ----
        k_xa2<<<NMOL, 256, 0, stream>>>(XB, vc, XA);
        k_gin_agg<<<NG, 256, 0, stream>>>(
            XA, bond_emb + (size_t)i * 3 * 8 * H, ROWG, PGSRC, PATTR,
            gin_eps + i, AGGB, STATS);
        mgemm<2, 8><<<dim3(2, NG / 128), 256, 0, stream>>>(
            0, AGGB, g1t + (size_t)i * 256 * 256, gin_b1 + i * H, 0, Z1B,
            256, 256, 256, 0, 0, 0, STATS, 0);
        mgemm<5, 7><<<dim3(2, NG / 128), 256, 0, stream>>>(
            0, Z1B, g2t + (size_t)i * 256 * 256, gin_b2 + i * H, Z2, 0,
            256, 256, 256, gin_g1 + i * H, gin_be1 + i * H, STATS, STATS + 512, 0);
        // ---- fused combine (in-kernel Z2 BN prep, +VN residual, SUMX) ----
        if (i < NLAYERS - 1)
            k_combine<true><<<NC / 64, 512, 0, stream>>>(
                HAGG, lin2t + (size_t)i * 256 * 128, cf_lin2_b + i * H,
                linwt + (size_t)i * 256 * 256, lin_b + i * H, Z2,
                STATS + 512, bn_g + i * H, bn_b + i * H, vc, XB, SUMX);
        else
            k_combine<false><<<NC / 64, 512, 0, stream>>>(
                HAGG, lin2t + (size_t)i * 256 * 128, cf_lin2_b + i * H,
                linwt + (size_t)i * 256 * 256, lin_b + i * H, Z2,
                STATS + 512, bn_g + i * H, bn_b + i * H, vc, XB, SUMX);
        float* t = vc; vc = vx; vx = t;
    }

    k_molmax<<<NMOL, 256, 0, stream>>>(XB, XM);
    mgemm<0, 1><<<dim3(2, NMOL / 128), 256, 0, stream>>>(
        XM, 0, ow1t, out_b1, Y1, 0, 256, 256, 256, 0, 0, 0, 0, 0);
    k_head<<<NMOL, 256, 0, stream>>>(Y1, out_w2, out_b2, out);
}

// Round 12
// 906.590 us; speedup vs baseline: 10.0502x; 1.0241x over previous
//
#include <hip/hip_runtime.h>
#include <math.h>

#define H 256
#define F 128
#define NLAYERS 4
#define NG 8192
#define NC 65536
#define EC 524288
#define EG 32768
#define NCONF 4096
#define NMOL 512
#define NGAUSS 50
#define NTAB 8192
#define TABSTEP 0.001953125f   // 16 / 8192
#define INVSTEP 512.0f

using s16x8 = __attribute__((ext_vector_type(8))) short;
using f32x4 = __attribute__((ext_vector_type(4))) float;

static __device__ __forceinline__ unsigned short f2bf(float f) {
    unsigned int u = __float_as_uint(f);
    u += 0x7fffu + ((u >> 16) & 1u);   // RNE (finite values)
    return (unsigned short)(u >> 16);
}
static __device__ __forceinline__ float bf2f(unsigned short b) {
    return __uint_as_float(((unsigned int)b) << 16);
}
static __device__ __forceinline__ float bflo(unsigned int u) {
    return __uint_as_float(u << 16);
}
static __device__ __forceinline__ float bfhi(unsigned int u) {
    return __uint_as_float(u & 0xffff0000u);
}
// conformer id of node row i: r = i>>13, j = i&8191, c = (j>>4)*8 + r
static __device__ __forceinline__ int conf_of(int i) {
    return (((i & (NG - 1)) >> 4) << 3) + (i >> 13);
}

// ---------------- init: X (no vn), SUMX0, VN0 ----------------
__global__ __launch_bounds__(256) void k_init_x(const float* __restrict__ atom_emb,
    const int* __restrict__ x_atom, const float* __restrict__ vn_emb,
    unsigned short* __restrict__ x, float* __restrict__ sumx,
    float* __restrict__ vn0)
{
    int c = blockIdx.x, h = threadIdx.x;
    int m = c >> 3, r = c & 7;
    float sum = 0.f;
    for (int t = 0; t < 16; ++t) {
        int g = m * 16 + t;
        float s = 0.f;
#pragma unroll
        for (int f = 0; f < 9; ++f) {
            int a = x_atom[g * 9 + f];
            s += atom_emb[(f * 64 + a) * H + h];
        }
        x[((size_t)r * NG + g) * H + h] = f2bf(s);
        sum += s;
    }
    sumx[(size_t)c * H + h] = sum;
    vn0[(size_t)c * H + h] = vn_emb[h];
}

// XA[g] = max_r (X[r*NG+g] + VN[conf]) ; block = molecule
__global__ __launch_bounds__(256) void k_xa2(const unsigned short* __restrict__ X,
    const float* __restrict__ vn, unsigned short* __restrict__ xa)
{
    int m = blockIdx.x, h = threadIdx.x;
    float xam[16];
#pragma unroll
    for (int t = 0; t < 16; ++t) xam[t] = -3.4e38f;
#pragma unroll 2
    for (int r = 0; r < 8; ++r) {
        float vv = vn[(size_t)(m * 8 + r) * H + h];
        size_t base = ((size_t)r * NG + m * 16) * H + h;
#pragma unroll
        for (int t = 0; t < 16; ++t)
            xam[t] = fmaxf(xam[t], bf2f(X[base + (size_t)t * H]) + vv);
    }
#pragma unroll
    for (int t = 0; t < 16; ++t)
        xa[(size_t)(m * 16 + t) * H + h] = f2bf(xam[t]);
}

__global__ __launch_bounds__(256) void k_molmax(const unsigned short* __restrict__ x,
                                                float* __restrict__ xm)
{
    int m = blockIdx.x, h = threadIdx.x;
    float best = -3.4e38f;
    for (int r = 0; r < 8; ++r) {
        size_t base = ((size_t)r * NG + m * 16) * H + h;
#pragma unroll 4
        for (int t = 0; t < 16; ++t) best = fmaxf(best, bf2f(x[base + (size_t)t * H]));
    }
    xm[(size_t)m * H + h] = best;
}

__global__ __launch_bounds__(256) void k_head(const float* __restrict__ y1,
    const float* __restrict__ w2, const float* __restrict__ b2,
    float* __restrict__ out)
{
    __shared__ float red[256];
    int m = blockIdx.x, h = threadIdx.x;
    red[h] = y1[(size_t)m * H + h] * w2[h];
    __syncthreads();
    for (int s = 128; s > 0; s >>= 1) {
        if (h < s) red[h] += red[h + s];
        __syncthreads();
    }
    if (h == 0) out[m] = red[0] + b2[0];
}

// ---------------- all weight transposes in ONE dispatch (6400 blocks) ----------------
__global__ __launch_bounds__(256) void k_wprep(
    const float* __restrict__ cf_lin1, const float* __restrict__ cf_mlp_w1,
    const float* __restrict__ cf_mlp_w2, const float* __restrict__ cf_lin2,
    const float* __restrict__ lin_w, const float* __restrict__ gin_w1,
    const float* __restrict__ gin_w2, const float* __restrict__ vn_w1,
    const float* __restrict__ vn_w2, const float* __restrict__ out_w1,
    unsigned short* __restrict__ lin1t, unsigned short* __restrict__ w1t,
    unsigned short* __restrict__ w2t, unsigned short* __restrict__ lin2t,
    unsigned short* __restrict__ linwt, unsigned short* __restrict__ g1t,
    unsigned short* __restrict__ g2t, unsigned short* __restrict__ vn1t,
    unsigned short* __restrict__ vn2t, unsigned short* __restrict__ ow1t)
{
    int b = blockIdx.x;
    const float* W; unsigned short* Wt; int K, N, Kp, l, n;
    if (b < 512)      { b -= 0;    l = b >> 7; n = b & 127; W = cf_lin1;   Wt = lin1t; K = 256; N = 128; Kp = 256; }
    else if (b < 1024){ b -= 512;  l = b >> 7; n = b & 127; W = cf_mlp_w1; Wt = w1t;   K = 50;  N = 128; Kp = 64;  }
    else if (b < 1536){ b -= 1024; l = b >> 7; n = b & 127; W = cf_mlp_w2; Wt = w2t;   K = 128; N = 128; Kp = 128; }
    else if (b < 2560){ b -= 1536; l = b >> 8; n = b & 255; W = cf_lin2;   Wt = lin2t; K = 128; N = 256; Kp = 128; }
    else if (b < 3584){ b -= 2560; l = b >> 8; n = b & 255; W = lin_w;     Wt = linwt; K = 256; N = 256; Kp = 256; }
    else if (b < 4608){ b -= 3584; l = b >> 8; n = b & 255; W = gin_w1;    Wt = g1t;   K = 256; N = 256; Kp = 256; }
    else if (b < 5632){ b -= 4608; l = b >> 8; n = b & 255; W = gin_w2;    Wt = g2t;   K = 256; N = 256; Kp = 256; }
    else if (b < 5888){ l = 0; n = b - 5632; W = vn_w1;  Wt = vn1t; K = 256; N = 256; Kp = 256; }
    else if (b < 6144){ l = 0; n = b - 5888; W = vn_w2;  Wt = vn2t; K = 256; N = 256; Kp = 256; }
    else              { l = 0; n = b - 6144; W = out_w1; Wt = ow1t; K = 256; N = 256; Kp = 256; }
    W  += (size_t)l * K * N;
    Wt += (size_t)l * N * Kp;
    for (int k = threadIdx.x; k < Kp; k += 256)
        Wt[(size_t)n * Kp + k] = (k < K) ? f2bf(W[(size_t)k * N + n]) : (unsigned short)0;
}

// ---------------- combined counting sort (both edge lists) ----------------

__global__ __launch_bounds__(256) void k_hist2(const int* __restrict__ ei_conf,
    const int* __restrict__ ei_graph, int* __restrict__ cnt)
{
    int idx = blockIdx.x * 256 + threadIdx.x;
    if (idx < EC) atomicAdd(&cnt[ei_conf[EC + idx]], 1);
    else {
        int j = idx - EC;
        if (j < EG) atomicAdd(&cnt[NC + ei_graph[EG + j]], 1);
    }
}

__global__ __launch_bounds__(256) void k_scan1m(const int* __restrict__ cnt,
    int* __restrict__ rowc, int* __restrict__ rowg,
    int* __restrict__ bsumc, int* __restrict__ bsumg)
{
    __shared__ int sh[256];
    int t = threadIdx.x, b = blockIdx.x;
    const int* src; int* part; int* bsum; int bb;
    if (b < 256) { src = cnt; part = rowc; bsum = bsumc; bb = b; }
    else         { src = cnt + NC; part = rowg; bsum = bsumg; bb = b - 256; }
    int idx = bb * 256 + t;
    int v = src[idx];
    sh[t] = v; __syncthreads();
    for (int s = 1; s < 256; s <<= 1) {
        int add = (t >= s) ? sh[t - s] : 0;
        __syncthreads();
        sh[t] += add;
        __syncthreads();
    }
    part[idx] = sh[t] - v;
    if (t == 255) bsum[bb] = sh[255];
}

__global__ __launch_bounds__(256) void k_scan2m(int* __restrict__ bsumc,
                                                int* __restrict__ bsumg)
{
    __shared__ int sh[256];
    int t = threadIdx.x;
    int* bs = (blockIdx.x == 0) ? bsumc : bsumg;
    int nb = (blockIdx.x == 0) ? 256 : 32;
    int v = (t < nb) ? bs[t] : 0;
    sh[t] = v; __syncthreads();
    for (int s = 1; s < 256; s <<= 1) {
        int add = (t >= s) ? sh[t - s] : 0;
        __syncthreads();
        sh[t] += add;
        __syncthreads();
    }
    if (t < nb) bs[t] = sh[t] - v;
}

__global__ __launch_bounds__(256) void k_scan3m(int* __restrict__ rowc,
    int* __restrict__ rowg, const int* __restrict__ bsumc,
    const int* __restrict__ bsumg, int* __restrict__ curc, int* __restrict__ curg)
{
    int t = threadIdx.x, b = blockIdx.x;
    if (b < 256) {
        int idx = b * 256 + t;
        int v = rowc[idx] + bsumc[b];
        rowc[idx] = v; curc[idx] = v;
        if (idx == 0) rowc[NC] = EC;
    } else {
        int bb = b - 256;
        int idx = bb * 256 + t;
        int v = rowg[idx] + bsumg[bb];
        rowg[idx] = v; curg[idx] = v;
        if (idx == 0) rowg[NG] = EG;
    }
}

__global__ __launch_bounds__(256) void k_perm2(const float* __restrict__ pos,
    const int* __restrict__ ei_conf, const int* __restrict__ ei_graph,
    const int* __restrict__ attr, int* __restrict__ curc, int* __restrict__ curg,
    int* __restrict__ psrc, float2* __restrict__ pdcc,
    int* __restrict__ pgsrc, int* __restrict__ pattr)
{
    int idx = blockIdx.x * 256 + threadIdx.x;
    if (idx < EC) {
        int s = ei_conf[idx], t = ei_conf[EC + idx];
        float dx = pos[s * 3 + 0] - pos[t * 3 + 0];
        float dy = pos[s * 3 + 1] - pos[t * 3 + 1];
        float dz = pos[s * 3 + 2] - pos[t * 3 + 2];
        float dd = sqrtf(dx * dx + dy * dy + dz * dz);
        int p = atomicAdd(&curc[t], 1);
        psrc[p] = s;
        pdcc[p] = make_float2(dd, 0.5f * (cosf(dd * 0.314159265358979f) + 1.0f));
    } else {
        int j = idx - EC;
        if (j < EG) {
            int s = ei_graph[j], t = ei_graph[EG + j];
            int p = atomicAdd(&curg[t], 1);
            pgsrc[p] = s;
            pattr[p] = attr[j * 3] | (attr[j * 3 + 1] << 4) | (attr[j * 3 + 2] << 8);
        }
    }
}

// ---------------- gather-based aggregations (no atomics) ----------------

// 8 channels/thread, 16 lanes/node, 16 nodes/block; NN table; 2-edge unroll.
__global__ __launch_bounds__(256) void k_cf_agg(const unsigned short* __restrict__ tab,
    const int* __restrict__ rowptr, const int* __restrict__ psrc,
    const float2* __restrict__ pdcc,
    const unsigned short* __restrict__ cfh, unsigned short* __restrict__ hagg)
{
    int slot = threadIdx.x >> 4;
    int c8 = (threadIdx.x & 15) << 3;
    int n = blockIdx.x * 16 + slot;
    int lo = rowptr[n], hi = rowptr[n + 1];
    float a[8] = {0.f, 0.f, 0.f, 0.f, 0.f, 0.f, 0.f, 0.f};
    int e = lo;
    for (; e + 2 <= hi; e += 2) {
        int s0 = psrc[e], s1 = psrc[e + 1];
        float2 d0 = pdcc[e], d1 = pdcc[e + 1];
        int it0 = (int)(d0.x * INVSTEP + 0.5f);
        int it1 = (int)(d1.x * INVSTEP + 0.5f);
        if (it0 > NTAB - 1) it0 = NTAB - 1;
        if (it1 > NTAB - 1) it1 = NTAB - 1;
        uint4 Ta = *(const uint4*)&tab[(size_t)it0 * F + c8];
        uint4 Ha = *(const uint4*)&cfh[(size_t)s0 * F + c8];
        uint4 Tb = *(const uint4*)&tab[(size_t)it1 * F + c8];
        uint4 Hb = *(const uint4*)&cfh[(size_t)s1 * F + c8];
        float c0 = d0.y, c1 = d1.y;
        a[0] = fmaf(bflo(Ta.x) * c0, bflo(Ha.x), a[0]);
        a[1] = fmaf(bfhi(Ta.x) * c0, bfhi(Ha.x), a[1]);
        a[2] = fmaf(bflo(Ta.y) * c0, bflo(Ha.y), a[2]);
        a[3] = fmaf(bfhi(Ta.y) * c0, bfhi(Ha.y), a[3]);
        a[4] = fmaf(bflo(Ta.z) * c0, bflo(Ha.z), a[4]);
        a[5] = fmaf(bfhi(Ta.z) * c0, bfhi(Ha.z), a[5]);
        a[6] = fmaf(bflo(Ta.w) * c0, bflo(Ha.w), a[6]);
        a[7] = fmaf(bfhi(Ta.w) * c0, bfhi(Ha.w), a[7]);
        a[0] = fmaf(bflo(Tb.x) * c1, bflo(Hb.x), a[0]);
        a[1] = fmaf(bfhi(Tb.x) * c1, bfhi(Hb.x), a[1]);
        a[2] = fmaf(bflo(Tb.y) * c1, bflo(Hb.y), a[2]);
        a[3] = fmaf(bfhi(Tb.y) * c1, bfhi(Hb.y), a[3]);
        a[4] = fmaf(bflo(Tb.z) * c1, bflo(Hb.z), a[4]);
        a[5] = fmaf(bfhi(Tb.z) * c1, bfhi(Hb.z), a[5]);
        a[6] = fmaf(bflo(Tb.w) * c1, bflo(Hb.w), a[6]);
        a[7] = fmaf(bfhi(Tb.w) * c1, bfhi(Hb.w), a[7]);
    }
    if (e < hi) {
        int s0 = psrc[e];
        float2 d0 = pdcc[e];
        int it0 = (int)(d0.x * INVSTEP + 0.5f);
        if (it0 > NTAB - 1) it0 = NTAB - 1;
        uint4 Ta = *(const uint4*)&tab[(size_t)it0 * F + c8];
        uint4 Ha = *(const uint4*)&cfh[(size_t)s0 * F + c8];
        float c0 = d0.y;
        a[0] = fmaf(bflo(Ta.x) * c0, bflo(Ha.x), a[0]);
        a[1] = fmaf(bfhi(Ta.x) * c0, bfhi(Ha.x), a[1]);
        a[2] = fmaf(bflo(Ta.y) * c0, bflo(Ha.y), a[2]);
        a[3] = fmaf(bfhi(Ta.y) * c0, bfhi(Ha.y), a[3]);
        a[4] = fmaf(bflo(Ta.z) * c0, bflo(Ha.z), a[4]);
        a[5] = fmaf(bfhi(Ta.z) * c0, bfhi(Ha.z), a[5]);
        a[6] = fmaf(bflo(Ta.w) * c0, bflo(Ha.w), a[6]);
        a[7] = fmaf(bfhi(Ta.w) * c0, bfhi(Ha.w), a[7]);
    }
    uint4 o;
    o.x = ((unsigned)f2bf(a[1]) << 16) | f2bf(a[0]);
    o.y = ((unsigned)f2bf(a[3]) << 16) | f2bf(a[2]);
    o.z = ((unsigned)f2bf(a[5]) << 16) | f2bf(a[4]);
    o.w = ((unsigned)f2bf(a[7]) << 16) | f2bf(a[6]);
    *(uint4*)&hagg[(size_t)n * F + c8] = o;
}

// AGG[g] = bf16((1+eps)*xa[g] + sum_e relu(xa[pgsrc[e]] + bond_sum)); block 0 zeroes stats
__global__ __launch_bounds__(256) void k_gin_agg(const unsigned short* __restrict__ xa,
    const float* __restrict__ bond, const int* __restrict__ growptr,
    const int* __restrict__ pgsrc, const int* __restrict__ pattr,
    const float* __restrict__ eps_p, unsigned short* __restrict__ agg,
    float* __restrict__ stats)
{
    int g = blockIdx.x, h = threadIdx.x;
    if (g == 0) {
#pragma unroll
        for (int q = 0; q < 4; ++q) stats[q * 256 + h] = 0.f;
    }
    int lo = growptr[g], hi = growptr[g + 1];
    float acc = 0.f;
    for (int e = lo; e < hi; ++e) {
        int s = pgsrc[e], a = pattr[e];
        float v = bf2f(xa[(size_t)s * H + h])
                + bond[(a & 15) * H + h]
                + bond[(8 + ((a >> 4) & 15)) * H + h]
                + bond[(16 + (a >> 8)) * H + h];
        acc += fmaxf(v, 0.f);
    }
    agg[(size_t)g * H + h] =
        f2bf((1.0f + eps_p[0]) * bf2f(xa[(size_t)g * H + h]) + acc);
}

// ---------------- MFMA GEMM ----------------
// tile 128x128, BK=64, 4 waves.
// ASRC: 0 = f32 A, 2 = bf16 A, 5 = bf16 A + in-kernel BN(scale/shift from stats_in)+relu,
//       6 = bf16 A + VN[conf(row)] add (f32)
// EPI:  1 = relu->Cf, 6 = ->bf16 Cb, 7 = ->Cf + column stats, 8 = ->bf16 Cb + column stats
template<int ASRC, int EPI>
__global__ __launch_bounds__(256) void mgemm(
    const float* __restrict__ Af, const unsigned short* __restrict__ Ab,
    const unsigned short* __restrict__ Bt,
    const float* __restrict__ bias,
    float* __restrict__ Cf, unsigned short* __restrict__ Cb,
    int K, int Kp, int ldc,
    const float* __restrict__ gam, const float* __restrict__ bet,
    const float* __restrict__ stats_in, float* __restrict__ stats_out,
    const float* __restrict__ vnp)
{
    __shared__ unsigned short As[128][72];
    __shared__ unsigned short Bs[128][72];
    __shared__ float scs[256], shs[256];
    const int tid = threadIdx.x;
    const int bm = blockIdx.y * 128;
    const int bn = blockIdx.x * 128;
    const int lane = tid & 63;
    const int wid = tid >> 6;
    const int wm = wid >> 1, wn = wid & 1;
    const int rsel = lane & 15, ksel = (lane >> 4) * 8;

    if constexpr (ASRC == 5) {
        float mean = stats_in[tid] * (1.0f / NG);
        float var = stats_in[256 + tid] * (1.0f / NG) - mean * mean;
        float sc = gam[tid] * rsqrtf(var + 1e-5f);
        scs[tid] = sc;
        shs[tid] = bet[tid] - mean * sc;
        __syncthreads();
    }

    f32x4 acc[4][4];
#pragma unroll
    for (int a = 0; a < 4; ++a)
#pragma unroll
        for (int b = 0; b < 4; ++b) acc[a][b] = (f32x4){0.f, 0.f, 0.f, 0.f};

    for (int k0 = 0; k0 < Kp; k0 += 64) {
#pragma unroll
        for (int i = 0; i < 4; ++i) {
            int c = tid + i * 256;
            int row = c >> 3, kc = (c & 7) * 8;
            *(uint4*)&Bs[row][kc] =
                *(const uint4*)&Bt[(size_t)(bn + row) * Kp + k0 + kc];
        }
        if constexpr (ASRC == 0) {
#pragma unroll
            for (int i = 0; i < 8; ++i) {
                int c = tid + i * 256;
                int row = c >> 4, kc = (c & 15) * 4;
                float4 v = *(const float4*)&Af[(size_t)(bm + row) * K + k0 + kc];
                ushort4 b;
                b.x = f2bf(v.x); b.y = f2bf(v.y); b.z = f2bf(v.z); b.w = f2bf(v.w);
                *(ushort4*)&As[row][kc] = b;
            }
        } else if constexpr (ASRC == 5) {
#pragma unroll
            for (int i = 0; i < 4; ++i) {
                int c = tid + i * 256;
                int row = c >> 3, kc = (c & 7) * 8;
                uint4 xv = *(const uint4*)&Ab[(size_t)(bm + row) * K + k0 + kc];
                const float* sp = &scs[k0 + kc];
                const float* hp = &shs[k0 + kc];
                float4 s0 = *(const float4*)sp, s1 = *(const float4*)(sp + 4);
                float4 h0 = *(const float4*)hp, h1 = *(const float4*)(hp + 4);
                uint4 o;
                o.x = ((unsigned)f2bf(fmaxf(fmaf(bfhi(xv.x), s0.y, h0.y), 0.f)) << 16)
                    | f2bf(fmaxf(fmaf(bflo(xv.x), s0.x, h0.x), 0.f));
                o.y = ((unsigned)f2bf(fmaxf(fmaf(bfhi(xv.y), s0.w, h0.w), 0.f)) << 16)
                    | f2bf(fmaxf(fmaf(bflo(xv.y), s0.z, h0.z), 0.f));
                o.z = ((unsigned)f2bf(fmaxf(fmaf(bfhi(xv.z), s1.y, h1.y), 0.f)) << 16)
                    | f2bf(fmaxf(fmaf(bflo(xv.z), s1.x, h1.x), 0.f));
                o.w = ((unsigned)f2bf(fmaxf(fmaf(bfhi(xv.w), s1.w, h1.w), 0.f)) << 16)
                    | f2bf(fmaxf(fmaf(bflo(xv.w), s1.z, h1.z), 0.f));
                *(uint4*)&As[row][kc] = o;
            }
        } else if constexpr (ASRC == 6) {
#pragma unroll
            for (int i = 0; i < 4; ++i) {
                int c = tid + i * 256;
                int row = c >> 3, kc = (c & 7) * 8;
                int gm = bm + row;
                int cf = conf_of(gm);
                uint4 xv = *(const uint4*)&Ab[(size_t)gm * K + k0 + kc];
                const float* vr = &vnp[(size_t)cf * 256 + k0 + kc];
                float4 v0 = *(const float4*)vr;
                float4 v1 = *(const float4*)(vr + 4);
                uint4 o;
                o.x = ((unsigned)f2bf(bfhi(xv.x) + v0.y) << 16) | f2bf(bflo(xv.x) + v0.x);
                o.y = ((unsigned)f2bf(bfhi(xv.y) + v0.w) << 16) | f2bf(bflo(xv.y) + v0.z);
                o.z = ((unsigned)f2bf(bfhi(xv.z) + v1.y) << 16) | f2bf(bflo(xv.z) + v1.x);
                o.w = ((unsigned)f2bf(bfhi(xv.w) + v1.w) << 16) | f2bf(bflo(xv.w) + v1.z);
                *(uint4*)&As[row][kc] = o;
            }
        } else {
#pragma unroll
            for (int i = 0; i < 4; ++i) {
                int c = tid + i * 256;
                int row = c >> 3, kc = (c & 7) * 8;
                *(uint4*)&As[row][kc] =
                    *(const uint4*)&Ab[(size_t)(bm + row) * K + k0 + kc];
            }
        }
        __syncthreads();
#pragma unroll
        for (int kk = 0; kk < 64; kk += 32) {
            s16x8 af[4], bf[4];
#pragma unroll
            for (int mi = 0; mi < 4; ++mi)
                af[mi] = *(const s16x8*)&As[wm * 64 + mi * 16 + rsel][kk + ksel];
#pragma unroll
            for (int ni = 0; ni < 4; ++ni)
                bf[ni] = *(const s16x8*)&Bs[wn * 64 + ni * 16 + rsel][kk + ksel];
#pragma unroll
            for (int mi = 0; mi < 4; ++mi)
#pragma unroll
                for (int ni = 0; ni < 4; ++ni)
                    acc[mi][ni] = __builtin_amdgcn_mfma_f32_16x16x32_bf16(
                        af[mi], bf[ni], acc[mi][ni], 0, 0, 0);
        }
        __syncthreads();
    }

    float colS[4] = {0.f, 0.f, 0.f, 0.f};
    float colQ[4] = {0.f, 0.f, 0.f, 0.f};
#pragma unroll
    for (int mi = 0; mi < 4; ++mi) {
#pragma unroll
        for (int r = 0; r < 4; ++r) {
            int m = bm + wm * 64 + mi * 16 + ((lane >> 4) << 2) + r;
#pragma unroll
            for (int ni = 0; ni < 4; ++ni) {
                int n = bn + wn * 64 + ni * 16 + (lane & 15);
                float v = acc[mi][ni][r];
                if (bias) v += bias[n];
                if constexpr (EPI == 1) {
                    Cf[(size_t)m * ldc + n] = fmaxf(v, 0.f);
                } else if constexpr (EPI == 6) {
                    Cb[(size_t)m * ldc + n] = f2bf(v);
                } else if constexpr (EPI == 7) {
                    Cf[(size_t)m * ldc + n] = v;
                    colS[ni] += v;
                    colQ[ni] = fmaf(v, v, colQ[ni]);
                } else {  // EPI == 8
                    Cb[(size_t)m * ldc + n] = f2bf(v);
                    colS[ni] += v;
                    colQ[ni] = fmaf(v, v, colQ[ni]);
                }
            }
        }
    }
    if constexpr (EPI == 7 || EPI == 8) {
        float* cs = (float*)&As[0][0];
        cs[tid] = 0.f;
        __syncthreads();
#pragma unroll
        for (int ni = 0; ni < 4; ++ni) {
            int nl = wn * 64 + ni * 16 + (lane & 15);
            atomicAdd(&cs[nl], colS[ni]);
            atomicAdd(&cs[128 + nl], colQ[ni]);
        }
        __syncthreads();
        if (tid < 128) {
            atomicAdd(&stats_out[bn + tid], cs[tid]);
            atomicAdd(&stats_out[256 + bn + tid], cs[128 + tid]);
        }
    }
}

// ---------------- fused table build: TAB[l][i] = mlp_l(gauss(i*step)) ----------------
__global__ __launch_bounds__(256) void k_tab(
    const unsigned short* __restrict__ w1t, const float* __restrict__ b1,
    const unsigned short* __restrict__ w2t, const float* __restrict__ b2,
    unsigned short* __restrict__ tab)
{
    __shared__ unsigned short As[128][72];
    __shared__ unsigned short Bs[128][72];
    __shared__ unsigned short T1s[128][152];
    const int l = blockIdx.y;
    w1t += (size_t)l * 128 * 64;  b1 += l * 128;
    w2t += (size_t)l * 128 * 128; b2 += l * 128;
    tab += (size_t)l * NTAB * F;
    const int tid = threadIdx.x;
    const int bm = blockIdx.x * 128;
    const int lane = tid & 63, wid = tid >> 6;
    const int wm = wid >> 1, wn = wid & 1;
    const int rsel = lane & 15, ksel = (lane >> 4) * 8;

    f32x4 acc[4][4];
#pragma unroll
    for (int a = 0; a < 4; ++a)
#pragma unroll
        for (int b = 0; b < 4; ++b) acc[a][b] = (f32x4){0.f, 0.f, 0.f, 0.f};

#pragma unroll
    for (int i = 0; i < 8; ++i) {
        int c = tid + i * 256;
        int row = c >> 4, kc = (c & 15) * 4;
        float dv = (float)(bm + row) * TABSTEP;
        ushort4 b;
        unsigned short* bp = (unsigned short*)&b;
#pragma unroll
        for (int j = 0; j < 4; ++j) {
            int k = kc + j;
            float f = 0.f;
            if (k < NGAUSS) {
                float t = dv - (float)k * (10.0f / 49.0f);
                f = __expf(-12.005f * t * t);
            }
            bp[j] = f2bf(f);
        }
        *(ushort4*)&As[row][kc] = b;
    }
#pragma unroll
    for (int i = 0; i < 4; ++i) {
        int c = tid + i * 256;
        int row = c >> 3, kc = (c & 7) * 8;
        *(uint4*)&Bs[row][kc] = *(const uint4*)&w1t[(size_t)row * 64 + kc];
    }
    __syncthreads();
#pragma unroll
    for (int kk = 0; kk < 64; kk += 32) {
        s16x8 af[4], bf[4];
#pragma unroll
        for (int mi = 0; mi < 4; ++mi)
            af[mi] = *(const s16x8*)&As[wm * 64 + mi * 16 + rsel][kk + ksel];
#pragma unroll
        for (int ni = 0; ni < 4; ++ni)
            bf[ni] = *(const s16x8*)&Bs[wn * 64 + ni * 16 + rsel][kk + ksel];
#pragma unroll
        for (int mi = 0; mi < 4; ++mi)
#pragma unroll
            for (int ni = 0; ni < 4; ++ni)
                acc[mi][ni] = __builtin_amdgcn_mfma_f32_16x16x32_bf16(
                    af[mi], bf[ni], acc[mi][ni], 0, 0, 0);
    }
    __syncthreads();
#pragma unroll
    for (int mi = 0; mi < 4; ++mi)
#pragma unroll
        for (int r = 0; r < 4; ++r) {
            int mrow = wm * 64 + mi * 16 + ((lane >> 4) << 2) + r;
#pragma unroll
            for (int ni = 0; ni < 4; ++ni) {
                int n = wn * 64 + ni * 16 + (lane & 15);
                T1s[mrow][n] = f2bf(fmaxf(acc[mi][ni][r] + b1[n], 0.f));
            }
        }
#pragma unroll
    for (int a = 0; a < 4; ++a)
#pragma unroll
        for (int b = 0; b < 4; ++b) acc[a][b] = (f32x4){0.f, 0.f, 0.f, 0.f};
    for (int k0 = 0; k0 < 128; k0 += 64) {
#pragma unroll
        for (int i = 0; i < 4; ++i) {
            int c = tid + i * 256;
            int row = c >> 3, kc = (c & 7) * 8;
            *(uint4*)&Bs[row][kc] = *(const uint4*)&w2t[(size_t)row * 128 + k0 + kc];
        }
        __syncthreads();
#pragma unroll
        for (int kk = 0; kk < 64; kk += 32) {
            s16x8 af[4], bf[4];
#pragma unroll
            for (int mi = 0; mi < 4; ++mi)
                af[mi] = *(const s16x8*)&T1s[wm * 64 + mi * 16 + rsel][k0 + kk + ksel];
#pragma unroll
            for (int ni = 0; ni < 4; ++ni)
                bf[ni] = *(const s16x8*)&Bs[wn * 64 + ni * 16 + rsel][kk + ksel];
#pragma unroll
            for (int mi = 0; mi < 4; ++mi)
#pragma unroll
                for (int ni = 0; ni < 4; ++ni)
                    acc[mi][ni] = __builtin_amdgcn_mfma_f32_16x16x32_bf16(
                        af[mi], bf[ni], acc[mi][ni], 0, 0, 0);
        }
        __syncthreads();
    }
#pragma unroll
    for (int mi = 0; mi < 4; ++mi)
#pragma unroll
        for (int r = 0; r < 4; ++r) {
            int m = bm + wm * 64 + mi * 16 + ((lane >> 4) << 2) + r;
#pragma unroll
            for (int ni = 0; ni < 4; ++ni) {
                int n = wn * 64 + ni * 16 + (lane & 15);
                tab[(size_t)m * F + n] = f2bf(acc[mi][ni][r] + b2[n]);
            }
        }
}

// ---------------- fused vn MLP: VNout = relu(relu((SUMX+17*VNin)@w1+b1)@w2+b2) ----------------
__global__ __launch_bounds__(512) void k_vnmlp(
    const float* __restrict__ SUMX, const float* __restrict__ VNin,
    const unsigned short* __restrict__ w1, const float* __restrict__ b1,
    const unsigned short* __restrict__ w2, const float* __restrict__ b2,
    float* __restrict__ VNout)
{
    __shared__ unsigned short As[128][72];
    __shared__ unsigned short Bs[256][72];
    __shared__ unsigned short Ts[128][264];
    const int tid = threadIdx.x;
    const int bm = blockIdx.x * 128;
    const int lane = tid & 63, wid = tid >> 6;
    const int wm = wid >> 2, wn = wid & 3;
    const int rsel = lane & 15, ksel = (lane >> 4) * 8;

    f32x4 acc[4][4];
#pragma unroll
    for (int a = 0; a < 4; ++a)
#pragma unroll
        for (int b = 0; b < 4; ++b) acc[a][b] = (f32x4){0.f, 0.f, 0.f, 0.f};
    for (int k0 = 0; k0 < 256; k0 += 64) {
#pragma unroll
        for (int i = 0; i < 4; ++i) {
            int c = tid + i * 512;
            int row = c >> 4, kc = (c & 15) * 4;
            size_t off = (size_t)(bm + row) * 256 + k0 + kc;
            float4 sx = *(const float4*)&SUMX[off];
            float4 vv = *(const float4*)&VNin[off];
            ushort4 b;
            b.x = f2bf(fmaf(17.f, vv.x, sx.x));
            b.y = f2bf(fmaf(17.f, vv.y, sx.y));
            b.z = f2bf(fmaf(17.f, vv.z, sx.z));
            b.w = f2bf(fmaf(17.f, vv.w, sx.w));
            *(ushort4*)&As[row][kc] = b;
        }
#pragma unroll
        for (int i = 0; i < 4; ++i) {
            int c = tid + i * 512;
            int row = c >> 3, kc = (c & 7) * 8;
            *(uint4*)&Bs[row][kc] = *(const uint4*)&w1[(size_t)row * 256 + k0 + kc];
        }
        __syncthreads();
#pragma unroll
        for (int kk = 0; kk < 64; kk += 32) {
            s16x8 af[4], bf[4];
#pragma unroll
            for (int mi = 0; mi < 4; ++mi)
                af[mi] = *(const s16x8*)&As[wm * 64 + mi * 16 + rsel][kk + ksel];
#pragma unroll
            for (int ni = 0; ni < 4; ++ni)
                bf[ni] = *(const s16x8*)&Bs[wn * 64 + ni * 16 + rsel][kk + ksel];
#pragma unroll
            for (int mi = 0; mi < 4; ++mi)
#pragma unroll
                for (int ni = 0; ni < 4; ++ni)
                    acc[mi][ni] = __builtin_amdgcn_mfma_f32_16x16x32_bf16(
                        af[mi], bf[ni], acc[mi][ni], 0, 0, 0);
        }
        __syncthreads();
    }
#pragma unroll
    for (int mi = 0; mi < 4; ++mi)
#pragma unroll
        for (int r = 0; r < 4; ++r) {
            int mrow = wm * 64 + mi * 16 + ((lane >> 4) << 2) + r;
#pragma unroll
            for (int ni = 0; ni < 4; ++ni) {
                int n = wn * 64 + ni * 16 + (lane & 15);
                Ts[mrow][n] = f2bf(fmaxf(acc[mi][ni][r] + b1[n], 0.f));
            }
        }
#pragma unroll
    for (int a = 0; a < 4; ++a)
#pragma unroll
        for (int b = 0; b < 4; ++b) acc[a][b] = (f32x4){0.f, 0.f, 0.f, 0.f};
    for (int k0 = 0; k0 < 256; k0 += 64) {
#pragma unroll
        for (int i = 0; i < 4; ++i) {
            int c = tid + i * 512;
            int row = c >> 3, kc = (c & 7) * 8;
            *(uint4*)&Bs[row][kc] = *(const uint4*)&w2[(size_t)row * 256 + k0 + kc];
        }
        __syncthreads();
#pragma unroll
        for (int kk = 0; kk < 64; kk += 32) {
            s16x8 af[4], bf[4];
#pragma unroll
            for (int mi = 0; mi < 4; ++mi)
                af[mi] = *(const s16x8*)&Ts[wm * 64 + mi * 16 + rsel][k0 + kk + ksel];
#pragma unroll
            for (int ni = 0; ni < 4; ++ni)
                bf[ni] = *(const s16x8*)&Bs[wn * 64 + ni * 16 + rsel][kk + ksel];
#pragma unroll
            for (int mi = 0; mi < 4; ++mi)
#pragma unroll
                for (int ni = 0; ni < 4; ++ni)
                    acc[mi][ni] = __builtin_amdgcn_mfma_f32_16x16x32_bf16(
                        af[mi], bf[ni], acc[mi][ni], 0, 0, 0);
        }
        __syncthreads();
    }
#pragma unroll
    for (int mi = 0; mi < 4; ++mi)
#pragma unroll
        for (int r = 0; r < 4; ++r) {
            int m = bm + wm * 64 + mi * 16 + ((lane >> 4) << 2) + r;
#pragma unroll
            for (int ni = 0; ni < 4; ++ni) {
                int n = wn * 64 + ni * 16 + (lane & 15);
                VNout[(size_t)m * 256 + n] = fmaxf(acc[mi][ni][r] + b2[n], 0.f);
            }
        }
}

// ---- fused combine v3 (128-row tile, 2m x 4n waves — proven shape; in-kernel Z2-BN):
//   X = relu(X + VN + relu(HAGG@lin2+b2)@linw + b + bn(Z2)); optional SUMX.
template <bool DOSUM>
__global__ __launch_bounds__(512) void k_combine(
    const unsigned short* __restrict__ HAGG,
    const unsigned short* __restrict__ lin2t, const float* __restrict__ lin2b,
    const unsigned short* __restrict__ linwt, const float* __restrict__ linb,
    const float* __restrict__ Z2,
    const float* __restrict__ stats2, const float* __restrict__ gam2,
    const float* __restrict__ bet2,
    const float* __restrict__ vn, unsigned short* __restrict__ X,
    float* __restrict__ SUMX)
{
    __shared__ unsigned short As[128][72];
    __shared__ unsigned short Bs[256][72];
    __shared__ unsigned short H2s[128][264];
    __shared__ float scb[256], shb[256];
    const int tid = threadIdx.x;
    const int bm = blockIdx.x * 128;
    const int lane = tid & 63;
    const int wid = tid >> 6;
    const int wm = wid >> 2, wn = wid & 3;
    const int rsel = lane & 15, ksel = (lane >> 4) * 8;

    if (tid < 256) {                            // Z2 BN prep
        float mean = stats2[tid] * (1.0f / NG);
        float var = stats2[256 + tid] * (1.0f / NG) - mean * mean;
        float sc = gam2[tid] * rsqrtf(var + 1e-5f);
        scb[tid] = sc;
        shb[tid] = bet2[tid] - mean * sc;
    }

    f32x4 acc[4][4];
#pragma unroll
    for (int a = 0; a < 4; ++a)
#pragma unroll
        for (int b = 0; b < 4; ++b) acc[a][b] = (f32x4){0.f, 0.f, 0.f, 0.f};

    // ---- stage 1: H2 = relu(HAGG[128x128] @ lin2 + b2) ----
    for (int k0 = 0; k0 < 128; k0 += 64) {
#pragma unroll
        for (int i = 0; i < 2; ++i) {
            int c = tid + i * 512;
            int row = c >> 3, kc = (c & 7) * 8;
            *(uint4*)&As[row][kc] =
                *(const uint4*)&HAGG[(size_t)(bm + row) * 128 + k0 + kc];
        }
#pragma unroll
        for (int i = 0; i < 4; ++i) {
            int c = tid + i * 512;
            int row = c >> 3, kc = (c & 7) * 8;
            *(uint4*)&Bs[row][kc] = *(const uint4*)&lin2t[(size_t)row * 128 + k0 + kc];
        }
        __syncthreads();
#pragma unroll
        for (int kk = 0; kk < 64; kk += 32) {
            s16x8 af[4], bf[4];
#pragma unroll
            for (int mi = 0; mi < 4; ++mi)
                af[mi] = *(const s16x8*)&As[wm * 64 + mi * 16 + rsel][kk + ksel];
#pragma unroll
            for (int ni = 0; ni < 4; ++ni)
                bf[ni] = *(const s16x8*)&Bs[wn * 64 + ni * 16 + rsel][kk + ksel];
#pragma unroll
            for (int mi = 0; mi < 4; ++mi)
#pragma unroll
                for (int ni = 0; ni < 4; ++ni)
                    acc[mi][ni] = __builtin_amdgcn_mfma_f32_16x16x32_bf16(
                        af[mi], bf[ni], acc[mi][ni], 0, 0, 0);
        }
        __syncthreads();
    }
#pragma unroll
    for (int mi = 0; mi < 4; ++mi)
#pragma unroll
        for (int r = 0; r < 4; ++r) {
            int mrow = wm * 64 + mi * 16 + ((lane >> 4) << 2) + r;
#pragma unroll
            for (int ni = 0; ni < 4; ++ni) {
                int n = wn * 64 + ni * 16 + (lane & 15);
                H2s[mrow][n] = f2bf(fmaxf(acc[mi][ni][r] + lin2b[n], 0.f));
            }
        }

    // ---- stage 2: acc = H2 @ linw ----
#pragma unroll
    for (int a = 0; a < 4; ++a)
#pragma unroll
        for (int b = 0; b < 4; ++b) acc[a][b] = (f32x4){0.f, 0.f, 0.f, 0.f};
    for (int k0 = 0; k0 < 256; k0 += 64) {
#pragma unroll
        for (int i = 0; i < 4; ++i) {
            int c = tid + i * 512;
            int row = c >> 3, kc = (c & 7) * 8;
            *(uint4*)&Bs[row][kc] = *(const uint4*)&linwt[(size_t)row * 256 + k0 + kc];
        }
        __syncthreads();   // first iter also covers H2s epilogue writes + scb/shb
#pragma unroll
        for (int kk = 0; kk < 64; kk += 32) {
            s16x8 af[4], bf[4];
#pragma unroll
            for (int mi = 0; mi < 4; ++mi)
                af[mi] = *(const s16x8*)&H2s[wm * 64 + mi * 16 + rsel][k0 + kk + ksel];
#pragma unroll
            for (int ni = 0; ni < 4; ++ni)
                bf[ni] = *(const s16x8*)&Bs[wn * 64 + ni * 16 + rsel][kk + ksel];
#pragma unroll
            for (int mi = 0; mi < 4; ++mi)
#pragma unroll
                for (int ni = 0; ni < 4; ++ni)
                    acc[mi][ni] = __builtin_amdgcn_mfma_f32_16x16x32_bf16(
                        af[mi], bf[ni], acc[mi][ni], 0, 0, 0);
        }
        __syncthreads();
    }
    // epilogue: residual (+VN, +bn(Z2)), relu, bf16 store; per-conformer SUMX
#pragma unroll
    for (int mi = 0; mi < 4; ++mi) {
        int gm0 = bm + wm * 64 + mi * 16;        // 16-row group = one conformer
        int cf = conf_of(gm0);
        float srow[4] = {0.f, 0.f, 0.f, 0.f};
#pragma unroll
        for (int r = 0; r < 4; ++r) {
            int m = gm0 + ((lane >> 4) << 2) + r;
            const float* z2row = &Z2[(size_t)(m & (NG - 1)) * 256];
#pragma unroll
            for (int ni = 0; ni < 4; ++ni) {
                int n = wn * 64 + ni * 16 + (lane & 15);
                size_t ix = (size_t)m * 256 + n;
                float z2v = fmaf(z2row[n], scb[n], shb[n]);
                float vnv = vn[(size_t)cf * 256 + n];
                float o = bf2f(X[ix]) + vnv + acc[mi][ni][r] + linb[n] + z2v;
                o = fmaxf(o, 0.f);
                X[ix] = f2bf(o);
                if (DOSUM) srow[ni] += o;
            }
        }
        if (DOSUM) {
#pragma unroll
            for (int ni = 0; ni < 4; ++ni) {
                float s = srow[ni];
                s += __shfl_xor(s, 16);
                s += __shfl_xor(s, 32);
                if ((lane >> 4) == 0) {
                    int n = wn * 64 + ni * 16 + (lane & 15);
                    SUMX[(size_t)cf * 256 + n] = s;
                }
            }
        }
    }
}

// ---------------- launch ----------------
extern "C" void kernel_launch(void* const* d_in, const int* in_sizes, int n_in,
                              void* d_out, int out_size, void* d_ws, size_t ws_size,
                              hipStream_t stream)
{
    (void)in_sizes; (void)n_in; (void)out_size; (void)ws_size;
    const float* pos       = (const float*)d_in[0];
    const float* atom_emb  = (const float*)d_in[1];
    const float* vn_emb    = (const float*)d_in[2];
    const float* cf_lin1   = (const float*)d_in[3];
    const float* cf_mlp_w1 = (const float*)d_in[4];
    const float* cf_mlp_b1 = (const float*)d_in[5];
    const float* cf_mlp_w2 = (const float*)d_in[6];
    const float* cf_mlp_b2 = (const float*)d_in[7];
    const float* cf_lin2   = (const float*)d_in[8];
    const float* cf_lin2_b = (const float*)d_in[9];
    const float* lin_w     = (const float*)d_in[10];
    const float* lin_b     = (const float*)d_in[11];
    const float* bond_emb  = (const float*)d_in[12];
    const float* gin_eps   = (const float*)d_in[13];
    const float* gin_w1    = (const float*)d_in[14];
    const float* gin_b1    = (const float*)d_in[15];
    const float* gin_g1    = (const float*)d_in[16];
    const float* gin_be1   = (const float*)d_in[17];
    const float* gin_w2    = (const float*)d_in[18];
    const float* gin_b2    = (const float*)d_in[19];
    const float* bn_g      = (const float*)d_in[20];
    const float* bn_b      = (const float*)d_in[21];
    const float* vn_w1     = (const float*)d_in[22];
    const float* vn_b1     = (const float*)d_in[23];
    const float* vn_w2     = (const float*)d_in[24];
    const float* vn_b2     = (const float*)d_in[25];
    const float* out_w1    = (const float*)d_in[26];
    const float* out_b1    = (const float*)d_in[27];
    const float* out_w2    = (const float*)d_in[28];
    const float* out_b2    = (const float*)d_in[29];
    const int* x_atom      = (const int*)d_in[30];
    const int* ei_conf     = (const int*)d_in[34];
    const int* ei_graph    = (const int*)d_in[35];
    const int* attr_graph  = (const int*)d_in[36];
    float* out = (float*)d_out;
    float* ws  = (float*)d_ws;

    size_t o = 0;
    float* Z2   = ws + o; o += (size_t)NG * H;
    float* VN0  = ws + o; o += (size_t)NCONF * H;
    float* VN1  = ws + o; o += (size_t)NCONF * H;
    float* SUMX = ws + o; o += (size_t)NCONF * H;
    float* XM   = ws + o; o += (size_t)NMOL * H;
    float* Y1   = ws + o; o += (size_t)NMOL * H;
    float* STATS= ws + o; o += 1024;
    float* PDCC = ws + o; o += (size_t)2 * EC;
    // bf16 regions
    unsigned short* XB   = (unsigned short*)(ws + o); o += (size_t)NC * H / 2;
    unsigned short* XA   = (unsigned short*)(ws + o); o += (size_t)NG * H / 2;
    unsigned short* AGGB = (unsigned short*)(ws + o); o += (size_t)NG * H / 2;
    unsigned short* Z1B  = (unsigned short*)(ws + o); o += (size_t)NG * H / 2;
    unsigned short* CFH  = (unsigned short*)(ws + o); o += (size_t)NC * F / 2;
    unsigned short* HAGG = (unsigned short*)(ws + o); o += (size_t)NC * F / 2;
    unsigned short* TAB  = (unsigned short*)(ws + o); o += (size_t)NLAYERS * NTAB * F / 2;
    // int region
    int* PSRC   = (int*)(ws + o); o += EC;
    int* PGSRC  = (int*)(ws + o); o += EG;
    int* PATTR  = (int*)(ws + o); o += EG;
    int* CNT    = (int*)(ws + o); o += NC + NG;
    int* ROWC   = (int*)(ws + o); o += NC + 64;
    int* CURC   = (int*)(ws + o); o += NC;
    int* ROWG   = (int*)(ws + o); o += NG + 64;
    int* CURG   = (int*)(ws + o); o += NG;
    int* BSUMC  = (int*)(ws + o); o += 256;
    int* BSUMG  = (int*)(ws + o); o += 64;
    // transposed bf16 weights
    unsigned short* WT = (unsigned short*)(ws + o);
    size_t wo = 0;
    unsigned short* lin1t = WT + wo; wo += (size_t)NLAYERS * 128 * 256;
    unsigned short* w1t   = WT + wo; wo += (size_t)NLAYERS * 128 * 64;
    unsigned short* w2t   = WT + wo; wo += (size_t)NLAYERS * 128 * 128;
    unsigned short* lin2t = WT + wo; wo += (size_t)NLAYERS * 256 * 128;
    unsigned short* linwt = WT + wo; wo += (size_t)NLAYERS * 256 * 256;
    unsigned short* g1t   = WT + wo; wo += (size_t)NLAYERS * 256 * 256;
    unsigned short* g2t   = WT + wo; wo += (size_t)NLAYERS * 256 * 256;
    unsigned short* vn1t  = WT + wo; wo += 256 * 256;
    unsigned short* vn2t  = WT + wo; wo += 256 * 256;
    unsigned short* ow1t  = WT + wo; wo += 256 * 256;

    // ---- weight prep: one dispatch + table build ----
    k_wprep<<<6400, 256, 0, stream>>>(
        cf_lin1, cf_mlp_w1, cf_mlp_w2, cf_lin2, lin_w, gin_w1, gin_w2,
        vn_w1, vn_w2, out_w1,
        lin1t, w1t, w2t, lin2t, linwt, g1t, g2t, vn1t, vn2t, ow1t);
    k_tab<<<dim3(NTAB / 128, NLAYERS), 256, 0, stream>>>(
        w1t, cf_mlp_b1, w2t, cf_mlp_b2, TAB);

    // ---- dst-sort both edge lists ----
    hipMemsetAsync(CNT, 0, (NC + NG) * sizeof(int), stream);
    k_hist2<<<(EC + EG) / 256, 256, 0, stream>>>(ei_conf, ei_graph, CNT);
    k_scan1m<<<288, 256, 0, stream>>>(CNT, ROWC, ROWG, BSUMC, BSUMG);
    k_scan2m<<<2, 256, 0, stream>>>(BSUMC, BSUMG);
    k_scan3m<<<288, 256, 0, stream>>>(ROWC, ROWG, BSUMC, BSUMG, CURC, CURG);
    k_perm2<<<(EC + EG) / 256, 256, 0, stream>>>(
        pos, ei_conf, ei_graph, attr_graph, CURC, CURG,
        PSRC, (float2*)PDCC, PGSRC, PATTR);

    k_init_x<<<NCONF, 256, 0, stream>>>(atom_emb, x_atom, vn_emb, XB, SUMX, VN0);

    float* vc = VN0;
    float* vx = VN1;
    for (int i = 0; i < NLAYERS; ++i) {
        if (i < NLAYERS - 1)
            k_vnmlp<<<NCONF / 128, 512, 0, stream>>>(
                SUMX, vc, vn1t, vn_b1, vn2t, vn_b2, vx);
        // ---- CFConv ----
        mgemm<6, 6><<<dim3(1, NC / 128), 256, 0, stream>>>(
            0, XB, lin1t + (size_t)i * 128 * 256, nullptr, 0, CFH,
            256, 256, 128, 0, 0, 0, 0, vc);
        k_cf_agg<<<NC / 16, 256, 0, stream>>>(TAB + (size_t)i * NTAB * F,
            ROWC, PSRC, (const float2*)PDCC, CFH, HAGG);
        // ---- GIN ----
        k_xa2<<<NMOL, 256, 0, stream>>>(XB, vc, XA);
        k_gin_agg<<<NG, 256, 0, stream>>>(
            XA, bond_emb + (size_t)i * 3 * 8 * H, ROWG, PGSRC, PATTR,
            gin_eps + i, AGGB, STATS);
        mgemm<2, 8><<<dim3(2, NG / 128), 256, 0, stream>>>(
            0, AGGB, g1t + (size_t)i * 256 * 256, gin_b1 + i * H, 0, Z1B,
            256, 256, 256, 0, 0, 0, STATS, 0);
        mgemm<5, 7><<<dim3(2, NG / 128), 256, 0, stream>>>(
            0, Z1B, g2t + (size_t)i * 256 * 256, gin_b2 + i * H, Z2, 0,
            256, 256, 256, gin_g1 + i * H, gin_be1 + i * H, STATS, STATS + 512, 0);
        // ---- fused combine (128-row shape, in-kernel Z2 BN, +VN residual, SUMX) ----
        if (i < NLAYERS - 1)
            k_combine<true><<<NC / 128, 512, 0, stream>>>(
                HAGG, lin2t + (size_t)i * 256 * 128, cf_lin2_b + i * H,
                linwt + (size_t)i * 256 * 256, lin_b + i * H, Z2,
                STATS + 512, bn_g + i * H, bn_b + i * H, vc, XB, SUMX);
        else
            k_combine<false><<<NC / 128, 512, 0, stream>>>(
                HAGG, lin2t + (size_t)i * 256 * 128, cf_lin2_b + i * H,
                linwt + (size_t)i * 256 * 256, lin_b + i * H, Z2,
                STATS + 512, bn_g + i * H, bn_b + i * H, vc, XB, SUMX);
        float* t = vc; vc = vx; vx = t;
    }

    k_molmax<<<NMOL, 256, 0, stream>>>(XB, XM);
    mgemm<0, 1><<<dim3(2, NMOL / 128), 256, 0, stream>>>(
        XM, 0, ow1t, out_b1, Y1, 0, 256, 256, 256, 0, 0, 0, 0, 0);
    k_head<<<NMOL, 256, 0, stream>>>(Y1, out_w2, out_b2, out);
}